// Round 8
// baseline (7581.271 us; speedup 1.0000x reference)
//
#include <hip/hip_runtime.h>
#include <hip/hip_bf16.h>
#include <hip/hip_cooperative_groups.h>

namespace cg = cooperative_groups;

#define BATCH 1024
#define NLAYER 19
#define DTOT 267696
#define NSLOT 64
#define PSL (NSLOT*128)   // floats per layer partial-stats region

typedef __attribute__((ext_vector_type(8))) short v8s;
typedef __attribute__((ext_vector_type(4))) float v4f;

__device__ inline float ldf(const float* p){ return *p; }
__device__ inline float ldf(const __hip_bfloat16* p){ return __bfloat162float(*p); }

__device__ inline unsigned short f2bf(float x){
    __hip_bfloat16 h = __float2bfloat16(x);
    return *reinterpret_cast<unsigned short*>(&h);
}
__device__ inline float bf2f(unsigned int u){
    return __uint_as_float(u << 16);
}
// device-coherent (agent-scope) ops: bypass the non-coherent per-XCD L2 for
// the small cross-block stats traffic inside the cooperative kernel.
__device__ inline float ld_coh(const float* p){
    return __hip_atomic_load(p, __ATOMIC_RELAXED, __HIP_MEMORY_SCOPE_AGENT);
}
__device__ inline void st_coh(float* p, float v){
    __hip_atomic_store(p, v, __ATOMIC_RELAXED, __HIP_MEMORY_SCOPE_AGENT);
}
__device__ inline int ld_coh_i(const int* p){
    return __hip_atomic_load(p, __ATOMIC_RELAXED, __HIP_MEMORY_SCOPE_AGENT);
}

// ---- dtype detector: flag=1 if inputs bf16, 0 if f32 ----
__global__ void detect_kernel(const unsigned short* __restrict__ xraw, int* __restrict__ flag)
{
    __shared__ int bad;
    if (threadIdx.x == 0) bad = 0;
    __syncthreads();
    int lbad = 0;
    for (int i = threadIdx.x; i < 4096; i += 256) {
        unsigned e = (xraw[i] >> 7) & 0xFF;
        if (e >= 147) lbad++;
    }
    if (lbad) atomicAdd(&bad, lbad);
    __syncthreads();
    if (threadIdx.x == 0) *flag = (bad == 0) ? 1 : 0;
}

__device__ inline bool flag_skip(const int* flag, int want)
{
    if (flag == nullptr) return false;
    return (*(volatile const int*)flag) != want;
}

// w_flat = origin + new_param @ P
template<typename T>
__global__ void wflat_kernel(const T* __restrict__ origin,
                             const T* __restrict__ P,
                             const T* __restrict__ npar,
                             float* __restrict__ wout, int D,
                             const int* flag, int want)
{
    if (flag_skip(flag, want)) return;
    int d = blockIdx.x*256 + threadIdx.x;
    if (d >= D) return;
    float acc = ldf(origin + d);
    #pragma unroll 8
    for (int k = 0; k < 40; k++)
        acc += ldf(npar + k) * ldf(P + (long long)k*D + d);
    wout[d] = acc;
}

// ---- weight transform: wflat (OIHW fp32) -> W_T[l][cout][kpad] bf16 ----
__global__ void wprep_kernel(const float* __restrict__ wflat, unsigned short* __restrict__ WT)
{
    static const int CINA[19]  = {3,16,16,16,16,16,16,16,32,32,32,32,32,32,64,64,64,64,64};
    static const int COUTA[19] = {16,16,16,16,16,16,16,32,32,32,32,32,32,64,64,64,64,64,64};
    static const int LGCA[19]  = {0,4,4,4,4,4,4,4,5,5,5,5,5,5,6,6,6,6,6};
    static const int KPADA[19] = {0,160,160,160,160,160,160,160,288,288,288,288,288,288,576,576,576,576,576};
    static const int WOFFA[19] = {0,432,2736,5040,7344,9648,11952,14256,18864,
        28080,37296,46512,55728,64944,83376,120240,157104,193968,230832};
    static const int WTOFFA[19]= {0,0,2560,5120,7680,10240,12800,15360,20480,29696,
        38912,48128,57344,66560,84992,121856,158720,195584,232448};
    int l = blockIdx.z;
    if (l == 0) return;
    int co = blockIdx.y;
    if (co >= COUTA[l]) return;
    int kp = blockIdx.x*192 + threadIdx.x;
    if (kp >= KPADA[l]) return;
    int cin = CINA[l];
    float v = 0.f;
    if (kp < 9*cin) {
        int tap = kp >> LGCA[l];
        int ci  = kp & (cin - 1);
        v = wflat[WOFFA[l] + (co*cin + ci)*9 + tap];
    }
    WT[WTOFFA[l] + co*KPADA[l] + kp] = f2bf(v);
}

__device__ inline void ldpair(const float* base, int p, float& x0, float& x1){
    const float2 v = ((const float2*)base)[p];
    x0 = v.x; x1 = v.y;
}
__device__ inline void ldpair(const __hip_bfloat16* base, int p, float& x0, float& x1){
    unsigned u = ((const unsigned int*)base)[p];
    x0 = __uint_as_float(u << 16);
    x1 = __uint_as_float(u & 0xffff0000u);
}

// ---- layer 0: direct conv (Cin=3), NCHW input -> NHWC bf16 raw ----
template<typename T>
__global__ __launch_bounds__(512) void conv_l0(
    const T* __restrict__ in, const float* __restrict__ wt,
    unsigned short* __restrict__ out, float* __restrict__ ps,
    const int* flag, int want)
{
    if (flag_skip(flag, want)) return;
    constexpr int WP = 38, W2 = 19;
    __shared__ uint2 smem2[2048];
    __shared__ unsigned int in_su[3*18*W2];
    __shared__ float sred[8][32];

    const int tid  = threadIdx.x;
    const int b    = blockIdx.x >> 1;
    const int half = blockIdx.x & 1;
    const int row0 = half*16 - 1;

    {
        const T* inb = in + (size_t)b*3072;
        for (int i = tid; i < 864; i += 512) {
            int w2 = i & 15, lr = (i >> 4) % 18, c = i / 288;
            int ih = row0 + lr;
            unsigned int pk = 0u;
            if ((unsigned)ih < 32u) {
                float x0, x1;
                ldpair(inb, (c*32 + ih)*16 + w2, x0, x1);
                pk = (unsigned int)f2bf(x0) | ((unsigned int)f2bf(x1) << 16);
            }
            in_su[(c*18 + lr)*W2 + 1 + w2] = pk;
        }
        unsigned short* in_ss = (unsigned short*)in_su;
        for (int i = tid; i < 54; i += 512) {
            in_ss[i*WP + 1]  = 0;
            in_ss[i*WP + 34] = 0;
        }
    }
    __syncthreads();

    const int r   = tid >> 5;
    const int col = tid & 31;
    const bool odd = (col & 1);

    float xin[27];
    #pragma unroll
    for (int ci = 0; ci < 3; ci++) {
        #pragma unroll
        for (int kh = 0; kh < 3; kh++) {
            const unsigned int* up = in_su + (ci*18 + r + kh)*W2 + ((col+1) >> 1);
            unsigned int u0 = up[0], u1 = up[1];
            const int kb = ci*9 + kh*3;
            xin[kb+0] = odd ? bf2f(u0 & 0xffffu) : bf2f(u0 >> 16);
            xin[kb+1] = odd ? bf2f(u0 >> 16)     : bf2f(u1 & 0xffffu);
            xin[kb+2] = odd ? bf2f(u1 & 0xffffu) : bf2f(u1 >> 16);
        }
    }

    float acc[16];
    #pragma unroll
    for (int co = 0; co < 16; co++) {
        float a = 0.f;
        #pragma unroll
        for (int k = 0; k < 27; k++)
            a += xin[k] * wt[co*27 + k];   // uniform addr -> SGPR weight
        acc[co] = a;
    }

    #pragma unroll
    for (int j = 0; j < 4; j++) {
        uint2 v;
        v.x = (unsigned)f2bf(acc[4*j+0]) | ((unsigned)f2bf(acc[4*j+1]) << 16);
        v.y = (unsigned)f2bf(acc[4*j+2]) | ((unsigned)f2bf(acc[4*j+3]) << 16);
        smem2[tid*4 + (j ^ (tid & 3))] = v;
    }
    __syncthreads();

    float s4[4] = {0,0,0,0}, q4[4] = {0,0,0,0};
    {
        uint2* ob = (uint2*)(out + (size_t)b*16384 + half*8192);
        #pragma unroll
        for (int it = 0; it < 4; it++) {
            int s = it*512 + tid;
            int phys = (s & ~3) | ((s & 3) ^ ((s >> 2) & 3));
            uint2 v = smem2[phys];
            ob[s] = v;
            float f0 = bf2f(v.x & 0xffffu), f1v = bf2f(v.x >> 16);
            float f2v = bf2f(v.y & 0xffffu), f3v = bf2f(v.y >> 16);
            s4[0] += f0;  q4[0] += f0*f0;
            s4[1] += f1v; q4[1] += f1v*f1v;
            s4[2] += f2v; q4[2] += f2v*f2v;
            s4[3] += f3v; q4[3] += f3v*f3v;
        }
    }
    #pragma unroll
    for (int off = 4; off < 64; off <<= 1) {
        #pragma unroll
        for (int k2 = 0; k2 < 4; k2++) {
            s4[k2] += __shfl_xor(s4[k2], off);
            q4[k2] += __shfl_xor(q4[k2], off);
        }
    }
    {
        const int lane = tid & 63, wv = tid >> 6;
        if (lane < 4) {
            #pragma unroll
            for (int k2 = 0; k2 < 4; k2++) {
                sred[wv][lane*4 + k2]      = s4[k2];
                sred[wv][16 + lane*4 + k2] = q4[k2];
            }
        }
    }
    __syncthreads();
    if (tid < 32) {
        float a = 0.f;
        #pragma unroll
        for (int wv = 0; wv < 8; wv++) a += sred[wv][tid];
        float* sl = ps + (blockIdx.x & (NSLOT-1))*128;
        atomicAdd(&sl[(tid < 16) ? tid : (48 + tid)], a);
    }
}

// ---- shared-memory layout reused across all conv layers + pool phase ----
struct SM {
    unsigned short in_s[16*32*32];   // input, then output bounce
    float red[128];
    float statred[256];
    float nm[64], nv[64];
    float pm_s[64], pv_s[64];
    uint4 zq;
};

// one block reduces 64-slot partials -> finals {m[64], rs[64]}, agent-stored
template<bool COH>
__device__ void finalize_stats(SM& sm, const float* __restrict__ psL,
                               float invN, float* __restrict__ fsL)
{
    const int tid = threadIdx.x;
    if (tid < 128) {
        float s = 0.f;
        #pragma unroll 8
        for (int k = 0; k < NSLOT; k++)
            s += COH ? ld_coh(&psL[k*128 + tid]) : psL[k*128 + tid];
        sm.statred[tid] = s;
    }
    __syncthreads();
    if (tid < 64) {
        float m = sm.statred[tid]*invN;
        float v = fmaxf(sm.statred[64 + tid]*invN - m*m, 0.f);
        st_coh(&fsL[tid],      m);
        st_coh(&fsL[64 + tid], rsqrtf(v + 1e-5f));
    }
    __syncthreads();
}

// all blocks: read 512B of finals -> sm.nm/nv (and pm/pv)
__device__ inline void load_finals(SM& sm, const float* __restrict__ fsL,
                                   const float* __restrict__ fsPN)
{
    const int tid = threadIdx.x;
    if (tid < 64) {
        sm.nm[tid] = ld_coh(&fsL[tid]);
        sm.nv[tid] = ld_coh(&fsL[64 + tid]);
    }
    if (fsPN != nullptr && tid < 64) {
        sm.pm_s[tid] = ld_coh(&fsPN[tid]);
        sm.pv_s[tid] = ld_coh(&fsPN[64 + tid]);
    }
    __syncthreads();
}

// ---- one MFMA implicit-GEMM 3x3 conv layer, BODY ONLY (r4-proven code) ----
// Caller must populate sm.nm/nv (and pm_s/pv_s if PN) and __syncthreads.
template<int CIN, int COUT, int HIN, int WIN, int ST, bool FUSE, bool PN,
         bool FUSE2, int PREVC, int PADF>
__device__ void conv_layer(SM& sm,
    const unsigned short* __restrict__ src, const unsigned short* __restrict__ prev,
    unsigned short* __restrict__ resid,
    const unsigned short* __restrict__ wt,
    unsigned short* __restrict__ out, float* __restrict__ stats)
{
    constexpr int HO = HIN/ST, WO = WIN/ST, M = HO*WO, MT = M/16;
    constexpr int NT = COUT/16;
    constexpr int K  = 9*CIN;
    constexpr int S  = (K + 31)/32;
    constexpr int KPAD = S*32;
    constexpr int lgC  = (CIN==16)?4:(CIN==32)?5:6;
    constexpr int lgWI = (WIN==32)?5:(WIN==16)?4:3;
    constexpr int lgWO = (WO==32)?5:(WO==16)?4:3;
    constexpr int CMASK = CIN/8 - 1;
    constexpr int JITER = (NT==1)? MT/4 : (NT==2)? MT/2 : MT;
    static_assert(M*COUT <= CIN*HIN*WIN, "out_s fits in in_s");
    static_assert(CIN*HIN*WIN <= 16*32*32, "fits SM.in_s");

    unsigned short* in_s = sm.in_s;
    const int tid = threadIdx.x;
    const int b   = blockIdx.x;

    // ---- staging ----
    {
        const uint4* sb4 = (const uint4*)(src + (size_t)b*(HIN*WIN)*CIN);
        constexpr int NP4 = CIN*HIN*WIN/8;
        if (FUSE) {
            const uint4* pb4 = (const uint4*)(prev + (size_t)b*(HIN*WIN)*CIN);
            uint4* rb4 = (uint4*)(resid + (size_t)b*(HIN*WIN)*CIN);
            for (int i = tid; i < NP4; i += 256) {
                uint4 v = sb4[i];
                uint4 pw = pb4[i];
                int e0 = i << 3;
                int c0 = e0 & (CIN-1);
                int p  = e0 >> lgC;
                float f[8] = { bf2f(v.x & 0xffffu), bf2f(v.x >> 16),
                               bf2f(v.y & 0xffffu), bf2f(v.y >> 16),
                               bf2f(v.z & 0xffffu), bf2f(v.z >> 16),
                               bf2f(v.w & 0xffffu), bf2f(v.w >> 16) };
                float g[8] = { bf2f(pw.x & 0xffffu), bf2f(pw.x >> 16),
                               bf2f(pw.y & 0xffffu), bf2f(pw.y >> 16),
                               bf2f(pw.z & 0xffffu), bf2f(pw.z >> 16),
                               bf2f(pw.w & 0xffffu), bf2f(pw.w >> 16) };
                #pragma unroll
                for (int k = 0; k < 8; k++) {
                    int c = c0 + k;
                    float fx = (f[k] - sm.nm[c])*sm.nv[c];
                    float gv = g[k];
                    if (PN) gv = fmaxf((gv - sm.pm_s[c])*sm.pv_s[c], 0.f);
                    f[k] = fmaxf(fx + gv, 0.f);
                }
                uint4 o;
                o.x = (unsigned)f2bf(f[0]) | ((unsigned)f2bf(f[1]) << 16);
                o.y = (unsigned)f2bf(f[2]) | ((unsigned)f2bf(f[3]) << 16);
                o.z = (unsigned)f2bf(f[4]) | ((unsigned)f2bf(f[5]) << 16);
                o.w = (unsigned)f2bf(f[6]) | ((unsigned)f2bf(f[7]) << 16);
                rb4[i] = o;
                int csw = c0 ^ ((p & CMASK) << 3);
                *(uint4*)(in_s + (p << lgC) + csw) = o;
            }
        } else if (FUSE2) {
            uint4* rb4 = (uint4*)(resid + (size_t)b*(HIN*WIN)*CIN);
            for (int i = tid; i < NP4; i += 256) {
                uint4 v = sb4[i];
                int e0 = i << 3;
                int c0 = e0 & (CIN-1);
                int p  = e0 >> lgC;
                int h  = p >> lgWI, wq = p & (WIN-1);
                int pp = (h << (lgWI+2)) + 2*wq;
                int pc0 = c0 - PADF;
                bool pv = (pc0 >= 0) && (pc0 <= PREVC - 8);
                uint4 pw;
                pw.x = 0; pw.y = 0; pw.z = 0; pw.w = 0;
                if (pv) pw = *(const uint4*)(prev + ((size_t)b*(HIN*WIN*4) + pp)*PREVC + pc0);
                float f[8] = { bf2f(v.x & 0xffffu), bf2f(v.x >> 16),
                               bf2f(v.y & 0xffffu), bf2f(v.y >> 16),
                               bf2f(v.z & 0xffffu), bf2f(v.z >> 16),
                               bf2f(v.w & 0xffffu), bf2f(v.w >> 16) };
                float g[8] = { bf2f(pw.x & 0xffffu), bf2f(pw.x >> 16),
                               bf2f(pw.y & 0xffffu), bf2f(pw.y >> 16),
                               bf2f(pw.z & 0xffffu), bf2f(pw.z >> 16),
                               bf2f(pw.w & 0xffffu), bf2f(pw.w >> 16) };
                #pragma unroll
                for (int k = 0; k < 8; k++) {
                    int c = c0 + k;
                    f[k] = fmaxf((f[k] - sm.nm[c])*sm.nv[c] + g[k], 0.f);
                }
                uint4 o;
                o.x = (unsigned)f2bf(f[0]) | ((unsigned)f2bf(f[1]) << 16);
                o.y = (unsigned)f2bf(f[2]) | ((unsigned)f2bf(f[3]) << 16);
                o.z = (unsigned)f2bf(f[4]) | ((unsigned)f2bf(f[5]) << 16);
                o.w = (unsigned)f2bf(f[6]) | ((unsigned)f2bf(f[7]) << 16);
                rb4[i] = o;
                int csw = c0 ^ ((p & CMASK) << 3);
                *(uint4*)(in_s + (p << lgC) + csw) = o;
            }
        } else {
            for (int i = tid; i < NP4; i += 256) {
                uint4 v = sb4[i];
                int e0 = i << 3;
                int c0 = e0 & (CIN-1);
                int p  = e0 >> lgC;
                float f[8] = { bf2f(v.x & 0xffffu), bf2f(v.x >> 16),
                               bf2f(v.y & 0xffffu), bf2f(v.y >> 16),
                               bf2f(v.z & 0xffffu), bf2f(v.z >> 16),
                               bf2f(v.w & 0xffffu), bf2f(v.w >> 16) };
                #pragma unroll
                for (int k = 0; k < 8; k++) {
                    int c = c0 + k;
                    f[k] = fmaxf((f[k] - sm.nm[c])*sm.nv[c], 0.f);
                }
                uint4 o;
                o.x = (unsigned)f2bf(f[0]) | ((unsigned)f2bf(f[1]) << 16);
                o.y = (unsigned)f2bf(f[2]) | ((unsigned)f2bf(f[3]) << 16);
                o.z = (unsigned)f2bf(f[4]) | ((unsigned)f2bf(f[5]) << 16);
                o.w = (unsigned)f2bf(f[6]) | ((unsigned)f2bf(f[7]) << 16);
                int csw = c0 ^ ((p & CMASK) << 3);
                *(uint4*)(in_s + (p << lgC) + csw) = o;
            }
        }
    }
    __syncthreads();

    const int w   = tid >> 6;
    const int ln  = tid & 63;
    const int l15 = ln & 15;
    const int q   = ln >> 4;

    int n0, mt0, step;
    if (NT == 1)      { n0 = 0;         mt0 = w;      step = 4; }
    else if (NT == 2) { n0 = (w&1)*16;  mt0 = w>>1;   step = 2; }
    else              { n0 = w*16;      mt0 = 0;      step = 1; }

    const unsigned short* wb = wt + (size_t)(n0 + l15)*KPAD + q*8;
    const int c0q = (CIN==16) ? ((q & 1) << 3) : (q << 3);

    v4f acc[JITER];
    #pragma unroll
    for (int j = 0; j < JITER; j++) acc[j] = v4f{0.f,0.f,0.f,0.f};

    if constexpr (CIN == 64) {
        #pragma unroll
        for (int s = 0; s < S; s++) {
            const v8s Bf = *(const v8s*)(wb + 32*s);
            const int tap = s >> 1;
            const int dh1 = tap/3 - 1, dw1 = tap%3 - 1;
            const int c0s = c0q + ((s & 1) << 5);
            #pragma unroll
            for (int j = 0; j < JITER; j++) {
                const int mt  = mt0 + j*step;
                const int p   = mt*16 + l15;
                const int ihb = (p >> lgWO) * ST;
                const int iwb = (p & (WO-1)) * ST;
                int ih = ihb + dh1, iw = iwb + dw1;
                bool valid = ((unsigned)ih < (unsigned)HIN) && ((unsigned)iw < (unsigned)WIN);
                int pp  = (ih << lgWI) + iw;
                int csw = c0s ^ ((pp & CMASK) << 3);
                int eoff = (pp << lgC) + csw;
                const v8s* ap = valid ? (const v8s*)(in_s + eoff) : (const v8s*)&sm.zq;
                v8s Af = *ap;
                acc[j] = __builtin_amdgcn_mfma_f32_16x16x32_bf16(Af, Bf, acc[j], 0, 0, 0);
            }
        }
    } else {
        v8s Bf[S];
        #pragma unroll
        for (int s = 0; s < S; s++)
            Bf[s] = *(const v8s*)(wb + 32*s);

        int dh1s[S], dw1s[S];
        if (CIN == 16) {
            int tq = q >> 1;
            #pragma unroll
            for (int s = 0; s < S; s++) {
                int tap = 2*s + tq;
                int dh = (tap*11) >> 5;
                int dw = tap - 3*dh;
                dh1s[s] = (tap >= 9) ? -1000 : (dh - 1);
                dw1s[s] = dw - 1;
            }
        }

        #pragma unroll
        for (int j = 0; j < JITER; j++) {
            const int mt  = mt0 + j*step;
            const int p   = mt*16 + l15;
            const int ihb = (p >> lgWO) * ST;
            const int iwb = (p & (WO-1)) * ST;
            #pragma unroll
            for (int s = 0; s < S; s++) {
                int dh1, dw1;
                if (CIN == 16) { dh1 = dh1s[s]; dw1 = dw1s[s]; }
                else           { dh1 = s/3 - 1; dw1 = s%3 - 1; }
                int ih = ihb + dh1, iw = iwb + dw1;
                bool valid = ((unsigned)ih < (unsigned)HIN) && ((unsigned)iw < (unsigned)WIN);
                int pp  = (ih << lgWI) + iw;
                int csw = c0q ^ ((pp & CMASK) << 3);
                int eoff = (pp << lgC) + csw;
                const v8s* ap = valid ? (const v8s*)(in_s + eoff) : (const v8s*)&sm.zq;
                v8s Af = *ap;
                acc[j] = __builtin_amdgcn_mfma_f32_16x16x32_bf16(Af, Bf[s], acc[j], 0, 0, 0);
            }
        }
    }
    __syncthreads();   // all in_s reads complete -> reuse as output bounce

    unsigned short* out_s = in_s;
    float sa = 0.f, qa = 0.f;
    #pragma unroll
    for (int j = 0; j < JITER; j++) {
        const int mt = mt0 + j*step;
        #pragma unroll
        for (int r2 = 0; r2 < 4; r2++) {
            float v = acc[j][r2];
            out_s[(mt*16 + q*4 + r2)*COUT + n0 + l15] = f2bf(v);
            sa += v; qa += v*v;
        }
    }
    __syncthreads();

    {
        constexpr int NIT = (M*COUT/8)/256;
        uint4* ob4 = (uint4*)(out + (size_t)b*M*COUT);
        const uint4* os4 = (const uint4*)in_s;
        #pragma unroll
        for (int it = 0; it < NIT; it++)
            ob4[it*256 + tid] = os4[it*256 + tid];
    }

    sa += __shfl_xor(sa, 16); sa += __shfl_xor(sa, 32);
    qa += __shfl_xor(qa, 16); qa += __shfl_xor(qa, 32);
    if (q == 0) {
        sm.red[(w*16 + l15)*2]     = sa;
        sm.red[(w*16 + l15)*2 + 1] = qa;
    }
    __syncthreads();
    if (tid < COUT) {
        float S2, Q2;
        if (NT == 1) {
            S2 = sm.red[tid*2] + sm.red[(16+tid)*2] + sm.red[(32+tid)*2] + sm.red[(48+tid)*2];
            Q2 = sm.red[tid*2+1] + sm.red[(16+tid)*2+1] + sm.red[(32+tid)*2+1] + sm.red[(48+tid)*2+1];
        } else if (NT == 2) {
            int w0 = tid >> 4, cl = tid & 15;
            S2 = sm.red[((w0*16)+cl)*2]     + sm.red[(((w0+2)*16)+cl)*2];
            Q2 = sm.red[((w0*16)+cl)*2 + 1] + sm.red[(((w0+2)*16)+cl)*2 + 1];
        } else {
            int w0 = tid >> 4, cl = tid & 15;
            S2 = sm.red[((w0*16)+cl)*2];
            Q2 = sm.red[((w0*16)+cl)*2 + 1];
        }
        float* sl = stats + (b & (NSLOT-1))*128;
        atomicAdd(&sl[tid],      S2);
        atomicAdd(&sl[64 + tid], Q2);
    }
}

// ---- standalone wrapper (fallback multi-dispatch path; r4 math exactly) ----
template<int CIN, int COUT, int HIN, int WIN, int ST, bool FUSE, bool PN,
         bool FUSE2, int PREVC, int PADF>
__global__ __launch_bounds__(256, 4) void conv_mfma_k(
    const unsigned short* __restrict__ src, const unsigned short* __restrict__ prev,
    unsigned short* __restrict__ resid,
    const unsigned short* __restrict__ wt,
    unsigned short* __restrict__ out, float* __restrict__ stats,
    const float* __restrict__ nstats, float ninvN,
    const float* __restrict__ pstats, float pinvN)
{
    __shared__ SM sm;
    const int tid = threadIdx.x;
    if (tid == 0) { sm.zq.x = 0; sm.zq.y = 0; sm.zq.z = 0; sm.zq.w = 0; }
    {
        const int idx = tid & 127, hf = tid >> 7;
        float sacc = 0.f;
        #pragma unroll 8
        for (int k = hf*32; k < hf*32 + 32; k++)
            sacc += nstats[k*128 + idx];
        sm.statred[tid] = sacc;
    }
    __syncthreads();
    if (tid < CIN) {
        float ssum = sm.statred[tid]      + sm.statred[128 + tid];
        float qsum = sm.statred[64 + tid] + sm.statred[192 + tid];
        float m = ssum*ninvN;
        float v = fmaxf(qsum*ninvN - m*m, 0.f);
        sm.nm[tid] = m; sm.nv[tid] = rsqrtf(v + 1e-5f);
    }
    if (PN && tid < CIN) {
        float ssum = 0.f, qsum = 0.f;
        for (int k = 0; k < NSLOT; k++) {
            ssum += pstats[k*128 + tid];
            qsum += pstats[k*128 + 64 + tid];
        }
        float m = ssum*pinvN;
        float v = fmaxf(qsum*pinvN - m*m, 0.f);
        sm.pm_s[tid] = m; sm.pv_s[tid] = rsqrtf(v + 1e-5f);
    }
    __syncthreads();
    conv_layer<CIN,COUT,HIN,WIN,ST,FUSE,PN,FUSE2,PREVC,PADF>(
        sm, src, prev, resid, wt, out, stats);
}

__device__ inline void stf(float* p, float v){ *p = v; }
__device__ inline void stf(__hip_bfloat16* p, float v){ *p = __float2bfloat16(v); }

// fallback pool+fc (r4)
template<typename T>
__global__ void poolfc_kernel(const unsigned short* __restrict__ x,
    const unsigned short* __restrict__ resid,
    const float* __restrict__ stats, float invN,
    const T* __restrict__ Wfc, const T* __restrict__ bfc,
    T* __restrict__ out, const int* flag, int want)
{
    if (flag_skip(flag, want)) return;
    int b = blockIdx.x;
    int c = threadIdx.x; // 64 threads
    float ssum = 0.f, qsum = 0.f;
    for (int k = 0; k < NSLOT; k++) {
        ssum += stats[k*128 + c];
        qsum += stats[k*128 + 64 + c];
    }
    float m = ssum*invN;
    float v = fmaxf(qsum*invN - m*m, 0.f);
    float rs = rsqrtf(v + 1e-5f);
    float s = 0.f;
    #pragma unroll
    for (int p = 0; p < 64; p++) {
        size_t idx = ((size_t)b*64 + p)*64 + c;
        float xv = bf2f((unsigned int)x[idx]);
        float rv = bf2f((unsigned int)resid[idx]);
        s += fmaxf((xv - m)*rs + rv, 0.f);
    }
    __shared__ float feat[64];
    feat[c] = s * (1.f/64.f);
    __syncthreads();
    if (c < 10) {
        float o = ldf(bfc + c);
        for (int k = 0; k < 64; k++)
            o += feat[k] * ldf(Wfc + c*64 + k);
        stf(out + b*10 + c, o);
    }
}

struct MegaArgs {
    unsigned short* curA;
    unsigned short* curB;
    unsigned short* f1;
    unsigned short* f2;
    const unsigned short* WT;
    float* ps;
    float* fs;        // 19 x 128 finals {m[64], rs[64]}
    const void* Wfc;
    const void* bfc;
    void* out;
    const int* flag;
};

// ---- cooperative mega kernel: layers 1..18 + pool/FC ----
// Cross-block stats use the finalize-block pattern: producers atomicAdd
// 64-slot partials; after grid.sync, block 0 reduces them ONCE into 128
// finals (agent-stores); second grid.sync; consumers coherently read 512B.
// (r6 lesson: per-block coherent re-reduce was 589MB of uncacheable traffic.)
__global__ __launch_bounds__(256, 4) void mega_kernel(MegaArgs a)
{
    __shared__ SM sm;
    cg::grid_group grid = cg::this_grid();
    const int tid = threadIdx.x;
    const int b   = blockIdx.x;

    if (tid == 0) { sm.zq.x = 0; sm.zq.y = 0; sm.zq.z = 0; sm.zq.w = 0; }

    constexpr float iN32 = 1.f/1048576.f;
    constexpr float iN16 = 1.f/262144.f;
    constexpr float iN8  = 1.f/65536.f;
    static const int WTOFF[NLAYER] = {0,0,2560,5120,7680,10240,12800,15360,20480,29696,
        38912,48128,57344,66560,84992,121856,158720,195584,232448};
    float* ps = a.ps;
    float* fs = a.fs;

    #define GSYNC() do { __threadfence(); grid.sync(); } while(0)

    // pre-phase: finalize layer-0 stats (written by conv_l0, prior dispatch)
    if (b == 0) finalize_stats<false>(sm, ps, iN32, fs);
    GSYNC();

    // L1
    load_finals(sm, fs + 0*128, nullptr);
    conv_layer<16,16,32,32,1,false,false,false,0,0>(sm, a.curB, nullptr, nullptr, a.WT+WTOFF[1], a.f1, ps+1*PSL);
    GSYNC();
    if (b == 0) finalize_stats<true>(sm, ps+1*PSL, iN32, fs+1*128);
    GSYNC();
    // L2
    load_finals(sm, fs + 1*128, nullptr);
    conv_layer<16,16,32,32,1,false,false,false,0,0>(sm, a.f1, nullptr, nullptr, a.WT+WTOFF[2], a.f2, ps+2*PSL);
    GSYNC();
    if (b == 0) finalize_stats<true>(sm, ps+2*PSL, iN32, fs+2*128);
    GSYNC();
    // L3 (FUSE + PN with layer-0 finals)
    load_finals(sm, fs + 2*128, fs);
    conv_layer<16,16,32,32,1,true,true,false,0,0>(sm, a.f2, a.curB, a.curA, a.WT+WTOFF[3], a.f1, ps+3*PSL);
    GSYNC();
    if (b == 0) finalize_stats<true>(sm, ps+3*PSL, iN32, fs+3*128);
    GSYNC();
    // L4
    load_finals(sm, fs + 3*128, nullptr);
    conv_layer<16,16,32,32,1,false,false,false,0,0>(sm, a.f1, nullptr, nullptr, a.WT+WTOFF[4], a.f2, ps+4*PSL);
    GSYNC();
    if (b == 0) finalize_stats<true>(sm, ps+4*PSL, iN32, fs+4*128);
    GSYNC();
    // L5 (FUSE)
    load_finals(sm, fs + 4*128, nullptr);
    conv_layer<16,16,32,32,1,true,false,false,0,0>(sm, a.f2, a.curA, a.curB, a.WT+WTOFF[5], a.f1, ps+5*PSL);
    GSYNC();
    if (b == 0) finalize_stats<true>(sm, ps+5*PSL, iN32, fs+5*128);
    GSYNC();
    // L6
    load_finals(sm, fs + 5*128, nullptr);
    conv_layer<16,16,32,32,1,false,false,false,0,0>(sm, a.f1, nullptr, nullptr, a.WT+WTOFF[6], a.f2, ps+6*PSL);
    GSYNC();
    if (b == 0) finalize_stats<true>(sm, ps+6*PSL, iN32, fs+6*128);
    GSYNC();
    // L7 (FUSE, stride2)
    load_finals(sm, fs + 6*128, nullptr);
    conv_layer<16,32,32,32,2,true,false,false,0,0>(sm, a.f2, a.curB, a.curA, a.WT+WTOFF[7], a.f1, ps+7*PSL);
    GSYNC();
    if (b == 0) finalize_stats<true>(sm, ps+7*PSL, iN16, fs+7*128);
    GSYNC();
    // L8
    load_finals(sm, fs + 7*128, nullptr);
    conv_layer<32,32,16,16,1,false,false,false,0,0>(sm, a.f1, nullptr, nullptr, a.WT+WTOFF[8], a.f2, ps+8*PSL);
    GSYNC();
    if (b == 0) finalize_stats<true>(sm, ps+8*PSL, iN16, fs+8*128);
    GSYNC();
    // L9 (FUSE2)
    load_finals(sm, fs + 8*128, nullptr);
    conv_layer<32,32,16,16,1,false,false,true,16,8>(sm, a.f2, a.curA, a.curB, a.WT+WTOFF[9], a.f1, ps+9*PSL);
    GSYNC();
    if (b == 0) finalize_stats<true>(sm, ps+9*PSL, iN16, fs+9*128);
    GSYNC();
    // L10
    load_finals(sm, fs + 9*128, nullptr);
    conv_layer<32,32,16,16,1,false,false,false,0,0>(sm, a.f1, nullptr, nullptr, a.WT+WTOFF[10], a.f2, ps+10*PSL);
    GSYNC();
    if (b == 0) finalize_stats<true>(sm, ps+10*PSL, iN16, fs+10*128);
    GSYNC();
    // L11 (FUSE)
    load_finals(sm, fs + 10*128, nullptr);
    conv_layer<32,32,16,16,1,true,false,false,0,0>(sm, a.f2, a.curB, a.curA, a.WT+WTOFF[11], a.f1, ps+11*PSL);
    GSYNC();
    if (b == 0) finalize_stats<true>(sm, ps+11*PSL, iN16, fs+11*128);
    GSYNC();
    // L12
    load_finals(sm, fs + 11*128, nullptr);
    conv_layer<32,32,16,16,1,false,false,false,0,0>(sm, a.f1, nullptr, nullptr, a.WT+WTOFF[12], a.f2, ps+12*PSL);
    GSYNC();
    if (b == 0) finalize_stats<true>(sm, ps+12*PSL, iN16, fs+12*128);
    GSYNC();
    // L13 (FUSE, stride2)
    load_finals(sm, fs + 12*128, nullptr);
    conv_layer<32,64,16,16,2,true,false,false,0,0>(sm, a.f2, a.curA, a.curB, a.WT+WTOFF[13], a.f1, ps+13*PSL);
    GSYNC();
    if (b == 0) finalize_stats<true>(sm, ps+13*PSL, iN8, fs+13*128);
    GSYNC();
    // L14
    load_finals(sm, fs + 13*128, nullptr);
    conv_layer<64,64,8,8,1,false,false,false,0,0>(sm, a.f1, nullptr, nullptr, a.WT+WTOFF[14], a.f2, ps+14*PSL);
    GSYNC();
    if (b == 0) finalize_stats<true>(sm, ps+14*PSL, iN8, fs+14*128);
    GSYNC();
    // L15 (FUSE2)
    load_finals(sm, fs + 14*128, nullptr);
    conv_layer<64,64,8,8,1,false,false,true,32,16>(sm, a.f2, a.curB, a.curA, a.WT+WTOFF[15], a.f1, ps+15*PSL);
    GSYNC();
    if (b == 0) finalize_stats<true>(sm, ps+15*PSL, iN8, fs+15*128);
    GSYNC();
    // L16
    load_finals(sm, fs + 15*128, nullptr);
    conv_layer<64,64,8,8,1,false,false,false,0,0>(sm, a.f1, nullptr, nullptr, a.WT+WTOFF[16], a.f2, ps+16*PSL);
    GSYNC();
    if (b == 0) finalize_stats<true>(sm, ps+16*PSL, iN8, fs+16*128);
    GSYNC();
    // L17 (FUSE)
    load_finals(sm, fs + 16*128, nullptr);
    conv_layer<64,64,8,8,1,true,false,false,0,0>(sm, a.f2, a.curA, a.curB, a.WT+WTOFF[17], a.f1, ps+17*PSL);
    GSYNC();
    if (b == 0) finalize_stats<true>(sm, ps+17*PSL, iN8, fs+17*128);
    GSYNC();
    // L18
    load_finals(sm, fs + 17*128, nullptr);
    conv_layer<64,64,8,8,1,false,false,false,0,0>(sm, a.f1, nullptr, nullptr, a.WT+WTOFF[18], a.f2, ps+18*PSL);
    GSYNC();
    if (b == 0) finalize_stats<true>(sm, ps+18*PSL, iN8, fs+18*128);
    GSYNC();

    // ---- pool + FC: bn_add(finals 18) + resid(curB), 256 threads ----
    {
        load_finals(sm, fs + 18*128, nullptr);
        const int c = tid & 63, pq = tid >> 6;
        const float m = sm.nm[c], rs = sm.nv[c];
        float s = 0.f;
        #pragma unroll
        for (int p = pq*16; p < pq*16 + 16; p++) {
            size_t idx = ((size_t)b*64 + p)*64 + c;
            float xv = bf2f((unsigned int)a.f2[idx]);
            float rv = bf2f((unsigned int)a.curB[idx]);
            s += fmaxf((xv - m)*rs + rv, 0.f);
        }
        __syncthreads();
        sm.statred[pq*64 + c] = s;
        __syncthreads();
        if (tid < 64) {
            float f = (sm.statred[tid] + sm.statred[64+tid]
                     + sm.statred[128+tid] + sm.statred[192+tid]) * (1.f/64.f);
            sm.pm_s[tid] = f;   // feat
        }
        __syncthreads();
        if (tid < 10) {
            if (ld_coh_i(a.flag) == 1) {
                const __hip_bfloat16* W  = (const __hip_bfloat16*)a.Wfc;
                const __hip_bfloat16* bb = (const __hip_bfloat16*)a.bfc;
                float o = ldf(bb + tid);
                for (int k = 0; k < 64; k++)
                    o += sm.pm_s[k] * ldf(W + tid*64 + k);
                ((__hip_bfloat16*)a.out)[b*10 + tid] = __float2bfloat16(o);
            } else {
                const float* W  = (const float*)a.Wfc;
                const float* bb = (const float*)a.bfc;
                float o = bb[tid];
                for (int k = 0; k < 64; k++)
                    o += sm.pm_s[k] * W[tid*64 + k];
                ((float*)a.out)[b*10 + tid] = o;
            }
        }
    }
    #undef GSYNC
}

extern "C" void kernel_launch(void* const* d_in, const int* in_sizes, int n_in,
                              void* d_out, int out_size, void* d_ws, size_t ws_size,
                              hipStream_t stream)
{
    char* ws = (char*)d_ws;
    float* wflat = (float*)(ws);                            // DTOT fp32
    int*   flag  = (int*)  (ws + 1146880);
    unsigned short* WT = (unsigned short*)(ws + 1179648);   // 269312 bf16
    unsigned short* curA = (unsigned short*)(ws + 1720320);               // 33.5MB
    unsigned short* curB = (unsigned short*)(ws + 1720320 + 33554432ULL); // 33.5MB (l0 raw)
    unsigned short* f1   = (unsigned short*)(ws + 1720320 + 67108864ULL);
    unsigned short* f2   = (unsigned short*)(ws + 1720320 + 100663296ULL);
    float* ps    = (float*)(ws + 135938048ULL);  // 19 x [64][128] fp32 partial stats
    float* fs    = (float*)(ws + 136560640ULL);  // 19 x 128 fp32 finals

    hipMemsetAsync(ps, 0, NLAYER*PSL*4, stream);
    detect_kernel<<<1, 256, 0, stream>>>((const unsigned short*)d_in[0], flag);

    wflat_kernel<__hip_bfloat16><<<(DTOT+255)/256, 256, 0, stream>>>(
        (const __hip_bfloat16*)d_in[1], (const __hip_bfloat16*)d_in[2],
        (const __hip_bfloat16*)d_in[3], wflat, DTOT, flag, 1);
    wflat_kernel<float><<<(DTOT+255)/256, 256, 0, stream>>>(
        (const float*)d_in[1], (const float*)d_in[2],
        (const float*)d_in[3], wflat, DTOT, flag, 0);

    {
        dim3 g(3, 64, 19);
        wprep_kernel<<<g, 192, 0, stream>>>(wflat, WT);
    }

    static const int WTOFF[NLAYER] = {0,0,2560,5120,7680,10240,12800,15360,20480,29696,
        38912,48128,57344,66560,84992,121856,158720,195584,232448};
    const float iN32 = 1.f/1048576.f;
    const float iN16 = 1.f/262144.f;
    const float iN8  = 1.f/65536.f;

    // ---- layer 0 (stats fused into epilogue) ----
    conv_l0<__hip_bfloat16><<<2*BATCH,512,0,stream>>>(
        (const __hip_bfloat16*)d_in[0], wflat, curB, ps, flag, 1);
    conv_l0<float><<<2*BATCH,512,0,stream>>>(
        (const float*)d_in[0], wflat, curB, ps, flag, 0);

    // ---- try cooperative mega kernel; fall back to multi-dispatch on error ----
    MegaArgs ma;
    ma.curA = curA; ma.curB = curB; ma.f1 = f1; ma.f2 = f2;
    ma.WT = WT; ma.ps = ps; ma.fs = fs;
    ma.Wfc = d_in[4]; ma.bfc = d_in[5];
    ma.out = d_out; ma.flag = flag;
    void* kargs[] = { &ma };
    hipError_t ce = hipLaunchCooperativeKernel((void*)mega_kernel, dim3(BATCH), dim3(256),
                                               kargs, 0, stream);
    if (ce != hipSuccess) {
        (void)hipGetLastError();   // clear sticky error, use proven r4 path
        conv_mfma_k<16,16,32,32,1,false,false,false,0,0><<<BATCH,256,0,stream>>>(
            curB, nullptr, nullptr, WT + WTOFF[1], f1, ps + 1*PSL, ps, iN32, nullptr, 0.f);
        conv_mfma_k<16,16,32,32,1,false,false,false,0,0><<<BATCH,256,0,stream>>>(
            f1, nullptr, nullptr, WT + WTOFF[2], f2, ps + 2*PSL, ps + 1*PSL, iN32, nullptr, 0.f);
        conv_mfma_k<16,16,32,32,1,true,true,false,0,0><<<BATCH,256,0,stream>>>(
            f2, curB, curA, WT + WTOFF[3], f1, ps + 3*PSL, ps + 2*PSL, iN32, ps, iN32);
        conv_mfma_k<16,16,32,32,1,false,false,false,0,0><<<BATCH,256,0,stream>>>(
            f1, nullptr, nullptr, WT + WTOFF[4], f2, ps + 4*PSL, ps + 3*PSL, iN32, nullptr, 0.f);
        conv_mfma_k<16,16,32,32,1,true,false,false,0,0><<<BATCH,256,0,stream>>>(
            f2, curA, curB, WT + WTOFF[5], f1, ps + 5*PSL, ps + 4*PSL, iN32, nullptr, 0.f);
        conv_mfma_k<16,16,32,32,1,false,false,false,0,0><<<BATCH,256,0,stream>>>(
            f1, nullptr, nullptr, WT + WTOFF[6], f2, ps + 6*PSL, ps + 5*PSL, iN32, nullptr, 0.f);
        conv_mfma_k<16,32,32,32,2,true,false,false,0,0><<<BATCH,256,0,stream>>>(
            f2, curB, curA, WT + WTOFF[7], f1, ps + 7*PSL, ps + 6*PSL, iN32, nullptr, 0.f);
        conv_mfma_k<32,32,16,16,1,false,false,false,0,0><<<BATCH,256,0,stream>>>(
            f1, nullptr, nullptr, WT + WTOFF[8], f2, ps + 8*PSL, ps + 7*PSL, iN16, nullptr, 0.f);
        conv_mfma_k<32,32,16,16,1,false,false,true,16,8><<<BATCH,256,0,stream>>>(
            f2, curA, curB, WT + WTOFF[9], f1, ps + 9*PSL, ps + 8*PSL, iN16, nullptr, 0.f);
        conv_mfma_k<32,32,16,16,1,false,false,false,0,0><<<BATCH,256,0,stream>>>(
            f1, nullptr, nullptr, WT + WTOFF[10], f2, ps + 10*PSL, ps + 9*PSL, iN16, nullptr, 0.f);
        conv_mfma_k<32,32,16,16,1,true,false,false,0,0><<<BATCH,256,0,stream>>>(
            f2, curB, curA, WT + WTOFF[11], f1, ps + 11*PSL, ps + 10*PSL, iN16, nullptr, 0.f);
        conv_mfma_k<32,32,16,16,1,false,false,false,0,0><<<BATCH,256,0,stream>>>(
            f1, nullptr, nullptr, WT + WTOFF[12], f2, ps + 12*PSL, ps + 11*PSL, iN16, nullptr, 0.f);
        conv_mfma_k<32,64,16,16,2,true,false,false,0,0><<<BATCH,256,0,stream>>>(
            f2, curA, curB, WT + WTOFF[13], f1, ps + 13*PSL, ps + 12*PSL, iN16, nullptr, 0.f);
        conv_mfma_k<64,64,8,8,1,false,false,false,0,0><<<BATCH,256,0,stream>>>(
            f1, nullptr, nullptr, WT + WTOFF[14], f2, ps + 14*PSL, ps + 13*PSL, iN8, nullptr, 0.f);
        conv_mfma_k<64,64,8,8,1,false,false,true,32,16><<<BATCH,256,0,stream>>>(
            f2, curB, curA, WT + WTOFF[15], f1, ps + 15*PSL, ps + 14*PSL, iN8, nullptr, 0.f);
        conv_mfma_k<64,64,8,8,1,false,false,false,0,0><<<BATCH,256,0,stream>>>(
            f1, nullptr, nullptr, WT + WTOFF[16], f2, ps + 16*PSL, ps + 15*PSL, iN8, nullptr, 0.f);
        conv_mfma_k<64,64,8,8,1,true,false,false,0,0><<<BATCH,256,0,stream>>>(
            f2, curA, curB, WT + WTOFF[17], f1, ps + 17*PSL, ps + 16*PSL, iN8, nullptr, 0.f);
        conv_mfma_k<64,64,8,8,1,false,false,false,0,0><<<BATCH,256,0,stream>>>(
            f1, nullptr, nullptr, WT + WTOFF[18], f2, ps + 18*PSL, ps + 17*PSL, iN8, nullptr, 0.f);

        poolfc_kernel<__hip_bfloat16><<<BATCH, 64, 0, stream>>>(
            f2, curB, ps + 18*PSL, iN8,
            (const __hip_bfloat16*)d_in[4], (const __hip_bfloat16*)d_in[5],
            (__hip_bfloat16*)d_out, flag, 1);
        poolfc_kernel<float><<<BATCH, 64, 0, stream>>>(
            f2, curB, ps + 18*PSL, iN8,
            (const float*)d_in[4], (const float*)d_in[5],
            (float*)d_out, flag, 0);
    }
}

// Round 9
// 4165.241 us; speedup vs baseline: 1.8201x; 1.8201x over previous
//
#include <hip/hip_runtime.h>
#include <hip/hip_bf16.h>
#include <hip/hip_cooperative_groups.h>

namespace cg = cooperative_groups;

#define BATCH 1024
#define NLAYER 19
#define DTOT 267696
#define NSLOT 64
#define PSL (NSLOT*128)   // floats per layer partial-stats region

typedef __attribute__((ext_vector_type(8))) short v8s;
typedef __attribute__((ext_vector_type(4))) float v4f;

__device__ inline float ldf(const float* p){ return *p; }
__device__ inline float ldf(const __hip_bfloat16* p){ return __bfloat162float(*p); }

__device__ inline unsigned short f2bf(float x){
    __hip_bfloat16 h = __float2bfloat16(x);
    return *reinterpret_cast<unsigned short*>(&h);
}
__device__ inline float bf2f(unsigned int u){
    return __uint_as_float(u << 16);
}
// agent-scope coherent ops (bypass non-coherent per-XCD L2 path)
__device__ inline float ld_coh(const float* p){
    return __hip_atomic_load(p, __ATOMIC_RELAXED, __HIP_MEMORY_SCOPE_AGENT);
}
__device__ inline void st_coh(float* p, float v){
    __hip_atomic_store(p, v, __ATOMIC_RELAXED, __HIP_MEMORY_SCOPE_AGENT);
}
__device__ inline int ld_coh_i(const int* p){
    return __hip_atomic_load(p, __ATOMIC_RELAXED, __HIP_MEMORY_SCOPE_AGENT);
}

// ---- dtype detector: flag=1 if inputs bf16, 0 if f32 ----
__global__ void detect_kernel(const unsigned short* __restrict__ xraw, int* __restrict__ flag)
{
    __shared__ int bad;
    if (threadIdx.x == 0) bad = 0;
    __syncthreads();
    int lbad = 0;
    for (int i = threadIdx.x; i < 4096; i += 256) {
        unsigned e = (xraw[i] >> 7) & 0xFF;
        if (e >= 147) lbad++;
    }
    if (lbad) atomicAdd(&bad, lbad);
    __syncthreads();
    if (threadIdx.x == 0) *flag = (bad == 0) ? 1 : 0;
}

__device__ inline bool flag_skip(const int* flag, int want)
{
    if (flag == nullptr) return false;
    return (*(volatile const int*)flag) != want;
}

// w_flat = origin + new_param @ P
template<typename T>
__global__ void wflat_kernel(const T* __restrict__ origin,
                             const T* __restrict__ P,
                             const T* __restrict__ npar,
                             float* __restrict__ wout, int D,
                             const int* flag, int want)
{
    if (flag_skip(flag, want)) return;
    int d = blockIdx.x*256 + threadIdx.x;
    if (d >= D) return;
    float acc = ldf(origin + d);
    #pragma unroll 8
    for (int k = 0; k < 40; k++)
        acc += ldf(npar + k) * ldf(P + (long long)k*D + d);
    wout[d] = acc;
}

// ---- weight transform: wflat (OIHW fp32) -> W_T[l][cout][kpad] bf16 ----
__global__ void wprep_kernel(const float* __restrict__ wflat, unsigned short* __restrict__ WT)
{
    static const int CINA[19]  = {3,16,16,16,16,16,16,16,32,32,32,32,32,32,64,64,64,64,64};
    static const int COUTA[19] = {16,16,16,16,16,16,16,32,32,32,32,32,32,64,64,64,64,64,64};
    static const int LGCA[19]  = {0,4,4,4,4,4,4,4,5,5,5,5,5,5,6,6,6,6,6};
    static const int KPADA[19] = {0,160,160,160,160,160,160,160,288,288,288,288,288,288,576,576,576,576,576};
    static const int WOFFA[19] = {0,432,2736,5040,7344,9648,11952,14256,18864,
        28080,37296,46512,55728,64944,83376,120240,157104,193968,230832};
    static const int WTOFFA[19]= {0,0,2560,5120,7680,10240,12800,15360,20480,29696,
        38912,48128,57344,66560,84992,121856,158720,195584,232448};
    int l = blockIdx.z;
    if (l == 0) return;
    int co = blockIdx.y;
    if (co >= COUTA[l]) return;
    int kp = blockIdx.x*192 + threadIdx.x;
    if (kp >= KPADA[l]) return;
    int cin = CINA[l];
    float v = 0.f;
    if (kp < 9*cin) {
        int tap = kp >> LGCA[l];
        int ci  = kp & (cin - 1);
        v = wflat[WOFFA[l] + (co*cin + ci)*9 + tap];
    }
    WT[WTOFFA[l] + co*KPADA[l] + kp] = f2bf(v);
}

__device__ inline void ldpair(const float* base, int p, float& x0, float& x1){
    const float2 v = ((const float2*)base)[p];
    x0 = v.x; x1 = v.y;
}
__device__ inline void ldpair(const __hip_bfloat16* base, int p, float& x0, float& x1){
    unsigned u = ((const unsigned int*)base)[p];
    x0 = __uint_as_float(u << 16);
    x1 = __uint_as_float(u & 0xffff0000u);
}

// ---- layer 0: direct conv (Cin=3), NCHW input -> NHWC bf16 raw ----
template<typename T>
__global__ __launch_bounds__(512) void conv_l0(
    const T* __restrict__ in, const float* __restrict__ wt,
    unsigned short* __restrict__ out, float* __restrict__ ps,
    const int* flag, int want)
{
    if (flag_skip(flag, want)) return;
    constexpr int WP = 38, W2 = 19;
    __shared__ uint2 smem2[2048];
    __shared__ unsigned int in_su[3*18*W2];
    __shared__ float sred[8][32];

    const int tid  = threadIdx.x;
    const int b    = blockIdx.x >> 1;
    const int half = blockIdx.x & 1;
    const int row0 = half*16 - 1;

    {
        const T* inb = in + (size_t)b*3072;
        for (int i = tid; i < 864; i += 512) {
            int w2 = i & 15, lr = (i >> 4) % 18, c = i / 288;
            int ih = row0 + lr;
            unsigned int pk = 0u;
            if ((unsigned)ih < 32u) {
                float x0, x1;
                ldpair(inb, (c*32 + ih)*16 + w2, x0, x1);
                pk = (unsigned int)f2bf(x0) | ((unsigned int)f2bf(x1) << 16);
            }
            in_su[(c*18 + lr)*W2 + 1 + w2] = pk;
        }
        unsigned short* in_ss = (unsigned short*)in_su;
        for (int i = tid; i < 54; i += 512) {
            in_ss[i*WP + 1]  = 0;
            in_ss[i*WP + 34] = 0;
        }
    }
    __syncthreads();

    const int r   = tid >> 5;
    const int col = tid & 31;
    const bool odd = (col & 1);

    float xin[27];
    #pragma unroll
    for (int ci = 0; ci < 3; ci++) {
        #pragma unroll
        for (int kh = 0; kh < 3; kh++) {
            const unsigned int* up = in_su + (ci*18 + r + kh)*W2 + ((col+1) >> 1);
            unsigned int u0 = up[0], u1 = up[1];
            const int kb = ci*9 + kh*3;
            xin[kb+0] = odd ? bf2f(u0 & 0xffffu) : bf2f(u0 >> 16);
            xin[kb+1] = odd ? bf2f(u0 >> 16)     : bf2f(u1 & 0xffffu);
            xin[kb+2] = odd ? bf2f(u1 & 0xffffu) : bf2f(u1 >> 16);
        }
    }

    float acc[16];
    #pragma unroll
    for (int co = 0; co < 16; co++) {
        float a = 0.f;
        #pragma unroll
        for (int k = 0; k < 27; k++)
            a += xin[k] * wt[co*27 + k];   // uniform addr -> SGPR weight
        acc[co] = a;
    }

    #pragma unroll
    for (int j = 0; j < 4; j++) {
        uint2 v;
        v.x = (unsigned)f2bf(acc[4*j+0]) | ((unsigned)f2bf(acc[4*j+1]) << 16);
        v.y = (unsigned)f2bf(acc[4*j+2]) | ((unsigned)f2bf(acc[4*j+3]) << 16);
        smem2[tid*4 + (j ^ (tid & 3))] = v;
    }
    __syncthreads();

    float s4[4] = {0,0,0,0}, q4[4] = {0,0,0,0};
    {
        uint2* ob = (uint2*)(out + (size_t)b*16384 + half*8192);
        #pragma unroll
        for (int it = 0; it < 4; it++) {
            int s = it*512 + tid;
            int phys = (s & ~3) | ((s & 3) ^ ((s >> 2) & 3));
            uint2 v = smem2[phys];
            ob[s] = v;
            float f0 = bf2f(v.x & 0xffffu), f1v = bf2f(v.x >> 16);
            float f2v = bf2f(v.y & 0xffffu), f3v = bf2f(v.y >> 16);
            s4[0] += f0;  q4[0] += f0*f0;
            s4[1] += f1v; q4[1] += f1v*f1v;
            s4[2] += f2v; q4[2] += f2v*f2v;
            s4[3] += f3v; q4[3] += f3v*f3v;
        }
    }
    #pragma unroll
    for (int off = 4; off < 64; off <<= 1) {
        #pragma unroll
        for (int k2 = 0; k2 < 4; k2++) {
            s4[k2] += __shfl_xor(s4[k2], off);
            q4[k2] += __shfl_xor(q4[k2], off);
        }
    }
    {
        const int lane = tid & 63, wv = tid >> 6;
        if (lane < 4) {
            #pragma unroll
            for (int k2 = 0; k2 < 4; k2++) {
                sred[wv][lane*4 + k2]      = s4[k2];
                sred[wv][16 + lane*4 + k2] = q4[k2];
            }
        }
    }
    __syncthreads();
    if (tid < 32) {
        float a = 0.f;
        #pragma unroll
        for (int wv = 0; wv < 8; wv++) a += sred[wv][tid];
        float* sl = ps + (blockIdx.x & (NSLOT-1))*128;
        atomicAdd(&sl[(tid < 16) ? tid : (48 + tid)], a);
    }
}

// ---- shared-memory layout reused across all conv layers + pool phase ----
struct SM {
    unsigned short in_s[16*32*32];   // input, then output bounce
    float red[128];
    float statred[256];
    float nm[64], nv[64];
    float pm_s[64], pv_s[64];
    uint4 zq;
};

// per-block cached reduce of pre-kernel partials (dispatch boundary made
// them coherent): ps0 -> sm.nm/nv. Normal loads, L2/L3-cached, 32KB shared.
__device__ void prologue_stats(SM& sm, const float* __restrict__ psL, float invN)
{
    const int tid = threadIdx.x;
    {
        const int idx = tid & 127, hf = tid >> 7;
        float sacc = 0.f;
        #pragma unroll 8
        for (int k = hf*32; k < hf*32 + 32; k++)
            sacc += psL[k*128 + idx];
        sm.statred[tid] = sacc;
    }
    __syncthreads();
    if (tid < 64) {
        float ssum = sm.statred[tid]      + sm.statred[128 + tid];
        float qsum = sm.statred[64 + tid] + sm.statred[192 + tid];
        float m = ssum*invN;
        float v = fmaxf(qsum*invN - m*m, 0.f);
        sm.nm[tid] = m; sm.nv[tid] = rsqrtf(v + 1e-5f);
    }
    __syncthreads();
}

// ---- lightweight generation barrier, NO cache-flushing fence ----
// Only the 128-float stats cross blocks (via agent-scope atomics/loads);
// activations are strictly per-block (own L2), so no L2 writeback needed.
// Last block to arrive finalizes layer stats (psL -> fsL) then releases.
// (r6/r8 lesson: grid.sync()+threadfence = ~200us each, full L2 flush,
//  565MB of activation refetch. This barrier avoids the flush entirely.)
__device__ void barrier_finalize(SM& sm, int* cnt, int* gen,
                                 const float* __restrict__ psL, float invN,
                                 float* __restrict__ fsL)
{
    __shared__ int role;
    __syncthreads();   // drains this block's stats atomics (vmcnt 0)
    if (threadIdx.x == 0) {
        int g = __hip_atomic_load(gen, __ATOMIC_RELAXED, __HIP_MEMORY_SCOPE_AGENT);
        int arrived = __hip_atomic_fetch_add(cnt, 1, __ATOMIC_ACQ_REL,
                                             __HIP_MEMORY_SCOPE_AGENT) + 1;
        if (arrived == BATCH) {
            role = 1;
        } else {
            role = 0;
            while (__hip_atomic_load(gen, __ATOMIC_ACQUIRE,
                                     __HIP_MEMORY_SCOPE_AGENT) == g)
                __builtin_amdgcn_s_sleep(2);
        }
    }
    __syncthreads();
    if (role) {
        const int tid = threadIdx.x;
        if (tid < 128) {
            float s = 0.f;
            #pragma unroll 8
            for (int k = 0; k < NSLOT; k++)
                s += ld_coh(&psL[k*128 + tid]);
            sm.statred[tid] = s;
        }
        __syncthreads();
        if (tid < 64) {
            float m = sm.statred[tid]*invN;
            float v = fmaxf(sm.statred[64 + tid]*invN - m*m, 0.f);
            st_coh(&fsL[tid],      m);
            st_coh(&fsL[64 + tid], rsqrtf(v + 1e-5f));
        }
        __syncthreads();
        if (tid == 0) {
            __hip_atomic_store(cnt, 0, __ATOMIC_RELAXED, __HIP_MEMORY_SCOPE_AGENT);
            __hip_atomic_fetch_add(gen, 1, __ATOMIC_RELEASE,
                                   __HIP_MEMORY_SCOPE_AGENT);
        }
    }
}

// all blocks: read 512B of finals -> sm.nm/nv
__device__ inline void load_finals(SM& sm, const float* __restrict__ fsL)
{
    const int tid = threadIdx.x;
    if (tid < 64) {
        sm.nm[tid] = ld_coh(&fsL[tid]);
        sm.nv[tid] = ld_coh(&fsL[64 + tid]);
    }
    __syncthreads();
}

// ---- one MFMA implicit-GEMM 3x3 conv layer, BODY ONLY (r4-proven code) ----
// Caller must populate sm.nm/nv (and pm_s/pv_s if PN) and __syncthreads.
template<int CIN, int COUT, int HIN, int WIN, int ST, bool FUSE, bool PN,
         bool FUSE2, int PREVC, int PADF>
__device__ void conv_layer(SM& sm,
    const unsigned short* __restrict__ src, const unsigned short* __restrict__ prev,
    unsigned short* __restrict__ resid,
    const unsigned short* __restrict__ wt,
    unsigned short* __restrict__ out, float* __restrict__ stats)
{
    constexpr int HO = HIN/ST, WO = WIN/ST, M = HO*WO, MT = M/16;
    constexpr int NT = COUT/16;
    constexpr int K  = 9*CIN;
    constexpr int S  = (K + 31)/32;
    constexpr int KPAD = S*32;
    constexpr int lgC  = (CIN==16)?4:(CIN==32)?5:6;
    constexpr int lgWI = (WIN==32)?5:(WIN==16)?4:3;
    constexpr int lgWO = (WO==32)?5:(WO==16)?4:3;
    constexpr int CMASK = CIN/8 - 1;
    constexpr int JITER = (NT==1)? MT/4 : (NT==2)? MT/2 : MT;
    static_assert(M*COUT <= CIN*HIN*WIN, "out_s fits in in_s");
    static_assert(CIN*HIN*WIN <= 16*32*32, "fits SM.in_s");

    unsigned short* in_s = sm.in_s;
    const int tid = threadIdx.x;
    const int b   = blockIdx.x;

    // ---- staging ----
    {
        const uint4* sb4 = (const uint4*)(src + (size_t)b*(HIN*WIN)*CIN);
        constexpr int NP4 = CIN*HIN*WIN/8;
        if (FUSE) {
            const uint4* pb4 = (const uint4*)(prev + (size_t)b*(HIN*WIN)*CIN);
            uint4* rb4 = (uint4*)(resid + (size_t)b*(HIN*WIN)*CIN);
            for (int i = tid; i < NP4; i += 256) {
                uint4 v = sb4[i];
                uint4 pw = pb4[i];
                int e0 = i << 3;
                int c0 = e0 & (CIN-1);
                int p  = e0 >> lgC;
                float f[8] = { bf2f(v.x & 0xffffu), bf2f(v.x >> 16),
                               bf2f(v.y & 0xffffu), bf2f(v.y >> 16),
                               bf2f(v.z & 0xffffu), bf2f(v.z >> 16),
                               bf2f(v.w & 0xffffu), bf2f(v.w >> 16) };
                float g[8] = { bf2f(pw.x & 0xffffu), bf2f(pw.x >> 16),
                               bf2f(pw.y & 0xffffu), bf2f(pw.y >> 16),
                               bf2f(pw.z & 0xffffu), bf2f(pw.z >> 16),
                               bf2f(pw.w & 0xffffu), bf2f(pw.w >> 16) };
                #pragma unroll
                for (int k = 0; k < 8; k++) {
                    int c = c0 + k;
                    float fx = (f[k] - sm.nm[c])*sm.nv[c];
                    float gv = g[k];
                    if (PN) gv = fmaxf((gv - sm.pm_s[c])*sm.pv_s[c], 0.f);
                    f[k] = fmaxf(fx + gv, 0.f);
                }
                uint4 o;
                o.x = (unsigned)f2bf(f[0]) | ((unsigned)f2bf(f[1]) << 16);
                o.y = (unsigned)f2bf(f[2]) | ((unsigned)f2bf(f[3]) << 16);
                o.z = (unsigned)f2bf(f[4]) | ((unsigned)f2bf(f[5]) << 16);
                o.w = (unsigned)f2bf(f[6]) | ((unsigned)f2bf(f[7]) << 16);
                rb4[i] = o;
                int csw = c0 ^ ((p & CMASK) << 3);
                *(uint4*)(in_s + (p << lgC) + csw) = o;
            }
        } else if (FUSE2) {
            uint4* rb4 = (uint4*)(resid + (size_t)b*(HIN*WIN)*CIN);
            for (int i = tid; i < NP4; i += 256) {
                uint4 v = sb4[i];
                int e0 = i << 3;
                int c0 = e0 & (CIN-1);
                int p  = e0 >> lgC;
                int h  = p >> lgWI, wq = p & (WIN-1);
                int pp = (h << (lgWI+2)) + 2*wq;
                int pc0 = c0 - PADF;
                bool pv = (pc0 >= 0) && (pc0 <= PREVC - 8);
                uint4 pw;
                pw.x = 0; pw.y = 0; pw.z = 0; pw.w = 0;
                if (pv) pw = *(const uint4*)(prev + ((size_t)b*(HIN*WIN*4) + pp)*PREVC + pc0);
                float f[8] = { bf2f(v.x & 0xffffu), bf2f(v.x >> 16),
                               bf2f(v.y & 0xffffu), bf2f(v.y >> 16),
                               bf2f(v.z & 0xffffu), bf2f(v.z >> 16),
                               bf2f(v.w & 0xffffu), bf2f(v.w >> 16) };
                float g[8] = { bf2f(pw.x & 0xffffu), bf2f(pw.x >> 16),
                               bf2f(pw.y & 0xffffu), bf2f(pw.y >> 16),
                               bf2f(pw.z & 0xffffu), bf2f(pw.z >> 16),
                               bf2f(pw.w & 0xffffu), bf2f(pw.w >> 16) };
                #pragma unroll
                for (int k = 0; k < 8; k++) {
                    int c = c0 + k;
                    f[k] = fmaxf((f[k] - sm.nm[c])*sm.nv[c] + g[k], 0.f);
                }
                uint4 o;
                o.x = (unsigned)f2bf(f[0]) | ((unsigned)f2bf(f[1]) << 16);
                o.y = (unsigned)f2bf(f[2]) | ((unsigned)f2bf(f[3]) << 16);
                o.z = (unsigned)f2bf(f[4]) | ((unsigned)f2bf(f[5]) << 16);
                o.w = (unsigned)f2bf(f[6]) | ((unsigned)f2bf(f[7]) << 16);
                rb4[i] = o;
                int csw = c0 ^ ((p & CMASK) << 3);
                *(uint4*)(in_s + (p << lgC) + csw) = o;
            }
        } else {
            for (int i = tid; i < NP4; i += 256) {
                uint4 v = sb4[i];
                int e0 = i << 3;
                int c0 = e0 & (CIN-1);
                int p  = e0 >> lgC;
                float f[8] = { bf2f(v.x & 0xffffu), bf2f(v.x >> 16),
                               bf2f(v.y & 0xffffu), bf2f(v.y >> 16),
                               bf2f(v.z & 0xffffu), bf2f(v.z >> 16),
                               bf2f(v.w & 0xffffu), bf2f(v.w >> 16) };
                #pragma unroll
                for (int k = 0; k < 8; k++) {
                    int c = c0 + k;
                    f[k] = fmaxf((f[k] - sm.nm[c])*sm.nv[c], 0.f);
                }
                uint4 o;
                o.x = (unsigned)f2bf(f[0]) | ((unsigned)f2bf(f[1]) << 16);
                o.y = (unsigned)f2bf(f[2]) | ((unsigned)f2bf(f[3]) << 16);
                o.z = (unsigned)f2bf(f[4]) | ((unsigned)f2bf(f[5]) << 16);
                o.w = (unsigned)f2bf(f[6]) | ((unsigned)f2bf(f[7]) << 16);
                int csw = c0 ^ ((p & CMASK) << 3);
                *(uint4*)(in_s + (p << lgC) + csw) = o;
            }
        }
    }
    __syncthreads();

    const int w   = tid >> 6;
    const int ln  = tid & 63;
    const int l15 = ln & 15;
    const int q   = ln >> 4;

    int n0, mt0, step;
    if (NT == 1)      { n0 = 0;         mt0 = w;      step = 4; }
    else if (NT == 2) { n0 = (w&1)*16;  mt0 = w>>1;   step = 2; }
    else              { n0 = w*16;      mt0 = 0;      step = 1; }

    const unsigned short* wb = wt + (size_t)(n0 + l15)*KPAD + q*8;
    const int c0q = (CIN==16) ? ((q & 1) << 3) : (q << 3);

    v4f acc[JITER];
    #pragma unroll
    for (int j = 0; j < JITER; j++) acc[j] = v4f{0.f,0.f,0.f,0.f};

    if constexpr (CIN == 64) {
        #pragma unroll
        for (int s = 0; s < S; s++) {
            const v8s Bf = *(const v8s*)(wb + 32*s);
            const int tap = s >> 1;
            const int dh1 = tap/3 - 1, dw1 = tap%3 - 1;
            const int c0s = c0q + ((s & 1) << 5);
            #pragma unroll
            for (int j = 0; j < JITER; j++) {
                const int mt  = mt0 + j*step;
                const int p   = mt*16 + l15;
                const int ihb = (p >> lgWO) * ST;
                const int iwb = (p & (WO-1)) * ST;
                int ih = ihb + dh1, iw = iwb + dw1;
                bool valid = ((unsigned)ih < (unsigned)HIN) && ((unsigned)iw < (unsigned)WIN);
                int pp  = (ih << lgWI) + iw;
                int csw = c0s ^ ((pp & CMASK) << 3);
                int eoff = (pp << lgC) + csw;
                const v8s* ap = valid ? (const v8s*)(in_s + eoff) : (const v8s*)&sm.zq;
                v8s Af = *ap;
                acc[j] = __builtin_amdgcn_mfma_f32_16x16x32_bf16(Af, Bf, acc[j], 0, 0, 0);
            }
        }
    } else {
        v8s Bf[S];
        #pragma unroll
        for (int s = 0; s < S; s++)
            Bf[s] = *(const v8s*)(wb + 32*s);

        int dh1s[S], dw1s[S];
        if (CIN == 16) {
            int tq = q >> 1;
            #pragma unroll
            for (int s = 0; s < S; s++) {
                int tap = 2*s + tq;
                int dh = (tap*11) >> 5;
                int dw = tap - 3*dh;
                dh1s[s] = (tap >= 9) ? -1000 : (dh - 1);
                dw1s[s] = dw - 1;
            }
        }

        #pragma unroll
        for (int j = 0; j < JITER; j++) {
            const int mt  = mt0 + j*step;
            const int p   = mt*16 + l15;
            const int ihb = (p >> lgWO) * ST;
            const int iwb = (p & (WO-1)) * ST;
            #pragma unroll
            for (int s = 0; s < S; s++) {
                int dh1, dw1;
                if (CIN == 16) { dh1 = dh1s[s]; dw1 = dw1s[s]; }
                else           { dh1 = s/3 - 1; dw1 = s%3 - 1; }
                int ih = ihb + dh1, iw = iwb + dw1;
                bool valid = ((unsigned)ih < (unsigned)HIN) && ((unsigned)iw < (unsigned)WIN);
                int pp  = (ih << lgWI) + iw;
                int csw = c0q ^ ((pp & CMASK) << 3);
                int eoff = (pp << lgC) + csw;
                const v8s* ap = valid ? (const v8s*)(in_s + eoff) : (const v8s*)&sm.zq;
                v8s Af = *ap;
                acc[j] = __builtin_amdgcn_mfma_f32_16x16x32_bf16(Af, Bf[s], acc[j], 0, 0, 0);
            }
        }
    }
    __syncthreads();   // all in_s reads complete -> reuse as output bounce

    unsigned short* out_s = in_s;
    float sa = 0.f, qa = 0.f;
    #pragma unroll
    for (int j = 0; j < JITER; j++) {
        const int mt = mt0 + j*step;
        #pragma unroll
        for (int r2 = 0; r2 < 4; r2++) {
            float v = acc[j][r2];
            out_s[(mt*16 + q*4 + r2)*COUT + n0 + l15] = f2bf(v);
            sa += v; qa += v*v;
        }
    }
    __syncthreads();

    {
        constexpr int NIT = (M*COUT/8)/256;
        uint4* ob4 = (uint4*)(out + (size_t)b*M*COUT);
        const uint4* os4 = (const uint4*)in_s;
        #pragma unroll
        for (int it = 0; it < NIT; it++)
            ob4[it*256 + tid] = os4[it*256 + tid];
    }

    sa += __shfl_xor(sa, 16); sa += __shfl_xor(sa, 32);
    qa += __shfl_xor(qa, 16); qa += __shfl_xor(qa, 32);
    if (q == 0) {
        sm.red[(w*16 + l15)*2]     = sa;
        sm.red[(w*16 + l15)*2 + 1] = qa;
    }
    __syncthreads();
    if (tid < COUT) {
        float S2, Q2;
        if (NT == 1) {
            S2 = sm.red[tid*2] + sm.red[(16+tid)*2] + sm.red[(32+tid)*2] + sm.red[(48+tid)*2];
            Q2 = sm.red[tid*2+1] + sm.red[(16+tid)*2+1] + sm.red[(32+tid)*2+1] + sm.red[(48+tid)*2+1];
        } else if (NT == 2) {
            int w0 = tid >> 4, cl = tid & 15;
            S2 = sm.red[((w0*16)+cl)*2]     + sm.red[(((w0+2)*16)+cl)*2];
            Q2 = sm.red[((w0*16)+cl)*2 + 1] + sm.red[(((w0+2)*16)+cl)*2 + 1];
        } else {
            int w0 = tid >> 4, cl = tid & 15;
            S2 = sm.red[((w0*16)+cl)*2];
            Q2 = sm.red[((w0*16)+cl)*2 + 1];
        }
        float* sl = stats + (b & (NSLOT-1))*128;
        atomicAdd(&sl[tid],      S2);
        atomicAdd(&sl[64 + tid], Q2);
    }
}

// ---- standalone wrapper (fallback multi-dispatch path; r4 math exactly) ----
template<int CIN, int COUT, int HIN, int WIN, int ST, bool FUSE, bool PN,
         bool FUSE2, int PREVC, int PADF>
__global__ __launch_bounds__(256, 4) void conv_mfma_k(
    const unsigned short* __restrict__ src, const unsigned short* __restrict__ prev,
    unsigned short* __restrict__ resid,
    const unsigned short* __restrict__ wt,
    unsigned short* __restrict__ out, float* __restrict__ stats,
    const float* __restrict__ nstats, float ninvN,
    const float* __restrict__ pstats, float pinvN)
{
    __shared__ SM sm;
    const int tid = threadIdx.x;
    if (tid == 0) { sm.zq.x = 0; sm.zq.y = 0; sm.zq.z = 0; sm.zq.w = 0; }
    {
        const int idx = tid & 127, hf = tid >> 7;
        float sacc = 0.f;
        #pragma unroll 8
        for (int k = hf*32; k < hf*32 + 32; k++)
            sacc += nstats[k*128 + idx];
        sm.statred[tid] = sacc;
    }
    __syncthreads();
    if (tid < CIN) {
        float ssum = sm.statred[tid]      + sm.statred[128 + tid];
        float qsum = sm.statred[64 + tid] + sm.statred[192 + tid];
        float m = ssum*ninvN;
        float v = fmaxf(qsum*ninvN - m*m, 0.f);
        sm.nm[tid] = m; sm.nv[tid] = rsqrtf(v + 1e-5f);
    }
    if (PN && tid < CIN) {
        float ssum = 0.f, qsum = 0.f;
        for (int k = 0; k < NSLOT; k++) {
            ssum += pstats[k*128 + tid];
            qsum += pstats[k*128 + 64 + tid];
        }
        float m = ssum*pinvN;
        float v = fmaxf(qsum*pinvN - m*m, 0.f);
        sm.pm_s[tid] = m; sm.pv_s[tid] = rsqrtf(v + 1e-5f);
    }
    __syncthreads();
    conv_layer<CIN,COUT,HIN,WIN,ST,FUSE,PN,FUSE2,PREVC,PADF>(
        sm, src, prev, resid, wt, out, stats);
}

__device__ inline void stf(float* p, float v){ *p = v; }
__device__ inline void stf(__hip_bfloat16* p, float v){ *p = __float2bfloat16(v); }

// fallback pool+fc (r4)
template<typename T>
__global__ void poolfc_kernel(const unsigned short* __restrict__ x,
    const unsigned short* __restrict__ resid,
    const float* __restrict__ stats, float invN,
    const T* __restrict__ Wfc, const T* __restrict__ bfc,
    T* __restrict__ out, const int* flag, int want)
{
    if (flag_skip(flag, want)) return;
    int b = blockIdx.x;
    int c = threadIdx.x; // 64 threads
    float ssum = 0.f, qsum = 0.f;
    for (int k = 0; k < NSLOT; k++) {
        ssum += stats[k*128 + c];
        qsum += stats[k*128 + 64 + c];
    }
    float m = ssum*invN;
    float v = fmaxf(qsum*invN - m*m, 0.f);
    float rs = rsqrtf(v + 1e-5f);
    float s = 0.f;
    #pragma unroll
    for (int p = 0; p < 64; p++) {
        size_t idx = ((size_t)b*64 + p)*64 + c;
        float xv = bf2f((unsigned int)x[idx]);
        float rv = bf2f((unsigned int)resid[idx]);
        s += fmaxf((xv - m)*rs + rv, 0.f);
    }
    __shared__ float feat[64];
    feat[c] = s * (1.f/64.f);
    __syncthreads();
    if (c < 10) {
        float o = ldf(bfc + c);
        for (int k = 0; k < 64; k++)
            o += feat[k] * ldf(Wfc + c*64 + k);
        stf(out + b*10 + c, o);
    }
}

struct MegaArgs {
    unsigned short* curA;
    unsigned short* curB;
    unsigned short* f1;
    unsigned short* f2;
    const unsigned short* WT;
    float* ps;
    float* fs;        // 19 x 128 finals {m[64], rs[64]}
    int* bar;         // [0]=cnt, [1]=gen
    const void* Wfc;
    const void* bfc;
    void* out;
    const int* flag;
};

// ---- cooperative mega kernel: layers 1..18 + pool/FC, light barriers ----
// Cooperative launch is used ONLY for the co-residency guarantee (spin
// barrier cannot deadlock); sync itself is the fence-free barrier above.
__global__ __launch_bounds__(256, 4) void mega_kernel(MegaArgs a)
{
    __shared__ SM sm;
    const int tid = threadIdx.x;
    const int b   = blockIdx.x;

    if (tid == 0) { sm.zq.x = 0; sm.zq.y = 0; sm.zq.z = 0; sm.zq.w = 0; }

    constexpr float iN32 = 1.f/1048576.f;
    constexpr float iN16 = 1.f/262144.f;
    constexpr float iN8  = 1.f/65536.f;
    static const int WTOFF[NLAYER] = {0,0,2560,5120,7680,10240,12800,15360,20480,29696,
        38912,48128,57344,66560,84992,121856,158720,195584,232448};
    float* ps = a.ps;
    float* fs = a.fs;
    int* cnt = a.bar;
    int* gen = a.bar + 1;

    // L3's PN stats (= layer-0 stats): pre-kernel data, normal cached loads.
    // pm_s/pv_s untouched until the pool phase.
    if (tid < 16) {
        float ssum = 0.f, qsum = 0.f;
        for (int k = 0; k < NSLOT; k++) {
            ssum += ps[k*128 + tid];
            qsum += ps[k*128 + 64 + tid];
        }
        float m = ssum*iN32;
        float v = fmaxf(qsum*iN32 - m*m, 0.f);
        sm.pm_s[tid] = m; sm.pv_s[tid] = rsqrtf(v + 1e-5f);
    }
    // layer-0 finals for L1's consumer (normal cached loads; 32KB shared)
    prologue_stats(sm, ps, iN32);

    // L1
    conv_layer<16,16,32,32,1,false,false,false,0,0>(sm, a.curB, nullptr, nullptr, a.WT+WTOFF[1], a.f1, ps+1*PSL);
    barrier_finalize(sm, cnt, gen, ps+1*PSL, iN32, fs+1*128);
    load_finals(sm, fs+1*128);
    // L2
    conv_layer<16,16,32,32,1,false,false,false,0,0>(sm, a.f1, nullptr, nullptr, a.WT+WTOFF[2], a.f2, ps+2*PSL);
    barrier_finalize(sm, cnt, gen, ps+2*PSL, iN32, fs+2*128);
    load_finals(sm, fs+2*128);
    // L3 (FUSE + PN via precomputed pm_s/pv_s)
    conv_layer<16,16,32,32,1,true,true,false,0,0>(sm, a.f2, a.curB, a.curA, a.WT+WTOFF[3], a.f1, ps+3*PSL);
    barrier_finalize(sm, cnt, gen, ps+3*PSL, iN32, fs+3*128);
    load_finals(sm, fs+3*128);
    // L4
    conv_layer<16,16,32,32,1,false,false,false,0,0>(sm, a.f1, nullptr, nullptr, a.WT+WTOFF[4], a.f2, ps+4*PSL);
    barrier_finalize(sm, cnt, gen, ps+4*PSL, iN32, fs+4*128);
    load_finals(sm, fs+4*128);
    // L5 (FUSE)
    conv_layer<16,16,32,32,1,true,false,false,0,0>(sm, a.f2, a.curA, a.curB, a.WT+WTOFF[5], a.f1, ps+5*PSL);
    barrier_finalize(sm, cnt, gen, ps+5*PSL, iN32, fs+5*128);
    load_finals(sm, fs+5*128);
    // L6
    conv_layer<16,16,32,32,1,false,false,false,0,0>(sm, a.f1, nullptr, nullptr, a.WT+WTOFF[6], a.f2, ps+6*PSL);
    barrier_finalize(sm, cnt, gen, ps+6*PSL, iN32, fs+6*128);
    load_finals(sm, fs+6*128);
    // L7 (FUSE, stride2)
    conv_layer<16,32,32,32,2,true,false,false,0,0>(sm, a.f2, a.curB, a.curA, a.WT+WTOFF[7], a.f1, ps+7*PSL);
    barrier_finalize(sm, cnt, gen, ps+7*PSL, iN16, fs+7*128);
    load_finals(sm, fs+7*128);
    // L8
    conv_layer<32,32,16,16,1,false,false,false,0,0>(sm, a.f1, nullptr, nullptr, a.WT+WTOFF[8], a.f2, ps+8*PSL);
    barrier_finalize(sm, cnt, gen, ps+8*PSL, iN16, fs+8*128);
    load_finals(sm, fs+8*128);
    // L9 (FUSE2)
    conv_layer<32,32,16,16,1,false,false,true,16,8>(sm, a.f2, a.curA, a.curB, a.WT+WTOFF[9], a.f1, ps+9*PSL);
    barrier_finalize(sm, cnt, gen, ps+9*PSL, iN16, fs+9*128);
    load_finals(sm, fs+9*128);
    // L10
    conv_layer<32,32,16,16,1,false,false,false,0,0>(sm, a.f1, nullptr, nullptr, a.WT+WTOFF[10], a.f2, ps+10*PSL);
    barrier_finalize(sm, cnt, gen, ps+10*PSL, iN16, fs+10*128);
    load_finals(sm, fs+10*128);
    // L11 (FUSE)
    conv_layer<32,32,16,16,1,true,false,false,0,0>(sm, a.f2, a.curB, a.curA, a.WT+WTOFF[11], a.f1, ps+11*PSL);
    barrier_finalize(sm, cnt, gen, ps+11*PSL, iN16, fs+11*128);
    load_finals(sm, fs+11*128);
    // L12
    conv_layer<32,32,16,16,1,false,false,false,0,0>(sm, a.f1, nullptr, nullptr, a.WT+WTOFF[12], a.f2, ps+12*PSL);
    barrier_finalize(sm, cnt, gen, ps+12*PSL, iN16, fs+12*128);
    load_finals(sm, fs+12*128);
    // L13 (FUSE, stride2)
    conv_layer<32,64,16,16,2,true,false,false,0,0>(sm, a.f2, a.curA, a.curB, a.WT+WTOFF[13], a.f1, ps+13*PSL);
    barrier_finalize(sm, cnt, gen, ps+13*PSL, iN8, fs+13*128);
    load_finals(sm, fs+13*128);
    // L14
    conv_layer<64,64,8,8,1,false,false,false,0,0>(sm, a.f1, nullptr, nullptr, a.WT+WTOFF[14], a.f2, ps+14*PSL);
    barrier_finalize(sm, cnt, gen, ps+14*PSL, iN8, fs+14*128);
    load_finals(sm, fs+14*128);
    // L15 (FUSE2)
    conv_layer<64,64,8,8,1,false,false,true,32,16>(sm, a.f2, a.curB, a.curA, a.WT+WTOFF[15], a.f1, ps+15*PSL);
    barrier_finalize(sm, cnt, gen, ps+15*PSL, iN8, fs+15*128);
    load_finals(sm, fs+15*128);
    // L16
    conv_layer<64,64,8,8,1,false,false,false,0,0>(sm, a.f1, nullptr, nullptr, a.WT+WTOFF[16], a.f2, ps+16*PSL);
    barrier_finalize(sm, cnt, gen, ps+16*PSL, iN8, fs+16*128);
    load_finals(sm, fs+16*128);
    // L17 (FUSE)
    conv_layer<64,64,8,8,1,true,false,false,0,0>(sm, a.f2, a.curA, a.curB, a.WT+WTOFF[17], a.f1, ps+17*PSL);
    barrier_finalize(sm, cnt, gen, ps+17*PSL, iN8, fs+17*128);
    load_finals(sm, fs+17*128);
    // L18
    conv_layer<64,64,8,8,1,false,false,false,0,0>(sm, a.f1, nullptr, nullptr, a.WT+WTOFF[18], a.f2, ps+18*PSL);
    barrier_finalize(sm, cnt, gen, ps+18*PSL, iN8, fs+18*128);
    load_finals(sm, fs+18*128);

    // ---- pool + FC: bn_add(finals 18) + resid(curB), 256 threads ----
    {
        const int c = tid & 63, pq = tid >> 6;
        const float m = sm.nm[c], rs = sm.nv[c];
        float s = 0.f;
        #pragma unroll
        for (int p = pq*16; p < pq*16 + 16; p++) {
            size_t idx = ((size_t)b*64 + p)*64 + c;
            float xv = bf2f((unsigned int)a.f2[idx]);
            float rv = bf2f((unsigned int)a.curB[idx]);
            s += fmaxf((xv - m)*rs + rv, 0.f);
        }
        __syncthreads();
        sm.statred[pq*64 + c] = s;
        __syncthreads();
        if (tid < 64) {
            float f = (sm.statred[tid] + sm.statred[64+tid]
                     + sm.statred[128+tid] + sm.statred[192+tid]) * (1.f/64.f);
            sm.pm_s[tid] = f;   // feat
        }
        __syncthreads();
        if (tid < 10) {
            if (ld_coh_i(a.flag) == 1) {
                const __hip_bfloat16* W  = (const __hip_bfloat16*)a.Wfc;
                const __hip_bfloat16* bb = (const __hip_bfloat16*)a.bfc;
                float o = ldf(bb + tid);
                for (int k = 0; k < 64; k++)
                    o += sm.pm_s[k] * ldf(W + tid*64 + k);
                ((__hip_bfloat16*)a.out)[b*10 + tid] = __float2bfloat16(o);
            } else {
                const float* W  = (const float*)a.Wfc;
                const float* bb = (const float*)a.bfc;
                float o = bb[tid];
                for (int k = 0; k < 64; k++)
                    o += sm.pm_s[k] * W[tid*64 + k];
                ((float*)a.out)[b*10 + tid] = o;
            }
        }
    }
}

extern "C" void kernel_launch(void* const* d_in, const int* in_sizes, int n_in,
                              void* d_out, int out_size, void* d_ws, size_t ws_size,
                              hipStream_t stream)
{
    char* ws = (char*)d_ws;
    float* wflat = (float*)(ws);                            // DTOT fp32
    int*   flag  = (int*)  (ws + 1146880);
    unsigned short* WT = (unsigned short*)(ws + 1179648);   // 269312 bf16
    unsigned short* curA = (unsigned short*)(ws + 1720320);               // 33.5MB
    unsigned short* curB = (unsigned short*)(ws + 1720320 + 33554432ULL); // 33.5MB (l0 raw)
    unsigned short* f1   = (unsigned short*)(ws + 1720320 + 67108864ULL);
    unsigned short* f2   = (unsigned short*)(ws + 1720320 + 100663296ULL);
    float* ps    = (float*)(ws + 135938048ULL);  // 19 x [64][128] fp32 partial stats
    float* fs    = (float*)(ws + 136560640ULL);  // 19 x 128 fp32 finals
    int*   bar   = (int*)  (ws + 136570368ULL);  // [cnt, gen]

    hipMemsetAsync(ps, 0, 632576, stream);   // ps + fs + bar
    detect_kernel<<<1, 256, 0, stream>>>((const unsigned short*)d_in[0], flag);

    wflat_kernel<__hip_bfloat16><<<(DTOT+255)/256, 256, 0, stream>>>(
        (const __hip_bfloat16*)d_in[1], (const __hip_bfloat16*)d_in[2],
        (const __hip_bfloat16*)d_in[3], wflat, DTOT, flag, 1);
    wflat_kernel<float><<<(DTOT+255)/256, 256, 0, stream>>>(
        (const float*)d_in[1], (const float*)d_in[2],
        (const float*)d_in[3], wflat, DTOT, flag, 0);

    {
        dim3 g(3, 64, 19);
        wprep_kernel<<<g, 192, 0, stream>>>(wflat, WT);
    }

    static const int WTOFF[NLAYER] = {0,0,2560,5120,7680,10240,12800,15360,20480,29696,
        38912,48128,57344,66560,84992,121856,158720,195584,232448};
    const float iN32 = 1.f/1048576.f;
    const float iN16 = 1.f/262144.f;
    const float iN8  = 1.f/65536.f;

    // ---- layer 0 (stats fused into epilogue) ----
    conv_l0<__hip_bfloat16><<<2*BATCH,512,0,stream>>>(
        (const __hip_bfloat16*)d_in[0], wflat, curB, ps, flag, 1);
    conv_l0<float><<<2*BATCH,512,0,stream>>>(
        (const float*)d_in[0], wflat, curB, ps, flag, 0);

    // ---- try cooperative mega kernel; fall back to multi-dispatch on error ----
    MegaArgs ma;
    ma.curA = curA; ma.curB = curB; ma.f1 = f1; ma.f2 = f2;
    ma.WT = WT; ma.ps = ps; ma.fs = fs; ma.bar = bar;
    ma.Wfc = d_in[4]; ma.bfc = d_in[5];
    ma.out = d_out; ma.flag = flag;
    void* kargs[] = { &ma };
    hipError_t ce = hipLaunchCooperativeKernel((void*)mega_kernel, dim3(BATCH), dim3(256),
                                               kargs, 0, stream);
    if (ce != hipSuccess) {
        (void)hipGetLastError();   // clear sticky error, use proven r4 path
        conv_mfma_k<16,16,32,32,1,false,false,false,0,0><<<BATCH,256,0,stream>>>(
            curB, nullptr, nullptr, WT + WTOFF[1], f1, ps + 1*PSL, ps, iN32, nullptr, 0.f);
        conv_mfma_k<16,16,32,32,1,false,false,false,0,0><<<BATCH,256,0,stream>>>(
            f1, nullptr, nullptr, WT + WTOFF[2], f2, ps + 2*PSL, ps + 1*PSL, iN32, nullptr, 0.f);
        conv_mfma_k<16,16,32,32,1,true,true,false,0,0><<<BATCH,256,0,stream>>>(
            f2, curB, curA, WT + WTOFF[3], f1, ps + 3*PSL, ps + 2*PSL, iN32, ps, iN32);
        conv_mfma_k<16,16,32,32,1,false,false,false,0,0><<<BATCH,256,0,stream>>>(
            f1, nullptr, nullptr, WT + WTOFF[4], f2, ps + 4*PSL, ps + 3*PSL, iN32, nullptr, 0.f);
        conv_mfma_k<16,16,32,32,1,true,false,false,0,0><<<BATCH,256,0,stream>>>(
            f2, curA, curB, WT + WTOFF[5], f1, ps + 5*PSL, ps + 4*PSL, iN32, nullptr, 0.f);
        conv_mfma_k<16,16,32,32,1,false,false,false,0,0><<<BATCH,256,0,stream>>>(
            f1, nullptr, nullptr, WT + WTOFF[6], f2, ps + 6*PSL, ps + 5*PSL, iN32, nullptr, 0.f);
        conv_mfma_k<16,32,32,32,2,true,false,false,0,0><<<BATCH,256,0,stream>>>(
            f2, curB, curA, WT + WTOFF[7], f1, ps + 7*PSL, ps + 6*PSL, iN32, nullptr, 0.f);
        conv_mfma_k<32,32,16,16,1,false,false,false,0,0><<<BATCH,256,0,stream>>>(
            f1, nullptr, nullptr, WT + WTOFF[8], f2, ps + 8*PSL, ps + 7*PSL, iN16, nullptr, 0.f);
        conv_mfma_k<32,32,16,16,1,false,false,true,16,8><<<BATCH,256,0,stream>>>(
            f2, curA, curB, WT + WTOFF[9], f1, ps + 9*PSL, ps + 8*PSL, iN16, nullptr, 0.f);
        conv_mfma_k<32,32,16,16,1,false,false,false,0,0><<<BATCH,256,0,stream>>>(
            f1, nullptr, nullptr, WT + WTOFF[10], f2, ps + 10*PSL, ps + 9*PSL, iN16, nullptr, 0.f);
        conv_mfma_k<32,32,16,16,1,true,false,false,0,0><<<BATCH,256,0,stream>>>(
            f2, curB, curA, WT + WTOFF[11], f1, ps + 11*PSL, ps + 10*PSL, iN16, nullptr, 0.f);
        conv_mfma_k<32,32,16,16,1,false,false,false,0,0><<<BATCH,256,0,stream>>>(
            f1, nullptr, nullptr, WT + WTOFF[12], f2, ps + 12*PSL, ps + 11*PSL, iN16, nullptr, 0.f);
        conv_mfma_k<32,64,16,16,2,true,false,false,0,0><<<BATCH,256,0,stream>>>(
            f2, curA, curB, WT + WTOFF[13], f1, ps + 13*PSL, ps + 12*PSL, iN16, nullptr, 0.f);
        conv_mfma_k<64,64,8,8,1,false,false,false,0,0><<<BATCH,256,0,stream>>>(
            f1, nullptr, nullptr, WT + WTOFF[14], f2, ps + 14*PSL, ps + 13*PSL, iN8, nullptr, 0.f);
        conv_mfma_k<64,64,8,8,1,false,false,true,32,16><<<BATCH,256,0,stream>>>(
            f2, curB, curA, WT + WTOFF[15], f1, ps + 15*PSL, ps + 14*PSL, iN8, nullptr, 0.f);
        conv_mfma_k<64,64,8,8,1,false,false,false,0,0><<<BATCH,256,0,stream>>>(
            f1, nullptr, nullptr, WT + WTOFF[16], f2, ps + 16*PSL, ps + 15*PSL, iN8, nullptr, 0.f);
        conv_mfma_k<64,64,8,8,1,true,false,false,0,0><<<BATCH,256,0,stream>>>(
            f2, curA, curB, WT + WTOFF[17], f1, ps + 17*PSL, ps + 16*PSL, iN8, nullptr, 0.f);
        conv_mfma_k<64,64,8,8,1,false,false,false,0,0><<<BATCH,256,0,stream>>>(
            f1, nullptr, nullptr, WT + WTOFF[18], f2, ps + 18*PSL, ps + 17*PSL, iN8, nullptr, 0.f);

        poolfc_kernel<__hip_bfloat16><<<BATCH, 64, 0, stream>>>(
            f2, curB, ps + 18*PSL, iN8,
            (const __hip_bfloat16*)d_in[4], (const __hip_bfloat16*)d_in[5],
            (__hip_bfloat16*)d_out, flag, 1);
        poolfc_kernel<float><<<BATCH, 64, 0, stream>>>(
            f2, curB, ps + 18*PSL, iN8,
            (const float*)d_in[4], (const float*)d_in[5],
            (float*)d_out, flag, 0);
    }
}

// Round 12
// 459.203 us; speedup vs baseline: 16.5096x; 9.0706x over previous
//
#include <hip/hip_runtime.h>
#include <hip/hip_bf16.h>

#define BATCH 1024
#define NLAYER 19
#define DTOT 267696
#define NSLOT 64
#define PSL (NSLOT*128)   // floats per layer partial-stats region

typedef __attribute__((ext_vector_type(8))) short v8s;
typedef __attribute__((ext_vector_type(4))) float v4f;

__device__ inline float ldf(const float* p){ return *p; }
__device__ inline float ldf(const __hip_bfloat16* p){ return __bfloat162float(*p); }

__device__ inline unsigned short f2bf(float x){
    __hip_bfloat16 h = __float2bfloat16(x);
    return *reinterpret_cast<unsigned short*>(&h);
}
__device__ inline float bf2f(unsigned int u){
    return __uint_as_float(u << 16);
}

// ---- dtype detector: flag=1 if inputs bf16, 0 if f32 ----
__global__ void detect_kernel(const unsigned short* __restrict__ xraw, int* __restrict__ flag)
{
    __shared__ int bad;
    if (threadIdx.x == 0) bad = 0;
    __syncthreads();
    int lbad = 0;
    for (int i = threadIdx.x; i < 4096; i += 256) {
        unsigned e = (xraw[i] >> 7) & 0xFF;
        if (e >= 147) lbad++;
    }
    if (lbad) atomicAdd(&bad, lbad);
    __syncthreads();
    if (threadIdx.x == 0) *flag = (bad == 0) ? 1 : 0;
}

__device__ inline bool is_bf16(const int* flag)
{
    return (*(volatile const int*)flag) == 1;
}

// w_flat = origin + new_param @ P  (runtime dtype branch; uniform)
__global__ void wflat_kernel(const void* __restrict__ origin,
                             const void* __restrict__ P,
                             const void* __restrict__ npar,
                             float* __restrict__ wout, int D,
                             const int* flag)
{
    int d = blockIdx.x*256 + threadIdx.x;
    if (d >= D) return;
    float acc;
    if (is_bf16(flag)) {
        const __hip_bfloat16* ob = (const __hip_bfloat16*)origin;
        const __hip_bfloat16* Pb = (const __hip_bfloat16*)P;
        const __hip_bfloat16* nb = (const __hip_bfloat16*)npar;
        acc = ldf(ob + d);
        #pragma unroll 8
        for (int k = 0; k < 40; k++)
            acc += ldf(nb + k) * ldf(Pb + (long long)k*D + d);
    } else {
        const float* of = (const float*)origin;
        const float* Pf = (const float*)P;
        const float* nf = (const float*)npar;
        acc = of[d];
        #pragma unroll 8
        for (int k = 0; k < 40; k++)
            acc += nf[k] * Pf[(long long)k*D + d];
    }
    wout[d] = acc;
}

// ---- weight transform: wflat (OIHW fp32) -> W_T[l][cout][kpad] bf16 ----
__global__ void wprep_kernel(const float* __restrict__ wflat, unsigned short* __restrict__ WT)
{
    static const int CINA[19]  = {3,16,16,16,16,16,16,16,32,32,32,32,32,32,64,64,64,64,64};
    static const int COUTA[19] = {16,16,16,16,16,16,16,32,32,32,32,32,32,64,64,64,64,64,64};
    static const int LGCA[19]  = {0,4,4,4,4,4,4,4,5,5,5,5,5,5,6,6,6,6,6};
    static const int KPADA[19] = {0,160,160,160,160,160,160,160,288,288,288,288,288,288,576,576,576,576,576};
    static const int WOFFA[19] = {0,432,2736,5040,7344,9648,11952,14256,18864,
        28080,37296,46512,55728,64944,83376,120240,157104,193968,230832};
    static const int WTOFFA[19]= {0,0,2560,5120,7680,10240,12800,15360,20480,29696,
        38912,48128,57344,66560,84992,121856,158720,195584,232448};
    int l = blockIdx.z;
    if (l == 0) return;
    int co = blockIdx.y;
    if (co >= COUTA[l]) return;
    int kp = blockIdx.x*192 + threadIdx.x;
    if (kp >= KPADA[l]) return;
    int cin = CINA[l];
    float v = 0.f;
    if (kp < 9*cin) {
        int tap = kp >> LGCA[l];
        int ci  = kp & (cin - 1);
        v = wflat[WOFFA[l] + (co*cin + ci)*9 + tap];
    }
    WT[WTOFFA[l] + co*KPADA[l] + kp] = f2bf(v);
}

__device__ inline void ldpair_f(const float* base, int p, float& x0, float& x1){
    const float2 v = ((const float2*)base)[p];
    x0 = v.x; x1 = v.y;
}
__device__ inline void ldpair_h(const __hip_bfloat16* base, int p, float& x0, float& x1){
    unsigned u = ((const unsigned int*)base)[p];
    x0 = __uint_as_float(u << 16);
    x1 = __uint_as_float(u & 0xffff0000u);
}

// ---- layer 0: direct conv (Cin=3), NCHW input -> NHWC bf16 raw ----
// Weights via wave-uniform compile-time-offset loads -> SGPRs.
// Epilogue fuses per-channel sum/sumsq stats (no separate stats pass).
// Runtime dtype branch confined to the staging loop (uniform).
__global__ __launch_bounds__(512) void conv_l0(
    const void* __restrict__ in, const float* __restrict__ wt,
    unsigned short* __restrict__ out, float* __restrict__ ps,
    const int* flag)
{
    constexpr int WP = 38, W2 = 19;
    __shared__ uint2 smem2[2048];
    __shared__ unsigned int in_su[3*18*W2];
    __shared__ float sred[8][32];

    const int tid  = threadIdx.x;
    const int b    = blockIdx.x >> 1;
    const int half = blockIdx.x & 1;
    const int row0 = half*16 - 1;
    const bool isbf = is_bf16(flag);

    {
        const __hip_bfloat16* inb_h = (const __hip_bfloat16*)in + (size_t)b*3072;
        const float*          inb_f = (const float*)in + (size_t)b*3072;
        for (int i = tid; i < 864; i += 512) {
            int w2 = i & 15, lr = (i >> 4) % 18, c = i / 288;
            int ih = row0 + lr;
            unsigned int pk = 0u;
            if ((unsigned)ih < 32u) {
                float x0, x1;
                if (isbf) ldpair_h(inb_h, (c*32 + ih)*16 + w2, x0, x1);
                else      ldpair_f(inb_f, (c*32 + ih)*16 + w2, x0, x1);
                pk = (unsigned int)f2bf(x0) | ((unsigned int)f2bf(x1) << 16);
            }
            in_su[(c*18 + lr)*W2 + 1 + w2] = pk;
        }
        unsigned short* in_ss = (unsigned short*)in_su;
        for (int i = tid; i < 54; i += 512) {
            in_ss[i*WP + 1]  = 0;
            in_ss[i*WP + 34] = 0;
        }
    }
    __syncthreads();

    const int r   = tid >> 5;
    const int col = tid & 31;
    const bool odd = (col & 1);

    // hoist the 3x3x3 input neighborhood into VGPRs (18 ds_read_b32)
    float xin[27];
    #pragma unroll
    for (int ci = 0; ci < 3; ci++) {
        #pragma unroll
        for (int kh = 0; kh < 3; kh++) {
            const unsigned int* up = in_su + (ci*18 + r + kh)*W2 + ((col+1) >> 1);
            unsigned int u0 = up[0], u1 = up[1];
            const int kb = ci*9 + kh*3;
            xin[kb+0] = odd ? bf2f(u0 & 0xffffu) : bf2f(u0 >> 16);
            xin[kb+1] = odd ? bf2f(u0 >> 16)     : bf2f(u1 & 0xffffu);
            xin[kb+2] = odd ? bf2f(u1 & 0xffffu) : bf2f(u1 >> 16);
        }
    }

    float acc[16];
    #pragma unroll
    for (int co = 0; co < 16; co++) {
        float a = 0.f;
        #pragma unroll
        for (int k = 0; k < 27; k++)
            a += xin[k] * wt[co*27 + k];   // uniform addr -> SGPR weight
        acc[co] = a;
    }

    #pragma unroll
    for (int j = 0; j < 4; j++) {
        uint2 v;
        v.x = (unsigned)f2bf(acc[4*j+0]) | ((unsigned)f2bf(acc[4*j+1]) << 16);
        v.y = (unsigned)f2bf(acc[4*j+2]) | ((unsigned)f2bf(acc[4*j+3]) << 16);
        smem2[tid*4 + (j ^ (tid & 3))] = v;
    }
    __syncthreads();

    // ---- output bounce + fused per-channel stats ----
    float s4[4] = {0,0,0,0}, q4[4] = {0,0,0,0};
    {
        uint2* ob = (uint2*)(out + (size_t)b*16384 + half*8192);
        #pragma unroll
        for (int it = 0; it < 4; it++) {
            int s = it*512 + tid;
            int phys = (s & ~3) | ((s & 3) ^ ((s >> 2) & 3));
            uint2 v = smem2[phys];
            ob[s] = v;
            float f0 = bf2f(v.x & 0xffffu), f1v = bf2f(v.x >> 16);
            float f2v = bf2f(v.y & 0xffffu), f3v = bf2f(v.y >> 16);
            s4[0] += f0;  q4[0] += f0*f0;
            s4[1] += f1v; q4[1] += f1v*f1v;
            s4[2] += f2v; q4[2] += f2v*f2v;
            s4[3] += f3v; q4[3] += f3v*f3v;
        }
    }
    // channel group k = tid&3 (channels 4k..4k+3); xor offsets >=4 preserve k
    #pragma unroll
    for (int off = 4; off < 64; off <<= 1) {
        #pragma unroll
        for (int k2 = 0; k2 < 4; k2++) {
            s4[k2] += __shfl_xor(s4[k2], off);
            q4[k2] += __shfl_xor(q4[k2], off);
        }
    }
    {
        const int lane = tid & 63, wv = tid >> 6;
        if (lane < 4) {
            #pragma unroll
            for (int k2 = 0; k2 < 4; k2++) {
                sred[wv][lane*4 + k2]      = s4[k2];
                sred[wv][16 + lane*4 + k2] = q4[k2];
            }
        }
    }
    __syncthreads();
    if (tid < 32) {
        float a = 0.f;
        #pragma unroll
        for (int wv = 0; wv < 8; wv++) a += sred[wv][tid];
        float* sl = ps + (blockIdx.x & (NSLOT-1))*128;
        atomicAdd(&sl[(tid < 16) ? tid : (48 + tid)], a);
    }
}

// ---- MFMA implicit-GEMM 3x3 conv, one block (4 waves) per image ----
// FUSE : staging performs preceding stride-1 bn_add (elementwise residual).
// FUSE2: staging performs preceding stride-2 bn_add (residual = 2x-res gather,
//        channel pad 8-aligned -> whole uint4 group valid or zero).
// Stats: 64-slot partial buffers [NSLOT][128]; producers atomicAdd into slot
// (b & 63); consumers reduce the 64 slots at kernel start (L2-hot 32KB read).
// Main loop: j-outer/s-inner with Bf[S] preload for CIN=16/32 (proven best);
// s-outer/j-inner for CIN=64 where Bf[18]=72 VGPRs would spill to scratch.
// (Mega-kernel fusion arc r5-r10: cross-XCD sync inside one kernel requires
//  ACQUIRE=L2-invalidate (~200us/barrier) or hangs with relaxed loads (stale
//  L2 line never refreshes) -> multi-dispatch is the correct structure.)
template<int CIN, int COUT, int HIN, int WIN, int ST, bool FUSE, bool PN,
         bool FUSE2, int PREVC, int PADF>
__global__ __launch_bounds__(256, 4) void conv_mfma(
    const unsigned short* __restrict__ src, const unsigned short* __restrict__ prev,
    unsigned short* __restrict__ resid,
    const unsigned short* __restrict__ wt,
    unsigned short* __restrict__ out, float* __restrict__ stats,
    const float* __restrict__ nstats, float ninvN,
    const float* __restrict__ pstats, float pinvN)
{
    constexpr int HO = HIN/ST, WO = WIN/ST, M = HO*WO, MT = M/16;
    constexpr int NT = COUT/16;
    constexpr int K  = 9*CIN;
    constexpr int S  = (K + 31)/32;
    constexpr int KPAD = S*32;
    constexpr int lgC  = (CIN==16)?4:(CIN==32)?5:6;
    constexpr int lgWI = (WIN==32)?5:(WIN==16)?4:3;
    constexpr int lgWO = (WO==32)?5:(WO==16)?4:3;
    constexpr int CMASK = CIN/8 - 1;
    constexpr int JITER = (NT==1)? MT/4 : (NT==2)? MT/2 : MT;
    static_assert(M*COUT <= CIN*HIN*WIN, "out_s fits in in_s");

    __shared__ unsigned short in_s[CIN*HIN*WIN];   // input, then output bounce
    __shared__ float red[128];
    __shared__ float statred[256];
    __shared__ float nm[64], nv[64];
    __shared__ float pm_s[64], pv_s[64];
    __shared__ uint4 zq;

    const int tid = threadIdx.x;
    const int b   = blockIdx.x;

    if (tid == 0) { zq.x = 0; zq.y = 0; zq.z = 0; zq.w = 0; }

    // ---- reduce 64-slot producer partials -> nm/nv (and pm/pv if PN) ----
    {
        const int idx = tid & 127, hf = tid >> 7;
        float sacc = 0.f;
        #pragma unroll 8
        for (int k = hf*32; k < hf*32 + 32; k++)
            sacc += nstats[k*128 + idx];
        statred[tid] = sacc;
    }
    __syncthreads();
    if (tid < CIN) {
        float ssum = statred[tid]      + statred[128 + tid];
        float qsum = statred[64 + tid] + statred[192 + tid];
        float m = ssum*ninvN;
        float v = fmaxf(qsum*ninvN - m*m, 0.f);
        nm[tid] = m; nv[tid] = rsqrtf(v + 1e-5f);
    }
    if (PN && tid < CIN) {
        float ssum = 0.f, qsum = 0.f;
        for (int k = 0; k < NSLOT; k++) {
            ssum += pstats[k*128 + tid];
            qsum += pstats[k*128 + 64 + tid];
        }
        float m = ssum*pinvN;
        float v = fmaxf(qsum*pinvN - m*m, 0.f);
        pm_s[tid] = m; pv_s[tid] = rsqrtf(v + 1e-5f);
    }
    __syncthreads();

    // ---- staging ----
    {
        const uint4* sb4 = (const uint4*)(src + (size_t)b*(HIN*WIN)*CIN);
        constexpr int NP4 = CIN*HIN*WIN/8;
        if (FUSE) {
            const uint4* pb4 = (const uint4*)(prev + (size_t)b*(HIN*WIN)*CIN);
            uint4* rb4 = (uint4*)(resid + (size_t)b*(HIN*WIN)*CIN);
            for (int i = tid; i < NP4; i += 256) {
                uint4 v = sb4[i];
                uint4 pw = pb4[i];
                int e0 = i << 3;
                int c0 = e0 & (CIN-1);
                int p  = e0 >> lgC;
                float f[8] = { bf2f(v.x & 0xffffu), bf2f(v.x >> 16),
                               bf2f(v.y & 0xffffu), bf2f(v.y >> 16),
                               bf2f(v.z & 0xffffu), bf2f(v.z >> 16),
                               bf2f(v.w & 0xffffu), bf2f(v.w >> 16) };
                float g[8] = { bf2f(pw.x & 0xffffu), bf2f(pw.x >> 16),
                               bf2f(pw.y & 0xffffu), bf2f(pw.y >> 16),
                               bf2f(pw.z & 0xffffu), bf2f(pw.z >> 16),
                               bf2f(pw.w & 0xffffu), bf2f(pw.w >> 16) };
                #pragma unroll
                for (int k = 0; k < 8; k++) {
                    int c = c0 + k;
                    float fx = (f[k] - nm[c])*nv[c];
                    float gv = g[k];
                    if (PN) gv = fmaxf((gv - pm_s[c])*pv_s[c], 0.f);
                    f[k] = fmaxf(fx + gv, 0.f);
                }
                uint4 o;
                o.x = (unsigned)f2bf(f[0]) | ((unsigned)f2bf(f[1]) << 16);
                o.y = (unsigned)f2bf(f[2]) | ((unsigned)f2bf(f[3]) << 16);
                o.z = (unsigned)f2bf(f[4]) | ((unsigned)f2bf(f[5]) << 16);
                o.w = (unsigned)f2bf(f[6]) | ((unsigned)f2bf(f[7]) << 16);
                rb4[i] = o;
                int csw = c0 ^ ((p & CMASK) << 3);
                *(uint4*)(in_s + (p << lgC) + csw) = o;
            }
        } else if (FUSE2) {
            // prev dims: (2*HIN)x(2*WIN)xPREVC; group valid iff pc0 in [0,PREVC-8]
            uint4* rb4 = (uint4*)(resid + (size_t)b*(HIN*WIN)*CIN);
            for (int i = tid; i < NP4; i += 256) {
                uint4 v = sb4[i];
                int e0 = i << 3;
                int c0 = e0 & (CIN-1);
                int p  = e0 >> lgC;
                int h  = p >> lgWI, wq = p & (WIN-1);
                int pp = (h << (lgWI+2)) + 2*wq;
                int pc0 = c0 - PADF;
                bool pv = (pc0 >= 0) && (pc0 <= PREVC - 8);
                uint4 pw;
                pw.x = 0; pw.y = 0; pw.z = 0; pw.w = 0;
                if (pv) pw = *(const uint4*)(prev + ((size_t)b*(HIN*WIN*4) + pp)*PREVC + pc0);
                float f[8] = { bf2f(v.x & 0xffffu), bf2f(v.x >> 16),
                               bf2f(v.y & 0xffffu), bf2f(v.y >> 16),
                               bf2f(v.z & 0xffffu), bf2f(v.z >> 16),
                               bf2f(v.w & 0xffffu), bf2f(v.w >> 16) };
                float g[8] = { bf2f(pw.x & 0xffffu), bf2f(pw.x >> 16),
                               bf2f(pw.y & 0xffffu), bf2f(pw.y >> 16),
                               bf2f(pw.z & 0xffffu), bf2f(pw.z >> 16),
                               bf2f(pw.w & 0xffffu), bf2f(pw.w >> 16) };
                #pragma unroll
                for (int k = 0; k < 8; k++) {
                    int c = c0 + k;
                    f[k] = fmaxf((f[k] - nm[c])*nv[c] + g[k], 0.f);
                }
                uint4 o;
                o.x = (unsigned)f2bf(f[0]) | ((unsigned)f2bf(f[1]) << 16);
                o.y = (unsigned)f2bf(f[2]) | ((unsigned)f2bf(f[3]) << 16);
                o.z = (unsigned)f2bf(f[4]) | ((unsigned)f2bf(f[5]) << 16);
                o.w = (unsigned)f2bf(f[6]) | ((unsigned)f2bf(f[7]) << 16);
                rb4[i] = o;
                int csw = c0 ^ ((p & CMASK) << 3);
                *(uint4*)(in_s + (p << lgC) + csw) = o;
            }
        } else {
            for (int i = tid; i < NP4; i += 256) {
                uint4 v = sb4[i];
                int e0 = i << 3;
                int c0 = e0 & (CIN-1);
                int p  = e0 >> lgC;
                float f[8] = { bf2f(v.x & 0xffffu), bf2f(v.x >> 16),
                               bf2f(v.y & 0xffffu), bf2f(v.y >> 16),
                               bf2f(v.z & 0xffffu), bf2f(v.z >> 16),
                               bf2f(v.w & 0xffffu), bf2f(v.w >> 16) };
                #pragma unroll
                for (int k = 0; k < 8; k++) {
                    int c = c0 + k;
                    f[k] = fmaxf((f[k] - nm[c])*nv[c], 0.f);
                }
                uint4 o;
                o.x = (unsigned)f2bf(f[0]) | ((unsigned)f2bf(f[1]) << 16);
                o.y = (unsigned)f2bf(f[2]) | ((unsigned)f2bf(f[3]) << 16);
                o.z = (unsigned)f2bf(f[4]) | ((unsigned)f2bf(f[5]) << 16);
                o.w = (unsigned)f2bf(f[6]) | ((unsigned)f2bf(f[7]) << 16);
                int csw = c0 ^ ((p & CMASK) << 3);
                *(uint4*)(in_s + (p << lgC) + csw) = o;
            }
        }
    }
    __syncthreads();

    const int w   = tid >> 6;
    const int ln  = tid & 63;
    const int l15 = ln & 15;
    const int q   = ln >> 4;

    int n0, mt0, step;
    if (NT == 1)      { n0 = 0;         mt0 = w;      step = 4; }
    else if (NT == 2) { n0 = (w&1)*16;  mt0 = w>>1;   step = 2; }
    else              { n0 = w*16;      mt0 = 0;      step = 1; }

    const unsigned short* wb = wt + (size_t)(n0 + l15)*KPAD + q*8;
    const int c0q = (CIN==16) ? ((q & 1) << 3) : (q << 3);

    v4f acc[JITER];
    #pragma unroll
    for (int j = 0; j < JITER; j++) acc[j] = v4f{0.f,0.f,0.f,0.f};

    if constexpr (CIN == 64) {
        // s-outer / j-inner: one weight fragment live, JITER independent MFMAs
        #pragma unroll
        for (int s = 0; s < S; s++) {
            const v8s Bf = *(const v8s*)(wb + 32*s);
            const int tap = s >> 1;
            const int dh1 = tap/3 - 1, dw1 = tap%3 - 1;
            const int c0s = c0q + ((s & 1) << 5);
            #pragma unroll
            for (int j = 0; j < JITER; j++) {
                const int mt  = mt0 + j*step;
                const int p   = mt*16 + l15;
                const int ihb = (p >> lgWO) * ST;
                const int iwb = (p & (WO-1)) * ST;
                int ih = ihb + dh1, iw = iwb + dw1;
                bool valid = ((unsigned)ih < (unsigned)HIN) && ((unsigned)iw < (unsigned)WIN);
                int pp  = (ih << lgWI) + iw;
                int csw = c0s ^ ((pp & CMASK) << 3);
                int eoff = (pp << lgC) + csw;
                const v8s* ap = valid ? (const v8s*)(in_s + eoff) : (const v8s*)&zq;
                v8s Af = *ap;
                acc[j] = __builtin_amdgcn_mfma_f32_16x16x32_bf16(Af, Bf, acc[j], 0, 0, 0);
            }
        }
    } else {
        v8s Bf[S];
        #pragma unroll
        for (int s = 0; s < S; s++)
            Bf[s] = *(const v8s*)(wb + 32*s);

        int dh1s[S], dw1s[S];
        if (CIN == 16) {
            int tq = q >> 1;
            #pragma unroll
            for (int s = 0; s < S; s++) {
                int tap = 2*s + tq;
                int dh = (tap*11) >> 5;
                int dw = tap - 3*dh;
                dh1s[s] = (tap >= 9) ? -1000 : (dh - 1);
                dw1s[s] = dw - 1;
            }
        }

        #pragma unroll
        for (int j = 0; j < JITER; j++) {
            const int mt  = mt0 + j*step;
            const int p   = mt*16 + l15;
            const int ihb = (p >> lgWO) * ST;
            const int iwb = (p & (WO-1)) * ST;
            #pragma unroll
            for (int s = 0; s < S; s++) {
                int dh1, dw1;
                if (CIN == 16) { dh1 = dh1s[s]; dw1 = dw1s[s]; }
                else           { dh1 = s/3 - 1; dw1 = s%3 - 1; }
                int ih = ihb + dh1, iw = iwb + dw1;
                bool valid = ((unsigned)ih < (unsigned)HIN) && ((unsigned)iw < (unsigned)WIN);
                int pp  = (ih << lgWI) + iw;
                int csw = c0q ^ ((pp & CMASK) << 3);
                int eoff = (pp << lgC) + csw;
                const v8s* ap = valid ? (const v8s*)(in_s + eoff) : (const v8s*)&zq;
                v8s Af = *ap;
                acc[j] = __builtin_amdgcn_mfma_f32_16x16x32_bf16(Af, Bf[s], acc[j], 0, 0, 0);
            }
        }
    }
    __syncthreads();   // all in_s reads complete -> reuse as output bounce

    unsigned short* out_s = in_s;
    float sa = 0.f, qa = 0.f;
    #pragma unroll
    for (int j = 0; j < JITER; j++) {
        const int mt = mt0 + j*step;
        #pragma unroll
        for (int r2 = 0; r2 < 4; r2++) {
            float v = acc[j][r2];
            out_s[(mt*16 + q*4 + r2)*COUT + n0 + l15] = f2bf(v);
            sa += v; qa += v*v;
        }
    }
    __syncthreads();

    {
        constexpr int NIT = (M*COUT/8)/256;
        uint4* ob4 = (uint4*)(out + (size_t)b*M*COUT);
        const uint4* os4 = (const uint4*)in_s;
        #pragma unroll
        for (int it = 0; it < NIT; it++)
            ob4[it*256 + tid] = os4[it*256 + tid];
    }

    sa += __shfl_xor(sa, 16); sa += __shfl_xor(sa, 32);
    qa += __shfl_xor(qa, 16); qa += __shfl_xor(qa, 32);
    if (q == 0) {
        red[(w*16 + l15)*2]     = sa;
        red[(w*16 + l15)*2 + 1] = qa;
    }
    __syncthreads();
    if (tid < COUT) {
        float S2, Q2;
        if (NT == 1) {
            S2 = red[tid*2] + red[(16+tid)*2] + red[(32+tid)*2] + red[(48+tid)*2];
            Q2 = red[tid*2+1] + red[(16+tid)*2+1] + red[(32+tid)*2+1] + red[(48+tid)*2+1];
        } else if (NT == 2) {
            int w0 = tid >> 4, cl = tid & 15;
            S2 = red[((w0*16)+cl)*2]     + red[(((w0+2)*16)+cl)*2];
            Q2 = red[((w0*16)+cl)*2 + 1] + red[(((w0+2)*16)+cl)*2 + 1];
        } else {
            int w0 = tid >> 4, cl = tid & 15;
            S2 = red[((w0*16)+cl)*2];
            Q2 = red[((w0*16)+cl)*2 + 1];
        }
        float* sl = stats + (b & (NSLOT-1))*128;
        atomicAdd(&sl[tid],      S2);
        atomicAdd(&sl[64 + tid], Q2);
    }
}

// final bn_add fused into pool+fc; stats = 64-slot partial region of l18.
// Runtime dtype branch for Wfc/bfc/out (uniform).
__global__ void poolfc_kernel(const unsigned short* __restrict__ x,
    const unsigned short* __restrict__ resid,
    const float* __restrict__ stats, float invN,
    const void* __restrict__ Wfc, const void* __restrict__ bfc,
    void* __restrict__ out, const int* flag)
{
    int b = blockIdx.x;
    int c = threadIdx.x; // 64 threads
    float ssum = 0.f, qsum = 0.f;
    for (int k = 0; k < NSLOT; k++) {
        ssum += stats[k*128 + c];
        qsum += stats[k*128 + 64 + c];
    }
    float m = ssum*invN;
    float v = fmaxf(qsum*invN - m*m, 0.f);
    float rs = rsqrtf(v + 1e-5f);
    float s = 0.f;
    #pragma unroll
    for (int p = 0; p < 64; p++) {
        size_t idx = ((size_t)b*64 + p)*64 + c;
        float xv = bf2f((unsigned int)x[idx]);
        float rv = bf2f((unsigned int)resid[idx]);
        s += fmaxf((xv - m)*rs + rv, 0.f);
    }
    __shared__ float feat[64];
    feat[c] = s * (1.f/64.f);
    __syncthreads();
    if (c < 10) {
        if (is_bf16(flag)) {
            const __hip_bfloat16* W  = (const __hip_bfloat16*)Wfc;
            const __hip_bfloat16* bb = (const __hip_bfloat16*)bfc;
            float o = ldf(bb + c);
            for (int k = 0; k < 64; k++)
                o += feat[k] * ldf(W + c*64 + k);
            ((__hip_bfloat16*)out)[b*10 + c] = __float2bfloat16(o);
        } else {
            const float* W  = (const float*)Wfc;
            const float* bb = (const float*)bfc;
            float o = bb[c];
            for (int k = 0; k < 64; k++)
                o += feat[k] * W[c*64 + k];
            ((float*)out)[b*10 + c] = o;
        }
    }
}

extern "C" void kernel_launch(void* const* d_in, const int* in_sizes, int n_in,
                              void* d_out, int out_size, void* d_ws, size_t ws_size,
                              hipStream_t stream)
{
    char* ws = (char*)d_ws;
    float* wflat = (float*)(ws);                            // DTOT fp32
    int*   flag  = (int*)  (ws + 1146880);
    unsigned short* WT = (unsigned short*)(ws + 1179648);   // 269312 bf16
    unsigned short* curA = (unsigned short*)(ws + 1720320);               // 33.5MB
    unsigned short* curB = (unsigned short*)(ws + 1720320 + 33554432ULL); // 33.5MB (l0 raw)
    unsigned short* f1   = (unsigned short*)(ws + 1720320 + 67108864ULL);
    unsigned short* f2   = (unsigned short*)(ws + 1720320 + 100663296ULL);
    float* ps    = (float*)(ws + 135938048ULL);  // 19 x [64][128] fp32 partial stats

    hipMemsetAsync(ps, 0, NLAYER*PSL*4, stream);
    detect_kernel<<<1, 256, 0, stream>>>((const unsigned short*)d_in[0], flag);

    wflat_kernel<<<(DTOT+255)/256, 256, 0, stream>>>(
        d_in[1], d_in[2], d_in[3], wflat, DTOT, flag);

    {
        dim3 g(3, 64, 19);
        wprep_kernel<<<g, 192, 0, stream>>>(wflat, WT);
    }

    static const int WTOFF[NLAYER] = {0,0,2560,5120,7680,10240,12800,15360,20480,29696,
        38912,48128,57344,66560,84992,121856,158720,195584,232448};
    const float iN32 = 1.f/1048576.f;   // B*32*32
    const float iN16 = 1.f/262144.f;    // B*16*16
    const float iN8  = 1.f/65536.f;     // B*8*8

    // ---- layer 0 (stats fused into epilogue) ----
    conv_l0<<<2*BATCH,512,0,stream>>>(d_in[0], wflat, curB, ps, flag);

    // b0
    conv_mfma<16,16,32,32,1,false,false,false,0,0><<<BATCH,256,0,stream>>>(
        curB, nullptr, nullptr, WT + WTOFF[1], f1, ps + 1*PSL, ps, iN32, nullptr, 0.f);
    conv_mfma<16,16,32,32,1,false,false,false,0,0><<<BATCH,256,0,stream>>>(
        f1, nullptr, nullptr, WT + WTOFF[2], f2, ps + 2*PSL, ps + 1*PSL, iN32, nullptr, 0.f);
    // b1: fused bn_add(b0) [PN=l0 stats]; resid -> curA
    conv_mfma<16,16,32,32,1,true,true,false,0,0><<<BATCH,256,0,stream>>>(
        f2, curB, curA, WT + WTOFF[3], f1, ps + 3*PSL, ps + 2*PSL, iN32, ps, iN32);
    conv_mfma<16,16,32,32,1,false,false,false,0,0><<<BATCH,256,0,stream>>>(
        f1, nullptr, nullptr, WT + WTOFF[4], f2, ps + 4*PSL, ps + 3*PSL, iN32, nullptr, 0.f);
    // b2: fused bn_add(b1); resid -> curB
    conv_mfma<16,16,32,32,1,true,false,false,0,0><<<BATCH,256,0,stream>>>(
        f2, curA, curB, WT + WTOFF[5], f1, ps + 5*PSL, ps + 4*PSL, iN32, nullptr, 0.f);
    conv_mfma<16,16,32,32,1,false,false,false,0,0><<<BATCH,256,0,stream>>>(
        f1, nullptr, nullptr, WT + WTOFF[6], f2, ps + 6*PSL, ps + 5*PSL, iN32, nullptr, 0.f);
    // b3: fused bn_add(b2) into stride-2 conv-A(l7); resid -> curA (32²,16ch)
    conv_mfma<16,32,32,32,2,true,false,false,0,0><<<BATCH,256,0,stream>>>(
        f2, curB, curA, WT + WTOFF[7], f1, ps + 7*PSL, ps + 6*PSL, iN32, nullptr, 0.f);
    conv_mfma<32,32,16,16,1,false,false,false,0,0><<<BATCH,256,0,stream>>>(
        f1, nullptr, nullptr, WT + WTOFF[8], f2, ps + 8*PSL, ps + 7*PSL, iN16, nullptr, 0.f);
    // b4: FUSE2 bn_add(b3, stride2 shortcut from curA) into conv-A(l9); resid -> curB
    conv_mfma<32,32,16,16,1,false,false,true,16,8><<<BATCH,256,0,stream>>>(
        f2, curA, curB, WT + WTOFF[9], f1, ps + 9*PSL, ps + 8*PSL, iN16, nullptr, 0.f);
    conv_mfma<32,32,16,16,1,false,false,false,0,0><<<BATCH,256,0,stream>>>(
        f1, nullptr, nullptr, WT + WTOFF[10], f2, ps + 10*PSL, ps + 9*PSL, iN16, nullptr, 0.f);
    // b5: fused bn_add(b4); resid -> curA
    conv_mfma<32,32,16,16,1,true,false,false,0,0><<<BATCH,256,0,stream>>>(
        f2, curB, curA, WT + WTOFF[11], f1, ps + 11*PSL, ps + 10*PSL, iN16, nullptr, 0.f);
    conv_mfma<32,32,16,16,1,false,false,false,0,0><<<BATCH,256,0,stream>>>(
        f1, nullptr, nullptr, WT + WTOFF[12], f2, ps + 12*PSL, ps + 11*PSL, iN16, nullptr, 0.f);
    // b6: fused bn_add(b5) into stride-2 conv-A(l13); resid -> curB (16²,32ch)
    conv_mfma<32,64,16,16,2,true,false,false,0,0><<<BATCH,256,0,stream>>>(
        f2, curA, curB, WT + WTOFF[13], f1, ps + 13*PSL, ps + 12*PSL, iN16, nullptr, 0.f);
    conv_mfma<64,64,8,8,1,false,false,false,0,0><<<BATCH,256,0,stream>>>(
        f1, nullptr, nullptr, WT + WTOFF[14], f2, ps + 14*PSL, ps + 13*PSL, iN8, nullptr, 0.f);
    // b7: FUSE2 bn_add(b6, stride2 shortcut from curB) into conv-A(l15); resid -> curA
    conv_mfma<64,64,8,8,1,false,false,true,32,16><<<BATCH,256,0,stream>>>(
        f2, curB, curA, WT + WTOFF[15], f1, ps + 15*PSL, ps + 14*PSL, iN8, nullptr, 0.f);
    conv_mfma<64,64,8,8,1,false,false,false,0,0><<<BATCH,256,0,stream>>>(
        f1, nullptr, nullptr, WT + WTOFF[16], f2, ps + 16*PSL, ps + 15*PSL, iN8, nullptr, 0.f);
    // b8: fused bn_add(b7); resid -> curB
    conv_mfma<64,64,8,8,1,true,false,false,0,0><<<BATCH,256,0,stream>>>(
        f2, curA, curB, WT + WTOFF[17], f1, ps + 17*PSL, ps + 16*PSL, iN8, nullptr, 0.f);
    conv_mfma<64,64,8,8,1,false,false,false,0,0><<<BATCH,256,0,stream>>>(
        f1, nullptr, nullptr, WT + WTOFF[18], f2, ps + 18*PSL, ps + 17*PSL, iN8, nullptr, 0.f);

    // final bn_add(l18)+resid(curB) fused into pool+fc
    poolfc_kernel<<<BATCH, 64, 0, stream>>>(
        f2, curB, ps + 18*PSL, iN8, d_in[4], d_in[5], d_out, flag);
}

// Round 13
// 436.558 us; speedup vs baseline: 17.3660x; 1.0519x over previous
//
#include <hip/hip_runtime.h>
#include <hip/hip_bf16.h>

#define BATCH 1024
#define NLAYER 19
#define DTOT 267696
#define NSLOT 64
#define PSL (NSLOT*128)   // floats per layer partial-stats region

typedef __attribute__((ext_vector_type(8))) short v8s;
typedef __attribute__((ext_vector_type(4))) float v4f;

__device__ inline float ldf(const float* p){ return *p; }
__device__ inline float ldf(const __hip_bfloat16* p){ return __bfloat162float(*p); }

__device__ inline unsigned short f2bf(float x){
    __hip_bfloat16 h = __float2bfloat16(x);
    return *reinterpret_cast<unsigned short*>(&h);
}
__device__ inline float bf2f(unsigned int u){
    return __uint_as_float(u << 16);
}

// ---- dtype detector: flag=1 if inputs bf16, 0 if f32 ----
__global__ void detect_kernel(const unsigned short* __restrict__ xraw, int* __restrict__ flag)
{
    __shared__ int bad;
    if (threadIdx.x == 0) bad = 0;
    __syncthreads();
    int lbad = 0;
    for (int i = threadIdx.x; i < 4096; i += 256) {
        unsigned e = (xraw[i] >> 7) & 0xFF;
        if (e >= 147) lbad++;
    }
    if (lbad) atomicAdd(&bad, lbad);
    __syncthreads();
    if (threadIdx.x == 0) *flag = (bad == 0) ? 1 : 0;
}

__device__ inline bool is_bf16(const int* flag)
{
    return (*(volatile const int*)flag) == 1;
}

// w_flat = origin + new_param @ P  (runtime dtype branch; uniform)
__global__ void wflat_kernel(const void* __restrict__ origin,
                             const void* __restrict__ P,
                             const void* __restrict__ npar,
                             float* __restrict__ wout, int D,
                             const int* flag)
{
    int d = blockIdx.x*256 + threadIdx.x;
    if (d >= D) return;
    float acc;
    if (is_bf16(flag)) {
        const __hip_bfloat16* ob = (const __hip_bfloat16*)origin;
        const __hip_bfloat16* Pb = (const __hip_bfloat16*)P;
        const __hip_bfloat16* nb = (const __hip_bfloat16*)npar;
        acc = ldf(ob + d);
        #pragma unroll 8
        for (int k = 0; k < 40; k++)
            acc += ldf(nb + k) * ldf(Pb + (long long)k*D + d);
    } else {
        const float* of = (const float*)origin;
        const float* Pf = (const float*)P;
        const float* nf = (const float*)npar;
        acc = of[d];
        #pragma unroll 8
        for (int k = 0; k < 40; k++)
            acc += nf[k] * Pf[(long long)k*D + d];
    }
    wout[d] = acc;
}

// ---- weight transform: wflat (OIHW fp32) -> W_T[l][cout][kpad] bf16 ----
__global__ void wprep_kernel(const float* __restrict__ wflat, unsigned short* __restrict__ WT)
{
    static const int CINA[19]  = {3,16,16,16,16,16,16,16,32,32,32,32,32,32,64,64,64,64,64};
    static const int COUTA[19] = {16,16,16,16,16,16,16,32,32,32,32,32,32,64,64,64,64,64,64};
    static const int LGCA[19]  = {0,4,4,4,4,4,4,4,5,5,5,5,5,5,6,6,6,6,6};
    static const int KPADA[19] = {0,160,160,160,160,160,160,160,288,288,288,288,288,288,576,576,576,576,576};
    static const int WOFFA[19] = {0,432,2736,5040,7344,9648,11952,14256,18864,
        28080,37296,46512,55728,64944,83376,120240,157104,193968,230832};
    static const int WTOFFA[19]= {0,0,2560,5120,7680,10240,12800,15360,20480,29696,
        38912,48128,57344,66560,84992,121856,158720,195584,232448};
    int l = blockIdx.z;
    if (l == 0) return;
    int co = blockIdx.y;
    if (co >= COUTA[l]) return;
    int kp = blockIdx.x*192 + threadIdx.x;
    if (kp >= KPADA[l]) return;
    int cin = CINA[l];
    float v = 0.f;
    if (kp < 9*cin) {
        int tap = kp >> LGCA[l];
        int ci  = kp & (cin - 1);
        v = wflat[WOFFA[l] + (co*cin + ci)*9 + tap];
    }
    WT[WTOFFA[l] + co*KPADA[l] + kp] = f2bf(v);
}

// ---- layer 0: MFMA implicit-GEMM conv (Cin=3), NCHW input -> NHWC bf16 ----
// A = input patches [M=1024 pos][K=27 pad 32], B = weights [N=16][K], using
// the proven conv_mfma fragment conventions (lane&15 = row for A and B,
// lane>>4 = k-group of 8 consecutive k; k = ci*9 + kh*3 + kw).
// Input staged into zero-bordered LDS image [3][34][36] -> conv padding is
// free (no bounds checks); k>=27 reads arbitrary valid words, weight = 0.
// Epilogue (LDS bounce + slotted stats) copied from conv_mfma NT=1 path;
// the LDS image is aliased as the 32KB out bounce after the compute sync.
// (r12 lesson: scalar-VALU l0 was 46us, VALUBusy 65%, MfmaUtil 0 — 4x the
//  pure-FMA issue cost went to unpack/select overhead.)
__global__ __launch_bounds__(256, 4) void conv_l0(
    const void* __restrict__ in, const float* __restrict__ wt,
    unsigned short* __restrict__ out, float* __restrict__ ps,
    const int* flag)
{
    __shared__ unsigned short lbuf[16384];   // image 3*34*36=3672 u16; bounce 16384 u16
    __shared__ float red[128];

    const int tid = threadIdx.x;
    const int b   = blockIdx.x;
    const bool isbf = is_bf16(flag);

    // zero padded image region (3672 u16 = 1836 u32)
    {
        unsigned int* l4 = (unsigned int*)lbuf;
        for (int i = tid; i < 1836; i += 256) l4[i] = 0u;
    }
    __syncthreads();

    // stage interior: in[b][c][h][w] -> lbuf[c*1224 + (h+1)*36 + (w+1)]
    {
        const __hip_bfloat16* ih_ = (const __hip_bfloat16*)in + (size_t)b*3072;
        const float*          if_ = (const float*)in + (size_t)b*3072;
        for (int i = tid; i < 3072; i += 256) {
            int c = i >> 10, rem = i & 1023, h = rem >> 5, w2 = rem & 31;
            float x = isbf ? ldf(ih_ + i) : if_[i];
            lbuf[c*1224 + (h+1)*36 + (w2+1)] = f2bf(x);
        }
    }

    const int w_  = tid >> 6;
    const int ln  = tid & 63;
    const int l15 = ln & 15;
    const int q   = ln >> 4;

    // B fragment: lane (n=l15, k-group q), 8 consecutive k from wflat fp32
    v8s Bf;
    {
        union { unsigned int u[4]; v8s v; } bu;
        #pragma unroll
        for (int kk2 = 0; kk2 < 4; kk2++) {
            int k0 = q*8 + kk2*2, k1 = k0 + 1;
            float w0 = (k0 < 27) ? wt[l15*27 + k0] : 0.f;
            float w1 = (k1 < 27) ? wt[l15*27 + k1] : 0.f;
            bu.u[kk2] = (unsigned)f2bf(w0) | ((unsigned)f2bf(w1) << 16);
        }
        Bf = bu.v;
    }

    // per-lane A-gather offsets for its 8 k values
    int offk[8];
    #pragma unroll
    for (int kk = 0; kk < 8; kk++) {
        int k = q*8 + kk;
        int ci = k / 9;
        int tap = k - ci*9;
        int kh = tap / 3, kw = tap - kh*3;
        if (ci > 2) { ci = 0; kh = 0; kw = 0; }   // k>=27: weight=0, read anything
        offk[kk] = ci*1224 + kh*36 + kw;
    }
    __syncthreads();

    // 64 M-tiles; wave w_ handles mt = w_, w_+4, ... (16 MFMAs/wave)
    v4f acc[16];
    #pragma unroll
    for (int j = 0; j < 16; j++) acc[j] = v4f{0.f,0.f,0.f,0.f};

    #pragma unroll
    for (int j = 0; j < 16; j++) {
        const int mt = w_ + j*4;
        const int p  = mt*16 + l15;
        const int base = (p >> 5)*36 + (p & 31);
        union { unsigned int u[4]; v8s v; } au;
        #pragma unroll
        for (int kk2 = 0; kk2 < 4; kk2++) {
            unsigned a0 = lbuf[base + offk[kk2*2]];
            unsigned a1 = lbuf[base + offk[kk2*2+1]];
            au.u[kk2] = a0 | (a1 << 16);
        }
        acc[j] = __builtin_amdgcn_mfma_f32_16x16x32_bf16(au.v, Bf, acc[j], 0, 0, 0);
    }
    __syncthreads();   // all image reads done -> reuse lbuf as out bounce

    // ---- epilogue: bounce + fused stats (conv_mfma NT=1 pattern) ----
    float sa = 0.f, qa = 0.f;
    #pragma unroll
    for (int j = 0; j < 16; j++) {
        const int mt = w_ + j*4;
        #pragma unroll
        for (int r2 = 0; r2 < 4; r2++) {
            float v = acc[j][r2];
            lbuf[(mt*16 + q*4 + r2)*16 + l15] = f2bf(v);
            sa += v; qa += v*v;
        }
    }
    __syncthreads();
    {
        uint4* ob4 = (uint4*)(out + (size_t)b*16384);
        const uint4* os4 = (const uint4*)lbuf;
        #pragma unroll
        for (int it = 0; it < 8; it++)
            ob4[it*256 + tid] = os4[it*256 + tid];
    }
    sa += __shfl_xor(sa, 16); sa += __shfl_xor(sa, 32);
    qa += __shfl_xor(qa, 16); qa += __shfl_xor(qa, 32);
    if (q == 0) {
        red[(w_*16 + l15)*2]     = sa;
        red[(w_*16 + l15)*2 + 1] = qa;
    }
    __syncthreads();
    if (tid < 16) {
        float S2 = red[tid*2] + red[(16+tid)*2] + red[(32+tid)*2] + red[(48+tid)*2];
        float Q2 = red[tid*2+1] + red[(16+tid)*2+1] + red[(32+tid)*2+1] + red[(48+tid)*2+1];
        float* sl = ps + (b & (NSLOT-1))*128;
        atomicAdd(&sl[tid],      S2);
        atomicAdd(&sl[64 + tid], Q2);
    }
}

// ---- MFMA implicit-GEMM 3x3 conv, one block (4 waves) per image ----
// FUSE : staging performs preceding stride-1 bn_add (elementwise residual).
// FUSE2: staging performs preceding stride-2 bn_add (residual = 2x-res gather,
//        channel pad 8-aligned -> whole uint4 group valid or zero).
// Stats: 64-slot partial buffers [NSLOT][128]; producers atomicAdd into slot
// (b & 63); consumers reduce the 64 slots at kernel start (L2-hot 32KB read).
// Main loop: j-outer/s-inner with Bf[S] preload for CIN=16/32 (proven best);
// s-outer/j-inner for CIN=64 where Bf[18]=72 VGPRs would spill to scratch.
// (Mega-kernel fusion arc r5-r10: cross-XCD sync inside one kernel requires
//  ACQUIRE=L2-invalidate (~200us/barrier) or hangs with relaxed loads (stale
//  L2 line never refreshes) -> multi-dispatch is the correct structure.)
template<int CIN, int COUT, int HIN, int WIN, int ST, bool FUSE, bool PN,
         bool FUSE2, int PREVC, int PADF>
__global__ __launch_bounds__(256, 4) void conv_mfma(
    const unsigned short* __restrict__ src, const unsigned short* __restrict__ prev,
    unsigned short* __restrict__ resid,
    const unsigned short* __restrict__ wt,
    unsigned short* __restrict__ out, float* __restrict__ stats,
    const float* __restrict__ nstats, float ninvN,
    const float* __restrict__ pstats, float pinvN)
{
    constexpr int HO = HIN/ST, WO = WIN/ST, M = HO*WO, MT = M/16;
    constexpr int NT = COUT/16;
    constexpr int K  = 9*CIN;
    constexpr int S  = (K + 31)/32;
    constexpr int KPAD = S*32;
    constexpr int lgC  = (CIN==16)?4:(CIN==32)?5:6;
    constexpr int lgWI = (WIN==32)?5:(WIN==16)?4:3;
    constexpr int lgWO = (WO==32)?5:(WO==16)?4:3;
    constexpr int CMASK = CIN/8 - 1;
    constexpr int JITER = (NT==1)? MT/4 : (NT==2)? MT/2 : MT;
    static_assert(M*COUT <= CIN*HIN*WIN, "out_s fits in in_s");

    __shared__ unsigned short in_s[CIN*HIN*WIN];   // input, then output bounce
    __shared__ float red[128];
    __shared__ float statred[256];
    __shared__ float nm[64], nv[64];
    __shared__ float pm_s[64], pv_s[64];
    __shared__ uint4 zq;

    const int tid = threadIdx.x;
    const int b   = blockIdx.x;

    if (tid == 0) { zq.x = 0; zq.y = 0; zq.z = 0; zq.w = 0; }

    // ---- reduce 64-slot producer partials -> nm/nv (and pm/pv if PN) ----
    {
        const int idx = tid & 127, hf = tid >> 7;
        float sacc = 0.f;
        #pragma unroll 8
        for (int k = hf*32; k < hf*32 + 32; k++)
            sacc += nstats[k*128 + idx];
        statred[tid] = sacc;
    }
    __syncthreads();
    if (tid < CIN) {
        float ssum = statred[tid]      + statred[128 + tid];
        float qsum = statred[64 + tid] + statred[192 + tid];
        float m = ssum*ninvN;
        float v = fmaxf(qsum*ninvN - m*m, 0.f);
        nm[tid] = m; nv[tid] = rsqrtf(v + 1e-5f);
    }
    if (PN && tid < CIN) {
        float ssum = 0.f, qsum = 0.f;
        for (int k = 0; k < NSLOT; k++) {
            ssum += pstats[k*128 + tid];
            qsum += pstats[k*128 + 64 + tid];
        }
        float m = ssum*pinvN;
        float v = fmaxf(qsum*pinvN - m*m, 0.f);
        pm_s[tid] = m; pv_s[tid] = rsqrtf(v + 1e-5f);
    }
    __syncthreads();

    // ---- staging ----
    {
        const uint4* sb4 = (const uint4*)(src + (size_t)b*(HIN*WIN)*CIN);
        constexpr int NP4 = CIN*HIN*WIN/8;
        if (FUSE) {
            const uint4* pb4 = (const uint4*)(prev + (size_t)b*(HIN*WIN)*CIN);
            uint4* rb4 = (uint4*)(resid + (size_t)b*(HIN*WIN)*CIN);
            for (int i = tid; i < NP4; i += 256) {
                uint4 v = sb4[i];
                uint4 pw = pb4[i];
                int e0 = i << 3;
                int c0 = e0 & (CIN-1);
                int p  = e0 >> lgC;
                float f[8] = { bf2f(v.x & 0xffffu), bf2f(v.x >> 16),
                               bf2f(v.y & 0xffffu), bf2f(v.y >> 16),
                               bf2f(v.z & 0xffffu), bf2f(v.z >> 16),
                               bf2f(v.w & 0xffffu), bf2f(v.w >> 16) };
                float g[8] = { bf2f(pw.x & 0xffffu), bf2f(pw.x >> 16),
                               bf2f(pw.y & 0xffffu), bf2f(pw.y >> 16),
                               bf2f(pw.z & 0xffffu), bf2f(pw.z >> 16),
                               bf2f(pw.w & 0xffffu), bf2f(pw.w >> 16) };
                #pragma unroll
                for (int k = 0; k < 8; k++) {
                    int c = c0 + k;
                    float fx = (f[k] - nm[c])*nv[c];
                    float gv = g[k];
                    if (PN) gv = fmaxf((gv - pm_s[c])*pv_s[c], 0.f);
                    f[k] = fmaxf(fx + gv, 0.f);
                }
                uint4 o;
                o.x = (unsigned)f2bf(f[0]) | ((unsigned)f2bf(f[1]) << 16);
                o.y = (unsigned)f2bf(f[2]) | ((unsigned)f2bf(f[3]) << 16);
                o.z = (unsigned)f2bf(f[4]) | ((unsigned)f2bf(f[5]) << 16);
                o.w = (unsigned)f2bf(f[6]) | ((unsigned)f2bf(f[7]) << 16);
                rb4[i] = o;
                int csw = c0 ^ ((p & CMASK) << 3);
                *(uint4*)(in_s + (p << lgC) + csw) = o;
            }
        } else if (FUSE2) {
            // prev dims: (2*HIN)x(2*WIN)xPREVC; group valid iff pc0 in [0,PREVC-8]
            uint4* rb4 = (uint4*)(resid + (size_t)b*(HIN*WIN)*CIN);
            for (int i = tid; i < NP4; i += 256) {
                uint4 v = sb4[i];
                int e0 = i << 3;
                int c0 = e0 & (CIN-1);
                int p  = e0 >> lgC;
                int h  = p >> lgWI, wq = p & (WIN-1);
                int pp = (h << (lgWI+2)) + 2*wq;
                int pc0 = c0 - PADF;
                bool pv = (pc0 >= 0) && (pc0 <= PREVC - 8);
                uint4 pw;
                pw.x = 0; pw.y = 0; pw.z = 0; pw.w = 0;
                if (pv) pw = *(const uint4*)(prev + ((size_t)b*(HIN*WIN*4) + pp)*PREVC + pc0);
                float f[8] = { bf2f(v.x & 0xffffu), bf2f(v.x >> 16),
                               bf2f(v.y & 0xffffu), bf2f(v.y >> 16),
                               bf2f(v.z & 0xffffu), bf2f(v.z >> 16),
                               bf2f(v.w & 0xffffu), bf2f(v.w >> 16) };
                float g[8] = { bf2f(pw.x & 0xffffu), bf2f(pw.x >> 16),
                               bf2f(pw.y & 0xffffu), bf2f(pw.y >> 16),
                               bf2f(pw.z & 0xffffu), bf2f(pw.z >> 16),
                               bf2f(pw.w & 0xffffu), bf2f(pw.w >> 16) };
                #pragma unroll
                for (int k = 0; k < 8; k++) {
                    int c = c0 + k;
                    f[k] = fmaxf((f[k] - nm[c])*nv[c] + g[k], 0.f);
                }
                uint4 o;
                o.x = (unsigned)f2bf(f[0]) | ((unsigned)f2bf(f[1]) << 16);
                o.y = (unsigned)f2bf(f[2]) | ((unsigned)f2bf(f[3]) << 16);
                o.z = (unsigned)f2bf(f[4]) | ((unsigned)f2bf(f[5]) << 16);
                o.w = (unsigned)f2bf(f[6]) | ((unsigned)f2bf(f[7]) << 16);
                rb4[i] = o;
                int csw = c0 ^ ((p & CMASK) << 3);
                *(uint4*)(in_s + (p << lgC) + csw) = o;
            }
        } else {
            for (int i = tid; i < NP4; i += 256) {
                uint4 v = sb4[i];
                int e0 = i << 3;
                int c0 = e0 & (CIN-1);
                int p  = e0 >> lgC;
                float f[8] = { bf2f(v.x & 0xffffu), bf2f(v.x >> 16),
                               bf2f(v.y & 0xffffu), bf2f(v.y >> 16),
                               bf2f(v.z & 0xffffu), bf2f(v.z >> 16),
                               bf2f(v.w & 0xffffu), bf2f(v.w >> 16) };
                #pragma unroll
                for (int k = 0; k < 8; k++) {
                    int c = c0 + k;
                    f[k] = fmaxf((f[k] - nm[c])*nv[c], 0.f);
                }
                uint4 o;
                o.x = (unsigned)f2bf(f[0]) | ((unsigned)f2bf(f[1]) << 16);
                o.y = (unsigned)f2bf(f[2]) | ((unsigned)f2bf(f[3]) << 16);
                o.z = (unsigned)f2bf(f[4]) | ((unsigned)f2bf(f[5]) << 16);
                o.w = (unsigned)f2bf(f[6]) | ((unsigned)f2bf(f[7]) << 16);
                int csw = c0 ^ ((p & CMASK) << 3);
                *(uint4*)(in_s + (p << lgC) + csw) = o;
            }
        }
    }
    __syncthreads();

    const int w   = tid >> 6;
    const int ln  = tid & 63;
    const int l15 = ln & 15;
    const int q   = ln >> 4;

    int n0, mt0, step;
    if (NT == 1)      { n0 = 0;         mt0 = w;      step = 4; }
    else if (NT == 2) { n0 = (w&1)*16;  mt0 = w>>1;   step = 2; }
    else              { n0 = w*16;      mt0 = 0;      step = 1; }

    const unsigned short* wb = wt + (size_t)(n0 + l15)*KPAD + q*8;
    const int c0q = (CIN==16) ? ((q & 1) << 3) : (q << 3);

    v4f acc[JITER];
    #pragma unroll
    for (int j = 0; j < JITER; j++) acc[j] = v4f{0.f,0.f,0.f,0.f};

    if constexpr (CIN == 64) {
        // s-outer / j-inner: one weight fragment live, JITER independent MFMAs
        #pragma unroll
        for (int s = 0; s < S; s++) {
            const v8s Bf = *(const v8s*)(wb + 32*s);
            const int tap = s >> 1;
            const int dh1 = tap/3 - 1, dw1 = tap%3 - 1;
            const int c0s = c0q + ((s & 1) << 5);
            #pragma unroll
            for (int j = 0; j < JITER; j++) {
                const int mt  = mt0 + j*step;
                const int p   = mt*16 + l15;
                const int ihb = (p >> lgWO) * ST;
                const int iwb = (p & (WO-1)) * ST;
                int ih = ihb + dh1, iw = iwb + dw1;
                bool valid = ((unsigned)ih < (unsigned)HIN) && ((unsigned)iw < (unsigned)WIN);
                int pp  = (ih << lgWI) + iw;
                int csw = c0s ^ ((pp & CMASK) << 3);
                int eoff = (pp << lgC) + csw;
                const v8s* ap = valid ? (const v8s*)(in_s + eoff) : (const v8s*)&zq;
                v8s Af = *ap;
                acc[j] = __builtin_amdgcn_mfma_f32_16x16x32_bf16(Af, Bf, acc[j], 0, 0, 0);
            }
        }
    } else {
        v8s Bf[S];
        #pragma unroll
        for (int s = 0; s < S; s++)
            Bf[s] = *(const v8s*)(wb + 32*s);

        int dh1s[S], dw1s[S];
        if (CIN == 16) {
            int tq = q >> 1;
            #pragma unroll
            for (int s = 0; s < S; s++) {
                int tap = 2*s + tq;
                int dh = (tap*11) >> 5;
                int dw = tap - 3*dh;
                dh1s[s] = (tap >= 9) ? -1000 : (dh - 1);
                dw1s[s] = dw - 1;
            }
        }

        #pragma unroll
        for (int j = 0; j < JITER; j++) {
            const int mt  = mt0 + j*step;
            const int p   = mt*16 + l15;
            const int ihb = (p >> lgWO) * ST;
            const int iwb = (p & (WO-1)) * ST;
            #pragma unroll
            for (int s = 0; s < S; s++) {
                int dh1, dw1;
                if (CIN == 16) { dh1 = dh1s[s]; dw1 = dw1s[s]; }
                else           { dh1 = s/3 - 1; dw1 = s%3 - 1; }
                int ih = ihb + dh1, iw = iwb + dw1;
                bool valid = ((unsigned)ih < (unsigned)HIN) && ((unsigned)iw < (unsigned)WIN);
                int pp  = (ih << lgWI) + iw;
                int csw = c0q ^ ((pp & CMASK) << 3);
                int eoff = (pp << lgC) + csw;
                const v8s* ap = valid ? (const v8s*)(in_s + eoff) : (const v8s*)&zq;
                v8s Af = *ap;
                acc[j] = __builtin_amdgcn_mfma_f32_16x16x32_bf16(Af, Bf[s], acc[j], 0, 0, 0);
            }
        }
    }
    __syncthreads();   // all in_s reads complete -> reuse as output bounce

    unsigned short* out_s = in_s;
    float sa = 0.f, qa = 0.f;
    #pragma unroll
    for (int j = 0; j < JITER; j++) {
        const int mt = mt0 + j*step;
        #pragma unroll
        for (int r2 = 0; r2 < 4; r2++) {
            float v = acc[j][r2];
            out_s[(mt*16 + q*4 + r2)*COUT + n0 + l15] = f2bf(v);
            sa += v; qa += v*v;
        }
    }
    __syncthreads();

    {
        constexpr int NIT = (M*COUT/8)/256;
        uint4* ob4 = (uint4*)(out + (size_t)b*M*COUT);
        const uint4* os4 = (const uint4*)in_s;
        #pragma unroll
        for (int it = 0; it < NIT; it++)
            ob4[it*256 + tid] = os4[it*256 + tid];
    }

    sa += __shfl_xor(sa, 16); sa += __shfl_xor(sa, 32);
    qa += __shfl_xor(qa, 16); qa += __shfl_xor(qa, 32);
    if (q == 0) {
        red[(w*16 + l15)*2]     = sa;
        red[(w*16 + l15)*2 + 1] = qa;
    }
    __syncthreads();
    if (tid < COUT) {
        float S2, Q2;
        if (NT == 1) {
            S2 = red[tid*2] + red[(16+tid)*2] + red[(32+tid)*2] + red[(48+tid)*2];
            Q2 = red[tid*2+1] + red[(16+tid)*2+1] + red[(32+tid)*2+1] + red[(48+tid)*2+1];
        } else if (NT == 2) {
            int w0 = tid >> 4, cl = tid & 15;
            S2 = red[((w0*16)+cl)*2]     + red[(((w0+2)*16)+cl)*2];
            Q2 = red[((w0*16)+cl)*2 + 1] + red[(((w0+2)*16)+cl)*2 + 1];
        } else {
            int w0 = tid >> 4, cl = tid & 15;
            S2 = red[((w0*16)+cl)*2];
            Q2 = red[((w0*16)+cl)*2 + 1];
        }
        float* sl = stats + (b & (NSLOT-1))*128;
        atomicAdd(&sl[tid],      S2);
        atomicAdd(&sl[64 + tid], Q2);
    }
}

// final bn_add fused into pool+fc; stats = 64-slot partial region of l18.
// Runtime dtype branch for Wfc/bfc/out (uniform).
__global__ void poolfc_kernel(const unsigned short* __restrict__ x,
    const unsigned short* __restrict__ resid,
    const float* __restrict__ stats, float invN,
    const void* __restrict__ Wfc, const void* __restrict__ bfc,
    void* __restrict__ out, const int* flag)
{
    int b = blockIdx.x;
    int c = threadIdx.x; // 64 threads
    float ssum = 0.f, qsum = 0.f;
    for (int k = 0; k < NSLOT; k++) {
        ssum += stats[k*128 + c];
        qsum += stats[k*128 + 64 + c];
    }
    float m = ssum*invN;
    float v = fmaxf(qsum*invN - m*m, 0.f);
    float rs = rsqrtf(v + 1e-5f);
    float s = 0.f;
    #pragma unroll
    for (int p = 0; p < 64; p++) {
        size_t idx = ((size_t)b*64 + p)*64 + c;
        float xv = bf2f((unsigned int)x[idx]);
        float rv = bf2f((unsigned int)resid[idx]);
        s += fmaxf((xv - m)*rs + rv, 0.f);
    }
    __shared__ float feat[64];
    feat[c] = s * (1.f/64.f);
    __syncthreads();
    if (c < 10) {
        if (is_bf16(flag)) {
            const __hip_bfloat16* W  = (const __hip_bfloat16*)Wfc;
            const __hip_bfloat16* bb = (const __hip_bfloat16*)bfc;
            float o = ldf(bb + c);
            for (int k = 0; k < 64; k++)
                o += feat[k] * ldf(W + c*64 + k);
            ((__hip_bfloat16*)out)[b*10 + c] = __float2bfloat16(o);
        } else {
            const float* W  = (const float*)Wfc;
            const float* bb = (const float*)bfc;
            float o = bb[c];
            for (int k = 0; k < 64; k++)
                o += feat[k] * W[c*64 + k];
            ((float*)out)[b*10 + c] = o;
        }
    }
}

extern "C" void kernel_launch(void* const* d_in, const int* in_sizes, int n_in,
                              void* d_out, int out_size, void* d_ws, size_t ws_size,
                              hipStream_t stream)
{
    char* ws = (char*)d_ws;
    float* wflat = (float*)(ws);                            // DTOT fp32
    int*   flag  = (int*)  (ws + 1146880);
    unsigned short* WT = (unsigned short*)(ws + 1179648);   // 269312 bf16
    unsigned short* curA = (unsigned short*)(ws + 1720320);               // 33.5MB
    unsigned short* curB = (unsigned short*)(ws + 1720320 + 33554432ULL); // 33.5MB (l0 raw)
    unsigned short* f1   = (unsigned short*)(ws + 1720320 + 67108864ULL);
    unsigned short* f2   = (unsigned short*)(ws + 1720320 + 100663296ULL);
    float* ps    = (float*)(ws + 135938048ULL);  // 19 x [64][128] fp32 partial stats

    hipMemsetAsync(ps, 0, NLAYER*PSL*4, stream);
    detect_kernel<<<1, 256, 0, stream>>>((const unsigned short*)d_in[0], flag);

    wflat_kernel<<<(DTOT+255)/256, 256, 0, stream>>>(
        d_in[1], d_in[2], d_in[3], wflat, DTOT, flag);

    {
        dim3 g(3, 64, 19);
        wprep_kernel<<<g, 192, 0, stream>>>(wflat, WT);
    }

    static const int WTOFF[NLAYER] = {0,0,2560,5120,7680,10240,12800,15360,20480,29696,
        38912,48128,57344,66560,84992,121856,158720,195584,232448};
    const float iN32 = 1.f/1048576.f;   // B*32*32
    const float iN16 = 1.f/262144.f;    // B*16*16
    const float iN8  = 1.f/65536.f;     // B*8*8

    // ---- layer 0 (MFMA implicit-GEMM; stats fused into epilogue) ----
    conv_l0<<<BATCH,256,0,stream>>>(d_in[0], wflat, curB, ps, flag);

    // b0
    conv_mfma<16,16,32,32,1,false,false,false,0,0><<<BATCH,256,0,stream>>>(
        curB, nullptr, nullptr, WT + WTOFF[1], f1, ps + 1*PSL, ps, iN32, nullptr, 0.f);
    conv_mfma<16,16,32,32,1,false,false,false,0,0><<<BATCH,256,0,stream>>>(
        f1, nullptr, nullptr, WT + WTOFF[2], f2, ps + 2*PSL, ps + 1*PSL, iN32, nullptr, 0.f);
    // b1: fused bn_add(b0) [PN=l0 stats]; resid -> curA
    conv_mfma<16,16,32,32,1,true,true,false,0,0><<<BATCH,256,0,stream>>>(
        f2, curB, curA, WT + WTOFF[3], f1, ps + 3*PSL, ps + 2*PSL, iN32, ps, iN32);
    conv_mfma<16,16,32,32,1,false,false,false,0,0><<<BATCH,256,0,stream>>>(
        f1, nullptr, nullptr, WT + WTOFF[4], f2, ps + 4*PSL, ps + 3*PSL, iN32, nullptr, 0.f);
    // b2: fused bn_add(b1); resid -> curB
    conv_mfma<16,16,32,32,1,true,false,false,0,0><<<BATCH,256,0,stream>>>(
        f2, curA, curB, WT + WTOFF[5], f1, ps + 5*PSL, ps + 4*PSL, iN32, nullptr, 0.f);
    conv_mfma<16,16,32,32,1,false,false,false,0,0><<<BATCH,256,0,stream>>>(
        f1, nullptr, nullptr, WT + WTOFF[6], f2, ps + 6*PSL, ps + 5*PSL, iN32, nullptr, 0.f);
    // b3: fused bn_add(b2) into stride-2 conv-A(l7); resid -> curA (32²,16ch)
    conv_mfma<16,32,32,32,2,true,false,false,0,0><<<BATCH,256,0,stream>>>(
        f2, curB, curA, WT + WTOFF[7], f1, ps + 7*PSL, ps + 6*PSL, iN32, nullptr, 0.f);
    conv_mfma<32,32,16,16,1,false,false,false,0,0><<<BATCH,256,0,stream>>>(
        f1, nullptr, nullptr, WT + WTOFF[8], f2, ps + 8*PSL, ps + 7*PSL, iN16, nullptr, 0.f);
    // b4: FUSE2 bn_add(b3, stride2 shortcut from curA) into conv-A(l9); resid -> curB
    conv_mfma<32,32,16,16,1,false,false,true,16,8><<<BATCH,256,0,stream>>>(
        f2, curA, curB, WT + WTOFF[9], f1, ps + 9*PSL, ps + 8*PSL, iN16, nullptr, 0.f);
    conv_mfma<32,32,16,16,1,false,false,false,0,0><<<BATCH,256,0,stream>>>(
        f1, nullptr, nullptr, WT + WTOFF[10], f2, ps + 10*PSL, ps + 9*PSL, iN16, nullptr, 0.f);
    // b5: fused bn_add(b4); resid -> curA
    conv_mfma<32,32,16,16,1,true,false,false,0,0><<<BATCH,256,0,stream>>>(
        f2, curB, curA, WT + WTOFF[11], f1, ps + 11*PSL, ps + 10*PSL, iN16, nullptr, 0.f);
    conv_mfma<32,32,16,16,1,false,false,false,0,0><<<BATCH,256,0,stream>>>(
        f1, nullptr, nullptr, WT + WTOFF[12], f2, ps + 12*PSL, ps + 11*PSL, iN16, nullptr, 0.f);
    // b6: fused bn_add(b5) into stride-2 conv-A(l13); resid -> curB (16²,32ch)
    conv_mfma<32,64,16,16,2,true,false,false,0,0><<<BATCH,256,0,stream>>>(
        f2, curA, curB, WT + WTOFF[13], f1, ps + 13*PSL, ps + 12*PSL, iN16, nullptr, 0.f);
    conv_mfma<64,64,8,8,1,false,false,false,0,0><<<BATCH,256,0,stream>>>(
        f1, nullptr, nullptr, WT + WTOFF[14], f2, ps + 14*PSL, ps + 13*PSL, iN8, nullptr, 0.f);
    // b7: FUSE2 bn_add(b6, stride2 shortcut from curB) into conv-A(l15); resid -> curA
    conv_mfma<64,64,8,8,1,false,false,true,32,16><<<BATCH,256,0,stream>>>(
        f2, curB, curA, WT + WTOFF[15], f1, ps + 15*PSL, ps + 14*PSL, iN8, nullptr, 0.f);
    conv_mfma<64,64,8,8,1,false,false,false,0,0><<<BATCH,256,0,stream>>>(
        f1, nullptr, nullptr, WT + WTOFF[16], f2, ps + 16*PSL, ps + 15*PSL, iN8, nullptr, 0.f);
    // b8: fused bn_add(b7); resid -> curB
    conv_mfma<64,64,8,8,1,true,false,false,0,0><<<BATCH,256,0,stream>>>(
        f2, curA, curB, WT + WTOFF[17], f1, ps + 17*PSL, ps + 16*PSL, iN8, nullptr, 0.f);
    conv_mfma<64,64,8,8,1,false,false,false,0,0><<<BATCH,256,0,stream>>>(
        f1, nullptr, nullptr, WT + WTOFF[18], f2, ps + 18*PSL, ps + 17*PSL, iN8, nullptr, 0.f);

    // final bn_add(l18)+resid(curB) fused into pool+fc
    poolfc_kernel<<<BATCH, 64, 0, stream>>>(
        f2, curB, ps + 18*PSL, iN8, d_in[4], d_in[5], d_out, flag);
}

// Round 14
// 434.092 us; speedup vs baseline: 17.4647x; 1.0057x over previous
//
#include <hip/hip_runtime.h>
#include <hip/hip_bf16.h>

#define BATCH 1024
#define NLAYER 19
#define DTOT 267696
#define NSLOT 64
#define PSL (NSLOT*128)   // floats per layer partial-stats region

typedef __attribute__((ext_vector_type(8))) short v8s;
typedef __attribute__((ext_vector_type(4))) float v4f;

__device__ inline float ldf(const float* p){ return *p; }
__device__ inline float ldf(const __hip_bfloat16* p){ return __bfloat162float(*p); }

__device__ inline unsigned short f2bf(float x){
    __hip_bfloat16 h = __float2bfloat16(x);
    return *reinterpret_cast<unsigned short*>(&h);
}
__device__ inline float bf2f(unsigned int u){
    return __uint_as_float(u << 16);
}

// ---- dtype detector: flag=1 if inputs bf16, 0 if f32 ----
__global__ void detect_kernel(const unsigned short* __restrict__ xraw, int* __restrict__ flag)
{
    __shared__ int bad;
    if (threadIdx.x == 0) bad = 0;
    __syncthreads();
    int lbad = 0;
    for (int i = threadIdx.x; i < 4096; i += 256) {
        unsigned e = (xraw[i] >> 7) & 0xFF;
        if (e >= 147) lbad++;
    }
    if (lbad) atomicAdd(&bad, lbad);
    __syncthreads();
    if (threadIdx.x == 0) *flag = (bad == 0) ? 1 : 0;
}

__device__ inline bool is_bf16(const int* flag)
{
    return (*(volatile const int*)flag) == 1;
}

// ---- fused wflat+wprep: thread j computes wflat[j] = origin[j]+npar@P[:,j]
// with COALESCED P reads (j = global thread id), then scatters to its WT
// slot via the inverted relayout map. l=0 weights land in fp32 wflat0 for
// conv_l0. Pad slots (only 16ch layers: kp in [144,160), 7*16*16=1792) are
// zeroed by the first 1792 threads. WT content bit-identical to the old
// two-kernel path; saves one dispatch + the 2MB wflat round-trip.
__global__ void wprep_kernel(const void* __restrict__ origin,
                             const void* __restrict__ P,
                             const void* __restrict__ npar,
                             unsigned short* __restrict__ WT,
                             float* __restrict__ wflat0,
                             const int* flag)
{
    static const int WOFFA[20] = {0,432,2736,5040,7344,9648,11952,14256,18864,
        28080,37296,46512,55728,64944,83376,120240,157104,193968,230832,267696};
    static const int LGCA[19]  = {0,4,4,4,4,4,4,4,5,5,5,5,5,5,6,6,6,6,6};
    static const int KPADA[19] = {0,160,160,160,160,160,160,160,288,288,288,288,288,288,576,576,576,576,576};
    static const int WTOFFA[19]= {0,0,2560,5120,7680,10240,12800,15360,20480,29696,
        38912,48128,57344,66560,84992,121856,158720,195584,232448};

    const int j = blockIdx.x*256 + threadIdx.x;

    // zero the 16ch pad slots (layers 1..7, kp in [144,160))
    if (j < 1792) {
        int lp  = 1 + (j >> 8);
        int rem = j & 255;
        int co  = rem >> 4;
        int kp  = 144 + (rem & 15);
        WT[WTOFFA[lp] + co*160 + kp] = 0;
    }
    if (j >= DTOT) return;

    float acc;
    if (is_bf16(flag)) {
        const __hip_bfloat16* ob = (const __hip_bfloat16*)origin;
        const __hip_bfloat16* Pb = (const __hip_bfloat16*)P;
        const __hip_bfloat16* nb = (const __hip_bfloat16*)npar;
        acc = ldf(ob + j);
        #pragma unroll 8
        for (int k = 0; k < 40; k++)
            acc += ldf(nb + k) * ldf(Pb + (long long)k*DTOT + j);
    } else {
        const float* of = (const float*)origin;
        const float* Pf = (const float*)P;
        const float* nf = (const float*)npar;
        acc = of[j];
        #pragma unroll 8
        for (int k = 0; k < 40; k++)
            acc += nf[k] * Pf[(long long)k*DTOT + j];
    }

    // locate layer
    int l = 0;
    #pragma unroll
    for (int t = 1; t < 19; t++) if (j >= WOFFA[t]) l = t;

    if (l == 0) { wflat0[j] = acc; return; }

    const int rel   = j - WOFFA[l];
    const int oc_ic = rel / 9;
    const int tap   = rel - oc_ic*9;
    const int lg    = LGCA[l];
    const int co    = oc_ic >> lg;
    const int ci    = oc_ic & ((1 << lg) - 1);
    const int kp    = (tap << lg) | ci;
    WT[WTOFFA[l] + co*KPADA[l] + kp] = f2bf(acc);
}

// ---- layer 0: MFMA implicit-GEMM conv (Cin=3), NCHW input -> NHWC bf16 ----
// A = input patches [M=1024 pos][K=27 pad 32], B = weights [N=16][K], using
// the proven conv_mfma fragment conventions. Input staged into zero-bordered
// LDS image [3][34][36]; k>=27 reads valid words, weight = 0. Epilogue
// (bounce + slotted stats) is the conv_mfma NT=1 pattern.
__global__ __launch_bounds__(256, 4) void conv_l0(
    const void* __restrict__ in, const float* __restrict__ wt,
    unsigned short* __restrict__ out, float* __restrict__ ps,
    const int* flag)
{
    __shared__ unsigned short lbuf[16384];   // image 3*34*36=3672 u16; bounce 16384 u16
    __shared__ float red[128];

    const int tid = threadIdx.x;
    const int b   = blockIdx.x;
    const bool isbf = is_bf16(flag);

    {
        unsigned int* l4 = (unsigned int*)lbuf;
        for (int i = tid; i < 1836; i += 256) l4[i] = 0u;
    }
    __syncthreads();

    {
        const __hip_bfloat16* ih_ = (const __hip_bfloat16*)in + (size_t)b*3072;
        const float*          if_ = (const float*)in + (size_t)b*3072;
        for (int i = tid; i < 3072; i += 256) {
            int c = i >> 10, rem = i & 1023, h = rem >> 5, w2 = rem & 31;
            float x = isbf ? ldf(ih_ + i) : if_[i];
            lbuf[c*1224 + (h+1)*36 + (w2+1)] = f2bf(x);
        }
    }

    const int w_  = tid >> 6;
    const int ln  = tid & 63;
    const int l15 = ln & 15;
    const int q   = ln >> 4;

    v8s Bf;
    {
        union { unsigned int u[4]; v8s v; } bu;
        #pragma unroll
        for (int kk2 = 0; kk2 < 4; kk2++) {
            int k0 = q*8 + kk2*2, k1 = k0 + 1;
            float w0 = (k0 < 27) ? wt[l15*27 + k0] : 0.f;
            float w1 = (k1 < 27) ? wt[l15*27 + k1] : 0.f;
            bu.u[kk2] = (unsigned)f2bf(w0) | ((unsigned)f2bf(w1) << 16);
        }
        Bf = bu.v;
    }

    int offk[8];
    #pragma unroll
    for (int kk = 0; kk < 8; kk++) {
        int k = q*8 + kk;
        int ci = k / 9;
        int tap = k - ci*9;
        int kh = tap / 3, kw = tap - kh*3;
        if (ci > 2) { ci = 0; kh = 0; kw = 0; }
        offk[kk] = ci*1224 + kh*36 + kw;
    }
    __syncthreads();

    v4f acc[16];
    #pragma unroll
    for (int j = 0; j < 16; j++) acc[j] = v4f{0.f,0.f,0.f,0.f};

    #pragma unroll
    for (int j = 0; j < 16; j++) {
        const int mt = w_ + j*4;
        const int p  = mt*16 + l15;
        const int base = (p >> 5)*36 + (p & 31);
        union { unsigned int u[4]; v8s v; } au;
        #pragma unroll
        for (int kk2 = 0; kk2 < 4; kk2++) {
            unsigned a0 = lbuf[base + offk[kk2*2]];
            unsigned a1 = lbuf[base + offk[kk2*2+1]];
            au.u[kk2] = a0 | (a1 << 16);
        }
        acc[j] = __builtin_amdgcn_mfma_f32_16x16x32_bf16(au.v, Bf, acc[j], 0, 0, 0);
    }
    __syncthreads();

    float sa = 0.f, qa = 0.f;
    #pragma unroll
    for (int j = 0; j < 16; j++) {
        const int mt = w_ + j*4;
        #pragma unroll
        for (int r2 = 0; r2 < 4; r2++) {
            float v = acc[j][r2];
            lbuf[(mt*16 + q*4 + r2)*16 + l15] = f2bf(v);
            sa += v; qa += v*v;
        }
    }
    __syncthreads();
    {
        uint4* ob4 = (uint4*)(out + (size_t)b*16384);
        const uint4* os4 = (const uint4*)lbuf;
        #pragma unroll
        for (int it = 0; it < 8; it++)
            ob4[it*256 + tid] = os4[it*256 + tid];
    }
    sa += __shfl_xor(sa, 16); sa += __shfl_xor(sa, 32);
    qa += __shfl_xor(qa, 16); qa += __shfl_xor(qa, 32);
    if (q == 0) {
        red[(w_*16 + l15)*2]     = sa;
        red[(w_*16 + l15)*2 + 1] = qa;
    }
    __syncthreads();
    if (tid < 16) {
        float S2 = red[tid*2] + red[(16+tid)*2] + red[(32+tid)*2] + red[(48+tid)*2];
        float Q2 = red[tid*2+1] + red[(16+tid)*2+1] + red[(32+tid)*2+1] + red[(48+tid)*2+1];
        float* sl = ps + (b & (NSLOT-1))*128;
        atomicAdd(&sl[tid],      S2);
        atomicAdd(&sl[64 + tid], Q2);
    }
}

// ---- MFMA implicit-GEMM 3x3 conv, one block (4 waves) per image ----
// FUSE : staging performs preceding stride-1 bn_add (elementwise residual).
// FUSE2: staging performs preceding stride-2 bn_add (residual = 2x-res gather,
//        channel pad 8-aligned -> whole uint4 group valid or zero).
// Stats: 64-slot partial buffers [NSLOT][128]; producers atomicAdd into slot
// (b & 63); consumers reduce the 64 slots at kernel start (L2-hot 32KB read).
// Main loop: j-outer/s-inner with Bf[S] preload for CIN=16/32 (proven best);
// s-outer/j-inner for CIN=64 where Bf[18]=72 VGPRs would spill to scratch.
// (Mega-kernel fusion arc r5-r10: cross-XCD sync inside one kernel requires
//  ACQUIRE=L2-invalidate (~200us/barrier) or hangs with relaxed loads ->
//  multi-dispatch is the correct structure.)
template<int CIN, int COUT, int HIN, int WIN, int ST, bool FUSE, bool PN,
         bool FUSE2, int PREVC, int PADF>
__global__ __launch_bounds__(256, 4) void conv_mfma(
    const unsigned short* __restrict__ src, const unsigned short* __restrict__ prev,
    unsigned short* __restrict__ resid,
    const unsigned short* __restrict__ wt,
    unsigned short* __restrict__ out, float* __restrict__ stats,
    const float* __restrict__ nstats, float ninvN,
    const float* __restrict__ pstats, float pinvN)
{
    constexpr int HO = HIN/ST, WO = WIN/ST, M = HO*WO, MT = M/16;
    constexpr int NT = COUT/16;
    constexpr int K  = 9*CIN;
    constexpr int S  = (K + 31)/32;
    constexpr int KPAD = S*32;
    constexpr int lgC  = (CIN==16)?4:(CIN==32)?5:6;
    constexpr int lgWI = (WIN==32)?5:(WIN==16)?4:3;
    constexpr int lgWO = (WO==32)?5:(WO==16)?4:3;
    constexpr int CMASK = CIN/8 - 1;
    constexpr int JITER = (NT==1)? MT/4 : (NT==2)? MT/2 : MT;
    static_assert(M*COUT <= CIN*HIN*WIN, "out_s fits in in_s");

    __shared__ unsigned short in_s[CIN*HIN*WIN];   // input, then output bounce
    __shared__ float red[128];
    __shared__ float statred[256];
    __shared__ float nm[64], nv[64];
    __shared__ float pm_s[64], pv_s[64];
    __shared__ uint4 zq;

    const int tid = threadIdx.x;
    const int b   = blockIdx.x;

    if (tid == 0) { zq.x = 0; zq.y = 0; zq.z = 0; zq.w = 0; }

    // ---- reduce 64-slot producer partials -> nm/nv (and pm/pv if PN) ----
    {
        const int idx = tid & 127, hf = tid >> 7;
        float sacc = 0.f;
        #pragma unroll 8
        for (int k = hf*32; k < hf*32 + 32; k++)
            sacc += nstats[k*128 + idx];
        statred[tid] = sacc;
    }
    __syncthreads();
    if (tid < CIN) {
        float ssum = statred[tid]      + statred[128 + tid];
        float qsum = statred[64 + tid] + statred[192 + tid];
        float m = ssum*ninvN;
        float v = fmaxf(qsum*ninvN - m*m, 0.f);
        nm[tid] = m; nv[tid] = rsqrtf(v + 1e-5f);
    }
    if (PN && tid < CIN) {
        float ssum = 0.f, qsum = 0.f;
        for (int k = 0; k < NSLOT; k++) {
            ssum += pstats[k*128 + tid];
            qsum += pstats[k*128 + 64 + tid];
        }
        float m = ssum*pinvN;
        float v = fmaxf(qsum*pinvN - m*m, 0.f);
        pm_s[tid] = m; pv_s[tid] = rsqrtf(v + 1e-5f);
    }
    __syncthreads();

    // ---- staging ----
    {
        const uint4* sb4 = (const uint4*)(src + (size_t)b*(HIN*WIN)*CIN);
        constexpr int NP4 = CIN*HIN*WIN/8;
        if (FUSE) {
            const uint4* pb4 = (const uint4*)(prev + (size_t)b*(HIN*WIN)*CIN);
            uint4* rb4 = (uint4*)(resid + (size_t)b*(HIN*WIN)*CIN);
            for (int i = tid; i < NP4; i += 256) {
                uint4 v = sb4[i];
                uint4 pw = pb4[i];
                int e0 = i << 3;
                int c0 = e0 & (CIN-1);
                int p  = e0 >> lgC;
                float f[8] = { bf2f(v.x & 0xffffu), bf2f(v.x >> 16),
                               bf2f(v.y & 0xffffu), bf2f(v.y >> 16),
                               bf2f(v.z & 0xffffu), bf2f(v.z >> 16),
                               bf2f(v.w & 0xffffu), bf2f(v.w >> 16) };
                float g[8] = { bf2f(pw.x & 0xffffu), bf2f(pw.x >> 16),
                               bf2f(pw.y & 0xffffu), bf2f(pw.y >> 16),
                               bf2f(pw.z & 0xffffu), bf2f(pw.z >> 16),
                               bf2f(pw.w & 0xffffu), bf2f(pw.w >> 16) };
                #pragma unroll
                for (int k = 0; k < 8; k++) {
                    int c = c0 + k;
                    float fx = (f[k] - nm[c])*nv[c];
                    float gv = g[k];
                    if (PN) gv = fmaxf((gv - pm_s[c])*pv_s[c], 0.f);
                    f[k] = fmaxf(fx + gv, 0.f);
                }
                uint4 o;
                o.x = (unsigned)f2bf(f[0]) | ((unsigned)f2bf(f[1]) << 16);
                o.y = (unsigned)f2bf(f[2]) | ((unsigned)f2bf(f[3]) << 16);
                o.z = (unsigned)f2bf(f[4]) | ((unsigned)f2bf(f[5]) << 16);
                o.w = (unsigned)f2bf(f[6]) | ((unsigned)f2bf(f[7]) << 16);
                rb4[i] = o;
                int csw = c0 ^ ((p & CMASK) << 3);
                *(uint4*)(in_s + (p << lgC) + csw) = o;
            }
        } else if (FUSE2) {
            // prev dims: (2*HIN)x(2*WIN)xPREVC; group valid iff pc0 in [0,PREVC-8]
            uint4* rb4 = (uint4*)(resid + (size_t)b*(HIN*WIN)*CIN);
            for (int i = tid; i < NP4; i += 256) {
                uint4 v = sb4[i];
                int e0 = i << 3;
                int c0 = e0 & (CIN-1);
                int p  = e0 >> lgC;
                int h  = p >> lgWI, wq = p & (WIN-1);
                int pp = (h << (lgWI+2)) + 2*wq;
                int pc0 = c0 - PADF;
                bool pv = (pc0 >= 0) && (pc0 <= PREVC - 8);
                uint4 pw;
                pw.x = 0; pw.y = 0; pw.z = 0; pw.w = 0;
                if (pv) pw = *(const uint4*)(prev + ((size_t)b*(HIN*WIN*4) + pp)*PREVC + pc0);
                float f[8] = { bf2f(v.x & 0xffffu), bf2f(v.x >> 16),
                               bf2f(v.y & 0xffffu), bf2f(v.y >> 16),
                               bf2f(v.z & 0xffffu), bf2f(v.z >> 16),
                               bf2f(v.w & 0xffffu), bf2f(v.w >> 16) };
                float g[8] = { bf2f(pw.x & 0xffffu), bf2f(pw.x >> 16),
                               bf2f(pw.y & 0xffffu), bf2f(pw.y >> 16),
                               bf2f(pw.z & 0xffffu), bf2f(pw.z >> 16),
                               bf2f(pw.w & 0xffffu), bf2f(pw.w >> 16) };
                #pragma unroll
                for (int k = 0; k < 8; k++) {
                    int c = c0 + k;
                    f[k] = fmaxf((f[k] - nm[c])*nv[c] + g[k], 0.f);
                }
                uint4 o;
                o.x = (unsigned)f2bf(f[0]) | ((unsigned)f2bf(f[1]) << 16);
                o.y = (unsigned)f2bf(f[2]) | ((unsigned)f2bf(f[3]) << 16);
                o.z = (unsigned)f2bf(f[4]) | ((unsigned)f2bf(f[5]) << 16);
                o.w = (unsigned)f2bf(f[6]) | ((unsigned)f2bf(f[7]) << 16);
                rb4[i] = o;
                int csw = c0 ^ ((p & CMASK) << 3);
                *(uint4*)(in_s + (p << lgC) + csw) = o;
            }
        } else {
            for (int i = tid; i < NP4; i += 256) {
                uint4 v = sb4[i];
                int e0 = i << 3;
                int c0 = e0 & (CIN-1);
                int p  = e0 >> lgC;
                float f[8] = { bf2f(v.x & 0xffffu), bf2f(v.x >> 16),
                               bf2f(v.y & 0xffffu), bf2f(v.y >> 16),
                               bf2f(v.z & 0xffffu), bf2f(v.z >> 16),
                               bf2f(v.w & 0xffffu), bf2f(v.w >> 16) };
                #pragma unroll
                for (int k = 0; k < 8; k++) {
                    int c = c0 + k;
                    f[k] = fmaxf((f[k] - nm[c])*nv[c], 0.f);
                }
                uint4 o;
                o.x = (unsigned)f2bf(f[0]) | ((unsigned)f2bf(f[1]) << 16);
                o.y = (unsigned)f2bf(f[2]) | ((unsigned)f2bf(f[3]) << 16);
                o.z = (unsigned)f2bf(f[4]) | ((unsigned)f2bf(f[5]) << 16);
                o.w = (unsigned)f2bf(f[6]) | ((unsigned)f2bf(f[7]) << 16);
                int csw = c0 ^ ((p & CMASK) << 3);
                *(uint4*)(in_s + (p << lgC) + csw) = o;
            }
        }
    }
    __syncthreads();

    const int w   = tid >> 6;
    const int ln  = tid & 63;
    const int l15 = ln & 15;
    const int q   = ln >> 4;

    int n0, mt0, step;
    if (NT == 1)      { n0 = 0;         mt0 = w;      step = 4; }
    else if (NT == 2) { n0 = (w&1)*16;  mt0 = w>>1;   step = 2; }
    else              { n0 = w*16;      mt0 = 0;      step = 1; }

    const unsigned short* wb = wt + (size_t)(n0 + l15)*KPAD + q*8;
    const int c0q = (CIN==16) ? ((q & 1) << 3) : (q << 3);

    v4f acc[JITER];
    #pragma unroll
    for (int j = 0; j < JITER; j++) acc[j] = v4f{0.f,0.f,0.f,0.f};

    if constexpr (CIN == 64) {
        // s-outer / j-inner: one weight fragment live, JITER independent MFMAs
        #pragma unroll
        for (int s = 0; s < S; s++) {
            const v8s Bf = *(const v8s*)(wb + 32*s);
            const int tap = s >> 1;
            const int dh1 = tap/3 - 1, dw1 = tap%3 - 1;
            const int c0s = c0q + ((s & 1) << 5);
            #pragma unroll
            for (int j = 0; j < JITER; j++) {
                const int mt  = mt0 + j*step;
                const int p   = mt*16 + l15;
                const int ihb = (p >> lgWO) * ST;
                const int iwb = (p & (WO-1)) * ST;
                int ih = ihb + dh1, iw = iwb + dw1;
                bool valid = ((unsigned)ih < (unsigned)HIN) && ((unsigned)iw < (unsigned)WIN);
                int pp  = (ih << lgWI) + iw;
                int csw = c0s ^ ((pp & CMASK) << 3);
                int eoff = (pp << lgC) + csw;
                const v8s* ap = valid ? (const v8s*)(in_s + eoff) : (const v8s*)&zq;
                v8s Af = *ap;
                acc[j] = __builtin_amdgcn_mfma_f32_16x16x32_bf16(Af, Bf, acc[j], 0, 0, 0);
            }
        }
    } else {
        v8s Bf[S];
        #pragma unroll
        for (int s = 0; s < S; s++)
            Bf[s] = *(const v8s*)(wb + 32*s);

        int dh1s[S], dw1s[S];
        if (CIN == 16) {
            int tq = q >> 1;
            #pragma unroll
            for (int s = 0; s < S; s++) {
                int tap = 2*s + tq;
                int dh = (tap*11) >> 5;
                int dw = tap - 3*dh;
                dh1s[s] = (tap >= 9) ? -1000 : (dh - 1);
                dw1s[s] = dw - 1;
            }
        }

        #pragma unroll
        for (int j = 0; j < JITER; j++) {
            const int mt  = mt0 + j*step;
            const int p   = mt*16 + l15;
            const int ihb = (p >> lgWO) * ST;
            const int iwb = (p & (WO-1)) * ST;
            #pragma unroll
            for (int s = 0; s < S; s++) {
                int dh1, dw1;
                if (CIN == 16) { dh1 = dh1s[s]; dw1 = dw1s[s]; }
                else           { dh1 = s/3 - 1; dw1 = s%3 - 1; }
                int ih = ihb + dh1, iw = iwb + dw1;
                bool valid = ((unsigned)ih < (unsigned)HIN) && ((unsigned)iw < (unsigned)WIN);
                int pp  = (ih << lgWI) + iw;
                int csw = c0q ^ ((pp & CMASK) << 3);
                int eoff = (pp << lgC) + csw;
                const v8s* ap = valid ? (const v8s*)(in_s + eoff) : (const v8s*)&zq;
                v8s Af = *ap;
                acc[j] = __builtin_amdgcn_mfma_f32_16x16x32_bf16(Af, Bf[s], acc[j], 0, 0, 0);
            }
        }
    }
    __syncthreads();   // all in_s reads complete -> reuse as output bounce

    unsigned short* out_s = in_s;
    float sa = 0.f, qa = 0.f;
    #pragma unroll
    for (int j = 0; j < JITER; j++) {
        const int mt = mt0 + j*step;
        #pragma unroll
        for (int r2 = 0; r2 < 4; r2++) {
            float v = acc[j][r2];
            out_s[(mt*16 + q*4 + r2)*COUT + n0 + l15] = f2bf(v);
            sa += v; qa += v*v;
        }
    }
    __syncthreads();

    {
        constexpr int NIT = (M*COUT/8)/256;
        uint4* ob4 = (uint4*)(out + (size_t)b*M*COUT);
        const uint4* os4 = (const uint4*)in_s;
        #pragma unroll
        for (int it = 0; it < NIT; it++)
            ob4[it*256 + tid] = os4[it*256 + tid];
    }

    sa += __shfl_xor(sa, 16); sa += __shfl_xor(sa, 32);
    qa += __shfl_xor(qa, 16); qa += __shfl_xor(qa, 32);
    if (q == 0) {
        red[(w*16 + l15)*2]     = sa;
        red[(w*16 + l15)*2 + 1] = qa;
    }
    __syncthreads();
    if (tid < COUT) {
        float S2, Q2;
        if (NT == 1) {
            S2 = red[tid*2] + red[(16+tid)*2] + red[(32+tid)*2] + red[(48+tid)*2];
            Q2 = red[tid*2+1] + red[(16+tid)*2+1] + red[(32+tid)*2+1] + red[(48+tid)*2+1];
        } else if (NT == 2) {
            int w0 = tid >> 4, cl = tid & 15;
            S2 = red[((w0*16)+cl)*2]     + red[(((w0+2)*16)+cl)*2];
            Q2 = red[((w0*16)+cl)*2 + 1] + red[(((w0+2)*16)+cl)*2 + 1];
        } else {
            int w0 = tid >> 4, cl = tid & 15;
            S2 = red[((w0*16)+cl)*2];
            Q2 = red[((w0*16)+cl)*2 + 1];
        }
        float* sl = stats + (b & (NSLOT-1))*128;
        atomicAdd(&sl[tid],      S2);
        atomicAdd(&sl[64 + tid], Q2);
    }
}

// final bn_add fused into pool+fc; stats = 64-slot partial region of l18.
// 256 threads: 4-way p-split (r8-verified pool-phase structure).
__global__ __launch_bounds__(256) void poolfc_kernel(
    const unsigned short* __restrict__ x,
    const unsigned short* __restrict__ resid,
    const float* __restrict__ stats, float invN,
    const void* __restrict__ Wfc, const void* __restrict__ bfc,
    void* __restrict__ out, const int* flag)
{
    __shared__ float statred[256];
    __shared__ float nm[64], nv[64];
    __shared__ float part[256];
    __shared__ float feat[64];
    const int b = blockIdx.x;
    const int tid = threadIdx.x;

    {
        const int idx = tid & 127, hf = tid >> 7;
        float sacc = 0.f;
        #pragma unroll 8
        for (int k = hf*32; k < hf*32 + 32; k++)
            sacc += stats[k*128 + idx];
        statred[tid] = sacc;
    }
    __syncthreads();
    if (tid < 64) {
        float ssum = statred[tid]      + statred[128 + tid];
        float qsum = statred[64 + tid] + statred[192 + tid];
        float m = ssum*invN;
        float v = fmaxf(qsum*invN - m*m, 0.f);
        nm[tid] = m; nv[tid] = rsqrtf(v + 1e-5f);
    }
    __syncthreads();

    const int c = tid & 63, pq = tid >> 6;
    const float m = nm[c], rs = nv[c];
    float s = 0.f;
    #pragma unroll
    for (int p = pq*16; p < pq*16 + 16; p++) {
        size_t idx = ((size_t)b*64 + p)*64 + c;
        float xv = bf2f((unsigned int)x[idx]);
        float rv = bf2f((unsigned int)resid[idx]);
        s += fmaxf((xv - m)*rs + rv, 0.f);
    }
    part[pq*64 + c] = s;
    __syncthreads();
    if (tid < 64) {
        feat[tid] = (part[tid] + part[64+tid] + part[128+tid] + part[192+tid])
                  * (1.f/64.f);
    }
    __syncthreads();
    if (tid < 10) {
        if (is_bf16(flag)) {
            const __hip_bfloat16* W  = (const __hip_bfloat16*)Wfc;
            const __hip_bfloat16* bb = (const __hip_bfloat16*)bfc;
            float o = ldf(bb + tid);
            for (int k = 0; k < 64; k++)
                o += feat[k] * ldf(W + tid*64 + k);
            ((__hip_bfloat16*)out)[b*10 + tid] = __float2bfloat16(o);
        } else {
            const float* W  = (const float*)Wfc;
            const float* bb = (const float*)bfc;
            float o = bb[tid];
            for (int k = 0; k < 64; k++)
                o += feat[k] * W[tid*64 + k];
            ((float*)out)[b*10 + tid] = o;
        }
    }
}

extern "C" void kernel_launch(void* const* d_in, const int* in_sizes, int n_in,
                              void* d_out, int out_size, void* d_ws, size_t ws_size,
                              hipStream_t stream)
{
    char* ws = (char*)d_ws;
    float* wflat = (float*)(ws);                            // 432 fp32 (l0 weights)
    int*   flag  = (int*)  (ws + 1146880);
    unsigned short* WT = (unsigned short*)(ws + 1179648);   // 269312 bf16
    unsigned short* curA = (unsigned short*)(ws + 1720320);               // 33.5MB
    unsigned short* curB = (unsigned short*)(ws + 1720320 + 33554432ULL); // 33.5MB (l0 raw)
    unsigned short* f1   = (unsigned short*)(ws + 1720320 + 67108864ULL);
    unsigned short* f2   = (unsigned short*)(ws + 1720320 + 100663296ULL);
    float* ps    = (float*)(ws + 135938048ULL);  // 19 x [64][128] fp32 partial stats

    hipMemsetAsync(ps, 0, NLAYER*PSL*4, stream);
    detect_kernel<<<1, 256, 0, stream>>>((const unsigned short*)d_in[0], flag);

    // fused wflat+wprep (coalesced P reads, scattered WT writes; l0 -> wflat)
    wprep_kernel<<<(DTOT+255)/256, 256, 0, stream>>>(
        d_in[1], d_in[2], d_in[3], WT, wflat, flag);

    static const int WTOFF[NLAYER] = {0,0,2560,5120,7680,10240,12800,15360,20480,29696,
        38912,48128,57344,66560,84992,121856,158720,195584,232448};
    const float iN32 = 1.f/1048576.f;   // B*32*32
    const float iN16 = 1.f/262144.f;    // B*16*16
    const float iN8  = 1.f/65536.f;     // B*8*8

    // ---- layer 0 (MFMA implicit-GEMM; stats fused into epilogue) ----
    conv_l0<<<BATCH,256,0,stream>>>(d_in[0], wflat, curB, ps, flag);

    // b0
    conv_mfma<16,16,32,32,1,false,false,false,0,0><<<BATCH,256,0,stream>>>(
        curB, nullptr, nullptr, WT + WTOFF[1], f1, ps + 1*PSL, ps, iN32, nullptr, 0.f);
    conv_mfma<16,16,32,32,1,false,false,false,0,0><<<BATCH,256,0,stream>>>(
        f1, nullptr, nullptr, WT + WTOFF[2], f2, ps + 2*PSL, ps + 1*PSL, iN32, nullptr, 0.f);
    // b1: fused bn_add(b0) [PN=l0 stats]; resid -> curA
    conv_mfma<16,16,32,32,1,true,true,false,0,0><<<BATCH,256,0,stream>>>(
        f2, curB, curA, WT + WTOFF[3], f1, ps + 3*PSL, ps + 2*PSL, iN32, ps, iN32);
    conv_mfma<16,16,32,32,1,false,false,false,0,0><<<BATCH,256,0,stream>>>(
        f1, nullptr, nullptr, WT + WTOFF[4], f2, ps + 4*PSL, ps + 3*PSL, iN32, nullptr, 0.f);
    // b2: fused bn_add(b1); resid -> curB
    conv_mfma<16,16,32,32,1,true,false,false,0,0><<<BATCH,256,0,stream>>>(
        f2, curA, curB, WT + WTOFF[5], f1, ps + 5*PSL, ps + 4*PSL, iN32, nullptr, 0.f);
    conv_mfma<16,16,32,32,1,false,false,false,0,0><<<BATCH,256,0,stream>>>(
        f1, nullptr, nullptr, WT + WTOFF[6], f2, ps + 6*PSL, ps + 5*PSL, iN32, nullptr, 0.f);
    // b3: fused bn_add(b2) into stride-2 conv-A(l7); resid -> curA (32²,16ch)
    conv_mfma<16,32,32,32,2,true,false,false,0,0><<<BATCH,256,0,stream>>>(
        f2, curB, curA, WT + WTOFF[7], f1, ps + 7*PSL, ps + 6*PSL, iN32, nullptr, 0.f);
    conv_mfma<32,32,16,16,1,false,false,false,0,0><<<BATCH,256,0,stream>>>(
        f1, nullptr, nullptr, WT + WTOFF[8], f2, ps + 8*PSL, ps + 7*PSL, iN16, nullptr, 0.f);
    // b4: FUSE2 bn_add(b3, stride2 shortcut from curA) into conv-A(l9); resid -> curB
    conv_mfma<32,32,16,16,1,false,false,true,16,8><<<BATCH,256,0,stream>>>(
        f2, curA, curB, WT + WTOFF[9], f1, ps + 9*PSL, ps + 8*PSL, iN16, nullptr, 0.f);
    conv_mfma<32,32,16,16,1,false,false,false,0,0><<<BATCH,256,0,stream>>>(
        f1, nullptr, nullptr, WT + WTOFF[10], f2, ps + 10*PSL, ps + 9*PSL, iN16, nullptr, 0.f);
    // b5: fused bn_add(b4); resid -> curA
    conv_mfma<32,32,16,16,1,true,false,false,0,0><<<BATCH,256,0,stream>>>(
        f2, curB, curA, WT + WTOFF[11], f1, ps + 11*PSL, ps + 10*PSL, iN16, nullptr, 0.f);
    conv_mfma<32,32,16,16,1,false,false,false,0,0><<<BATCH,256,0,stream>>>(
        f1, nullptr, nullptr, WT + WTOFF[12], f2, ps + 12*PSL, ps + 11*PSL, iN16, nullptr, 0.f);
    // b6: fused bn_add(b5) into stride-2 conv-A(l13); resid -> curB (16²,32ch)
    conv_mfma<32,64,16,16,2,true,false,false,0,0><<<BATCH,256,0,stream>>>(
        f2, curA, curB, WT + WTOFF[13], f1, ps + 13*PSL, ps + 12*PSL, iN16, nullptr, 0.f);
    conv_mfma<64,64,8,8,1,false,false,false,0,0><<<BATCH,256,0,stream>>>(
        f1, nullptr, nullptr, WT + WTOFF[14], f2, ps + 14*PSL, ps + 13*PSL, iN8, nullptr, 0.f);
    // b7: FUSE2 bn_add(b6, stride2 shortcut from curB) into conv-A(l15); resid -> curA
    conv_mfma<64,64,8,8,1,false,false,true,32,16><<<BATCH,256,0,stream>>>(
        f2, curB, curA, WT + WTOFF[15], f1, ps + 15*PSL, ps + 14*PSL, iN8, nullptr, 0.f);
    conv_mfma<64,64,8,8,1,false,false,false,0,0><<<BATCH,256,0,stream>>>(
        f1, nullptr, nullptr, WT + WTOFF[16], f2, ps + 16*PSL, ps + 15*PSL, iN8, nullptr, 0.f);
    // b8: fused bn_add(b7); resid -> curB
    conv_mfma<64,64,8,8,1,true,false,false,0,0><<<BATCH,256,0,stream>>>(
        f2, curA, curB, WT + WTOFF[17], f1, ps + 17*PSL, ps + 16*PSL, iN8, nullptr, 0.f);
    conv_mfma<64,64,8,8,1,false,false,false,0,0><<<BATCH,256,0,stream>>>(
        f1, nullptr, nullptr, WT + WTOFF[18], f2, ps + 18*PSL, ps + 17*PSL, iN8, nullptr, 0.f);

    // final bn_add(l18)+resid(curB) fused into pool+fc
    poolfc_kernel<<<BATCH, 256, 0, stream>>>(
        f2, curB, ps + 18*PSL, iN8, d_in[4], d_in[5], d_out, flag);
}